// Round 2
// baseline (17701.488 us; speedup 1.0000x reference)
//
#include <hip/hip_runtime.h>
#include <math.h>

// Problem constants (match reference)
#define R_TOT 16384      // B*L
#define LSEQ  4096
#define DMODEL 1024
#define NHEAD 8
#define DHEAD 128        // DK = DV

__device__ __forceinline__ float sigmoidf_(float x) { return 1.f / (1.f + expf(-x)); }

// ---------------------------------------------------------------------------
// Generic fp32 tiled GEMM: C(MxN) = epilogue(A(MxK) @ B(KxN))
// A is split: cols [0,Ksplit) from A (stride lda1), [Ksplit,K) from A2 (stride lda2)
// MODE 0: none  1: sigmoid  2: gelu(x+bias)  3: p-gate (bias, /exp(log_temp), eps+sigmoid)
// ---------------------------------------------------------------------------
template<int MODE>
__global__ __launch_bounds__(256)
void sgemm(const float* __restrict__ A, const float* __restrict__ A2,
           int Ksplit, int lda1, int lda2,
           const float* __restrict__ Bm, const float* __restrict__ bias,
           const float* __restrict__ aux, float* __restrict__ C,
           int M, int N, int K)
{
    __shared__ float As[16][65];
    __shared__ float Bs[16][65];
    const int tid = threadIdx.x;
    const int m0 = blockIdx.y * 64, n0 = blockIdx.x * 64;
    const int tx = tid & 15, ty = tid >> 4;
    const int arow = tid >> 2, ak0 = (tid & 3) * 4;
    const int bcol = tid & 63, bk0 = (tid >> 6) * 4;
    float acc[4][4] = {};
    for (int k0 = 0; k0 < K; k0 += 16) {
#pragma unroll
        for (int i = 0; i < 4; ++i) {
            int kg = k0 + ak0 + i;
            int mg = m0 + arow;
            float v = 0.f;
            if (mg < M && kg < K)
                v = (kg < Ksplit) ? A[(size_t)mg * lda1 + kg]
                                  : A2[(size_t)mg * lda2 + (kg - Ksplit)];
            As[ak0 + i][arow] = v;
        }
#pragma unroll
        for (int i = 0; i < 4; ++i) {
            int kg = k0 + bk0 + i;
            int ng = n0 + bcol;
            float v = 0.f;
            if (kg < K && ng < N) v = Bm[(size_t)kg * N + ng];
            Bs[bk0 + i][bcol] = v;
        }
        __syncthreads();
#pragma unroll
        for (int kk = 0; kk < 16; ++kk) {
            float a[4], b[4];
#pragma unroll
            for (int i = 0; i < 4; ++i) a[i] = As[kk][ty * 4 + i];
#pragma unroll
            for (int j = 0; j < 4; ++j) b[j] = Bs[kk][tx * 4 + j];
#pragma unroll
            for (int i = 0; i < 4; ++i)
#pragma unroll
                for (int j = 0; j < 4; ++j) acc[i][j] = fmaf(a[i], b[j], acc[i][j]);
        }
        __syncthreads();
    }
#pragma unroll
    for (int i = 0; i < 4; ++i) {
        int row = m0 + ty * 4 + i;
        if (row >= M) continue;
#pragma unroll
        for (int j = 0; j < 4; ++j) {
            int col = n0 + tx * 4 + j;
            if (col >= N) continue;
            float x = acc[i][j];
            if (MODE == 1) {
                x = sigmoidf_(x);
            } else if (MODE == 2) {
                x += bias[col];
                x = 0.5f * x * (1.f + erff(x * 0.70710678118654752f));
            } else if (MODE == 3) {
                x += bias[col];
                x *= expf(-aux[col >> 2]);      // divide by exp(log_temp[head])
                x = 0.02f + 0.98f * sigmoidf_(x);
            }
            C[(size_t)row * N + col] = x;
        }
    }
}

// ---------------------------------------------------------------------------
// Short causal conv (K=4) over D channels + SiLU.  x,y: (R, D) fp32, w: (D,4)
// ---------------------------------------------------------------------------
__global__ __launch_bounds__(256)
void shortconv(const float* __restrict__ x, const float* __restrict__ w,
               float* __restrict__ y)
{
    size_t idx = (size_t)blockIdx.x * 256 + threadIdx.x;
    if (idx >= (size_t)R_TOT * DMODEL) return;
    int c = (int)(idx & (DMODEL - 1));
    long r = (long)(idx >> 10);
    int l = (int)(r & (LSEQ - 1));
    const float* wc = w + c * 4;
    float acc = 0.f;
#pragma unroll
    for (int j = 0; j < 4; ++j) {
        int xl = l - 3 + j;
        if (xl >= 0) acc += x[(r - l + xl) * DMODEL + c] * wc[j];
    }
    y[idx] = acc * sigmoidf_(acc);   // silu
}

// ---------------------------------------------------------------------------
// Delta-rule chunked scan.  One block per (b, h, dv-block of 32).
// q,k,v: (R, 1024) fp32 (post conv+silu), beta: (R, 8), ret: (8)
// dout:  (R, 1024) laid out as (b, l, h, dv)
// ---------------------------------------------------------------------------
__global__ __launch_bounds__(256)
void delta_scan(const float* __restrict__ q, const float* __restrict__ k,
                const float* __restrict__ v, const float* __restrict__ beta,
                const float* __restrict__ ret, float* __restrict__ dout)
{
    const int bid = blockIdx.x;          // b*32 + h*4 + dvb
    const int b = bid >> 5, h = (bid >> 2) & 7, dvb = bid & 3;
    const int tid = threadIdx.x;

    __shared__ float qs[32][130], ks[32][130], wsm[32][130];
    __shared__ float S[128][33];
    __shared__ float Am[32][33], at[32][33], us[32][33], ua[32][33];
    __shared__ float betas[32];

    const float lam = 0.6f + 0.4f * (1.f / (1.f + expf(-ret[h])));

    for (int idx = tid; idx < 128 * 32; idx += 256) S[idx >> 5][idx & 31] = 0.f;
    __syncthreads();

    const size_t baseQ = (size_t)b * LSEQ * DMODEL + (size_t)h * DHEAD;

    for (int c = 0; c < 128; ++c) {
        const size_t rowbase = baseQ + (size_t)c * 32 * DMODEL;
        // load q,k rows (32 x 128) and v slice (32 x 32)
        for (int idx = tid; idx < 32 * 128; idx += 256) {
            int i = idx >> 7, d = idx & 127;
            size_t g = rowbase + (size_t)i * DMODEL + d;
            qs[i][d] = q[g];
            ks[i][d] = k[g];
        }
        for (int idx = tid; idx < 32 * 32; idx += 256) {
            int i = idx >> 5, t = idx & 31;
            us[i][t] = v[rowbase + (size_t)i * DMODEL + dvb * 32 + t];
        }
        if (tid < 32)
            betas[tid] = beta[((size_t)b * LSEQ + c * 32 + tid) * NHEAD + h];
        __syncthreads();

        // l2-normalize rows of q and k (eps 1e-6): 32 groups of 8 threads
        {
            int row = tid >> 3, ln = tid & 7;
            float sq = 0.f, sk = 0.f;
            for (int d = ln; d < 128; d += 8) {
                float a_ = qs[row][d]; sq += a_ * a_;
                float b_ = ks[row][d]; sk += b_ * b_;
            }
#pragma unroll
            for (int m = 1; m < 8; m <<= 1) {
                sq += __shfl_xor(sq, m);
                sk += __shfl_xor(sk, m);
            }
            float rq = rsqrtf(sq + 1e-6f), rk = rsqrtf(sk + 1e-6f);
            for (int d = ln; d < 128; d += 8) { qs[row][d] *= rq; ks[row][d] *= rk; }
        }
        __syncthreads();

        // A = tril(kb k^T, -1), attn = tril(q k^T)
        for (int idx = tid; idx < 1024; idx += 256) {
            int i = idx >> 5, j = idx & 31;
            float da = 0.f, dt = 0.f;
            for (int d = 0; d < 128; ++d) {
                float kj = ks[j][d];
                da += ks[i][d] * kj;
                dt += qs[i][d] * kj;
            }
            Am[i][j] = (i > j) ? betas[i] * da : 0.f;
            at[i][j] = (i >= j) ? dt : 0.f;
        }
        for (int idx = tid; idx < 32 * 128; idx += 256) {
            int i = idx >> 7, d = idx & 127;
            wsm[i][d] = betas[i] * ks[i][d];
        }
        for (int idx = tid; idx < 1024; idx += 256) {
            int i = idx >> 5;
            us[i][idx & 31] *= betas[i];
        }
        __syncthreads();

        // forward substitution: (I + A) x = rhs, 160 columns (32 u + 128 w)
        if (tid < 160) {
            if (tid < 32) {
                int t = tid;
                for (int i = 1; i < 32; ++i) {
                    float s = 0.f;
                    for (int m = 0; m < i; ++m) s += Am[i][m] * us[m][t];
                    us[i][t] -= s;
                }
            } else {
                int d = tid - 32;
                for (int i = 1; i < 32; ++i) {
                    float s = 0.f;
                    for (int m = 0; m < i; ++m) s += Am[i][m] * wsm[m][d];
                    wsm[i][d] -= s;
                }
            }
        }
        __syncthreads();

        // u_adj = u - w @ S
        for (int idx = tid; idx < 1024; idx += 256) {
            int i = idx >> 5, t = idx & 31;
            float s = us[i][t];
            for (int d = 0; d < 128; ++d) s -= wsm[i][d] * S[d][t];
            ua[i][t] = s;
        }
        __syncthreads();

        // o = q @ S + attn @ u_adj  (write out)
        for (int idx = tid; idx < 1024; idx += 256) {
            int i = idx >> 5, t = idx & 31;
            float s = 0.f;
            for (int d = 0; d < 128; ++d) s += qs[i][d] * S[d][t];
            for (int j = 0; j <= i; ++j) s += at[i][j] * ua[j][t];
            dout[rowbase + (size_t)i * DMODEL + dvb * 32 + t] = s;
        }
        __syncthreads();

        // S = lam * S + k^T @ u_adj
        for (int idx = tid; idx < 4096; idx += 256) {
            int d = idx >> 5, t = idx & 31;
            float s = S[d][t] * lam;
            for (int i = 0; i < 32; ++i) s += ks[i][d] * ua[i][t];
            S[d][t] = s;
        }
        __syncthreads();
    }
}

// ---------------------------------------------------------------------------
// FIR (recompute) + per-(b,l,h) means of f_short, f_long, delta, v -> stats (R,32)
// One block per (r, h), 128 threads (= d).
// ---------------------------------------------------------------------------
__global__ __launch_bounds__(128)
void fir_stats(const float* __restrict__ v, const float* __restrict__ dlt,
               const float* __restrict__ wshort, const float* __restrict__ wlong,
               float* __restrict__ stats)
{
    const int r = blockIdx.x, h = blockIdx.y, d = threadIdx.x;
    const int l = r & (LSEQ - 1);
    const size_t base = (size_t)r * DMODEL + h * DHEAD + d;
    const long rb = (long)(r - l);   // b*L
    float vd = v[base];
    const float* wsp = wshort + ((size_t)h * DHEAD + d) * 3;
    float fs = 0.f;
#pragma unroll
    for (int j = 0; j < 3; ++j) {
        int xl = l - 2 + j;
        if (xl >= 0) fs += v[(rb + xl) * DMODEL + h * DHEAD + d] * wsp[j];
    }
    const float* wlp = wlong + ((size_t)h * DHEAD + d) * 63;
    float fl = 0.f;
    for (int j = 0; j < 63; ++j) {
        int xl = l - 62 + j;
        if (xl >= 0) fl += v[(rb + xl) * DMODEL + h * DHEAD + d] * wlp[j];
    }
    float dl = dlt[base];
    float v0 = fs, v1 = fl, v2 = dl, v3 = vd;
#pragma unroll
    for (int m = 1; m < 64; m <<= 1) {
        v0 += __shfl_xor(v0, m); v1 += __shfl_xor(v1, m);
        v2 += __shfl_xor(v2, m); v3 += __shfl_xor(v3, m);
    }
    __shared__ float red[2][4];
    int wv = d >> 6;
    if ((d & 63) == 0) { red[wv][0] = v0; red[wv][1] = v1; red[wv][2] = v2; red[wv][3] = v3; }
    __syncthreads();
    if (d == 0) {
        const float inv = 1.f / 128.f;
        stats[(size_t)r * 32 + 0  + h] = (red[0][0] + red[1][0]) * inv;
        stats[(size_t)r * 32 + 8  + h] = (red[0][1] + red[1][1]) * inv;
        stats[(size_t)r * 32 + 16 + h] = (red[0][2] + red[1][2]) * inv;
        stats[(size_t)r * 32 + 24 + h] = (red[0][3] + red[1][3]) * inv;
    }
}

// ---------------------------------------------------------------------------
// Combine: o = p0*fs + p1*fl + p2*delta + p3*v ; RMS-norm over DV; * o_norm_w
// One block per (r, h), 128 threads (= d). Writes (R,1024).
// ---------------------------------------------------------------------------
__global__ __launch_bounds__(128)
void combine(const float* __restrict__ v, const float* __restrict__ dlt,
             const float* __restrict__ wshort, const float* __restrict__ wlong,
             const float* __restrict__ p, const float* __restrict__ onw,
             float* __restrict__ on)
{
    const int r = blockIdx.x, h = blockIdx.y, d = threadIdx.x;
    const int l = r & (LSEQ - 1);
    const size_t base = (size_t)r * DMODEL + h * DHEAD + d;
    const long rb = (long)(r - l);
    float vd = v[base];
    const float* wsp = wshort + ((size_t)h * DHEAD + d) * 3;
    float fs = 0.f;
#pragma unroll
    for (int j = 0; j < 3; ++j) {
        int xl = l - 2 + j;
        if (xl >= 0) fs += v[(rb + xl) * DMODEL + h * DHEAD + d] * wsp[j];
    }
    const float* wlp = wlong + ((size_t)h * DHEAD + d) * 63;
    float fl = 0.f;
    for (int j = 0; j < 63; ++j) {
        int xl = l - 62 + j;
        if (xl >= 0) fl += v[(rb + xl) * DMODEL + h * DHEAD + d] * wlp[j];
    }
    float dl = dlt[base];
    const float* pp = p + (size_t)r * 32 + h * 4;
    float o = pp[0] * fs + pp[1] * fl + pp[2] * dl + pp[3] * vd;
    float ss = o * o;
#pragma unroll
    for (int m = 1; m < 64; m <<= 1) ss += __shfl_xor(ss, m);
    __shared__ float red[2];
    int wv = d >> 6;
    if ((d & 63) == 0) red[wv] = ss;
    __syncthreads();
    float tot = red[0] + red[1];
    on[base] = o * rsqrtf(tot * (1.f / 128.f) + 1e-5f) * onw[d];
}

// ---------------------------------------------------------------------------
// Workspace budget (~196.5 MiB):
//   A (64MB): q_pre -> k -> hdn-chunk -> o_normed
//   B (64MB): k_pre -> v
//   C (64MB): v_pre -> delta_out
//   d_out (64MB) doubles as scratch: q (dead before final GEMM writes it)
// ---------------------------------------------------------------------------
extern "C" void kernel_launch(void* const* d_in, const int* in_sizes, int n_in,
                              void* d_out, int out_size, void* d_ws, size_t ws_size,
                              hipStream_t stream)
{
    const float* hs   = (const float*)d_in[0];
    const float* Wq   = (const float*)d_in[1];
    const float* Wk   = (const float*)d_in[2];
    const float* Wv   = (const float*)d_in[3];
    const float* Wb   = (const float*)d_in[4];
    const float* cqw  = (const float*)d_in[5];
    const float* ckw  = (const float*)d_in[6];
    const float* cvw  = (const float*)d_in[7];
    const float* ret  = (const float*)d_in[8];
    const float* fsw  = (const float*)d_in[9];
    const float* flw  = (const float*)d_in[10];
    const float* gw1  = (const float*)d_in[11];
    const float* gb1  = (const float*)d_in[12];
    const float* gw2  = (const float*)d_in[13];
    const float* gb2  = (const float*)d_in[14];
    const float* ltmp = (const float*)d_in[15];
    const float* onw  = (const float*)d_in[16];
    const float* Wo   = (const float*)d_in[17];
    float* out = (float*)d_out;

    char* wsp = (char*)d_ws;
    size_t off = 0;
    auto alloc = [&](size_t nfloats) -> float* {
        float* pt = (float*)(wsp + off);
        off += ((nfloats * 4 + 255) / 256) * 256;
        return pt;
    };
    const int R = R_TOT;
    float* bufA  = alloc((size_t)R * DMODEL);
    float* bufB  = alloc((size_t)R * DMODEL);
    float* bufC  = alloc((size_t)R * DMODEL);
    float* beta  = alloc((size_t)R * NHEAD);
    float* stats = alloc((size_t)R * 32);
    float* pbuf  = alloc((size_t)R * 32);
    float* bufO  = out;                       // d_out as scratch for q
    (void)ws_size; (void)in_sizes; (void)n_in; (void)out_size;

    dim3 blk(256);
    dim3 gQKV(DMODEL / 64, R / 64);
    // projections: qp->A, kp->B, vp->C
    sgemm<0><<<gQKV, blk, 0, stream>>>(hs, nullptr, DMODEL, DMODEL, 0, Wq, nullptr, nullptr, bufA, R, DMODEL, DMODEL);
    sgemm<0><<<gQKV, blk, 0, stream>>>(hs, nullptr, DMODEL, DMODEL, 0, Wk, nullptr, nullptr, bufB, R, DMODEL, DMODEL);
    sgemm<0><<<gQKV, blk, 0, stream>>>(hs, nullptr, DMODEL, DMODEL, 0, Wv, nullptr, nullptr, bufC, R, DMODEL, DMODEL);
    // beta = sigmoid(hs @ Wb)
    dim3 gB(1, R / 64);
    sgemm<1><<<gB, blk, 0, stream>>>(hs, nullptr, DMODEL, DMODEL, 0, Wb, nullptr, nullptr, beta, R, NHEAD, DMODEL);
    // short conv + silu (ping-pong): q: A->O, k: B->A, v: C->B
    int convGrid = (int)(((size_t)R * DMODEL + 255) / 256);
    shortconv<<<convGrid, blk, 0, stream>>>(bufA, cqw, bufO);
    shortconv<<<convGrid, blk, 0, stream>>>(bufB, ckw, bufA);
    shortconv<<<convGrid, blk, 0, stream>>>(bufC, cvw, bufB);
    // delta rule scan: q=O, k=A, v=B -> delta in C
    delta_scan<<<128, blk, 0, stream>>>(bufO, bufA, bufB, beta, ret, bufC);
    // stats (v=B, delta=C)
    dim3 gRH(R, NHEAD);
    fir_stats<<<gRH, dim3(128), 0, stream>>>(bufB, bufC, fsw, flw, stats);
    // gate MLP in two row-chunks of 8192; hdn chunk reuses bufA (k is dead)
    const int RC = 8192;
    float* hdn = bufA;
    for (int r0 = 0; r0 < R; r0 += RC) {
        dim3 gG1(2048 / 64, RC / 64);
        sgemm<2><<<gG1, blk, 0, stream>>>(hs + (size_t)r0 * DMODEL, stats + (size_t)r0 * 32,
                                          DMODEL, DMODEL, 32, gw1, gb1, nullptr,
                                          hdn, RC, 2048, 1056);
        dim3 gG2(1, RC / 64);
        sgemm<3><<<gG2, blk, 0, stream>>>(hdn, nullptr, 2048, 2048, 0, gw2, gb2, ltmp,
                                          pbuf + (size_t)r0 * 32, RC, 32, 2048);
    }
    // combine + RMS norm -> A (hdn is consumed)
    combine<<<gRH, dim3(128), 0, stream>>>(bufB, bufC, fsw, flw, pbuf, onw, bufA);
    // final projection: A @ Wo -> d_out
    sgemm<0><<<gQKV, blk, 0, stream>>>(bufA, nullptr, DMODEL, DMODEL, 0, Wo, nullptr, nullptr, out, R, DMODEL, DMODEL);
}

// Round 3
// 9865.450 us; speedup vs baseline: 1.7943x; 1.7943x over previous
//
#include <hip/hip_runtime.h>
#include <hip/hip_bf16.h>
#include <math.h>

#define R_TOT 16384      // B*L
#define LSEQ  4096
#define DMODEL 1024
#define NHEAD 8
#define DHEAD 128        // DK = DV
#define NCHUNK 128       // LSEQ/32

typedef __hip_bfloat16 bf16;

__device__ __forceinline__ float sigmoidf_(float x) { return 1.f / (1.f + expf(-x)); }

// ---------------------------------------------------------------------------
// Generic fp32 tiled GEMM (unchanged from round 2)
// MODE 0: none  1: sigmoid  2: gelu(x+bias)  3: p-gate
// ---------------------------------------------------------------------------
template<int MODE>
__global__ __launch_bounds__(256)
void sgemm(const float* __restrict__ A, const float* __restrict__ A2,
           int Ksplit, int lda1, int lda2,
           const float* __restrict__ Bm, const float* __restrict__ bias,
           const float* __restrict__ aux, float* __restrict__ C,
           int M, int N, int K)
{
    __shared__ float As[16][65];
    __shared__ float Bs[16][65];
    const int tid = threadIdx.x;
    const int m0 = blockIdx.y * 64, n0 = blockIdx.x * 64;
    const int tx = tid & 15, ty = tid >> 4;
    const int arow = tid >> 2, ak0 = (tid & 3) * 4;
    const int bcol = tid & 63, bk0 = (tid >> 6) * 4;
    float acc[4][4] = {};
    for (int k0 = 0; k0 < K; k0 += 16) {
#pragma unroll
        for (int i = 0; i < 4; ++i) {
            int kg = k0 + ak0 + i;
            int mg = m0 + arow;
            float v = 0.f;
            if (mg < M && kg < K)
                v = (kg < Ksplit) ? A[(size_t)mg * lda1 + kg]
                                  : A2[(size_t)mg * lda2 + (kg - Ksplit)];
            As[ak0 + i][arow] = v;
        }
#pragma unroll
        for (int i = 0; i < 4; ++i) {
            int kg = k0 + bk0 + i;
            int ng = n0 + bcol;
            float v = 0.f;
            if (kg < K && ng < N) v = Bm[(size_t)kg * N + ng];
            Bs[bk0 + i][bcol] = v;
        }
        __syncthreads();
#pragma unroll
        for (int kk = 0; kk < 16; ++kk) {
            float a[4], b[4];
#pragma unroll
            for (int i = 0; i < 4; ++i) a[i] = As[kk][ty * 4 + i];
#pragma unroll
            for (int j = 0; j < 4; ++j) b[j] = Bs[kk][tx * 4 + j];
#pragma unroll
            for (int i = 0; i < 4; ++i)
#pragma unroll
                for (int j = 0; j < 4; ++j) acc[i][j] = fmaf(a[i], b[j], acc[i][j]);
        }
        __syncthreads();
    }
#pragma unroll
    for (int i = 0; i < 4; ++i) {
        int row = m0 + ty * 4 + i;
        if (row >= M) continue;
#pragma unroll
        for (int j = 0; j < 4; ++j) {
            int col = n0 + tx * 4 + j;
            if (col >= N) continue;
            float x = acc[i][j];
            if (MODE == 1) {
                x = sigmoidf_(x);
            } else if (MODE == 2) {
                x += bias[col];
                x = 0.5f * x * (1.f + erff(x * 0.70710678118654752f));
            } else if (MODE == 3) {
                x += bias[col];
                x *= expf(-aux[col >> 2]);
                x = 0.02f + 0.98f * sigmoidf_(x);
            }
            C[(size_t)row * N + col] = x;
        }
    }
}

// ---------------------------------------------------------------------------
// Short causal conv (K=4) + SiLU.  OUT_BF16: write bf16 (for v), else fp32.
// ---------------------------------------------------------------------------
template<int OUT_BF16>
__global__ __launch_bounds__(256)
void shortconv(const float* __restrict__ x, const float* __restrict__ w,
               float* __restrict__ yf, bf16* __restrict__ yb)
{
    size_t idx = (size_t)blockIdx.x * 256 + threadIdx.x;
    if (idx >= (size_t)R_TOT * DMODEL) return;
    int c = (int)(idx & (DMODEL - 1));
    long r = (long)(idx >> 10);
    int l = (int)(r & (LSEQ - 1));
    const float* wc = w + c * 4;
    float acc = 0.f;
#pragma unroll
    for (int j = 0; j < 4; ++j) {
        int xl = l - 3 + j;
        if (xl >= 0) acc += x[(r - l + xl) * DMODEL + c] * wc[j];
    }
    float y = acc * sigmoidf_(acc);
    if (OUT_BF16) yb[idx] = __float2bfloat16(y);
    else          yf[idx] = y;
}

// ---------------------------------------------------------------------------
// Phase 1: per-(b,h,chunk) prep — fully parallel, 4096 blocks x 256 thr.
// Reads  : qconv (fp32, in bufO), kconv (fp32, in bufA), v (bf16), beta
// Writes : qe (fp32, in-place over bufO), kn (fp32, in-place over bufA),
//          w|u (bf16 tiles in bufC), o_pre (bf16, into delta slot)
// qe = qn - attn@w ;  o_pre = attn@u ;  so  o = qe@S + o_pre  (exact algebra)
// ---------------------------------------------------------------------------
__global__ __launch_bounds__(256)
void chunk_prep(const float* __restrict__ qconv, const float* __restrict__ kconv,
                const bf16* __restrict__ vbf, const float* __restrict__ beta,
                float* __restrict__ qe_out, float* __restrict__ kn_out,
                bf16* __restrict__ wu, bf16* __restrict__ opre)
{
    const int bid = blockIdx.x;              // (b*8+h)*128 + c
    const int c = bid & 127, h = (bid >> 7) & 7, b = bid >> 10;
    const int tid = threadIdx.x;

    __shared__ float qs[32][130], ks[32][130], vs[32][130], ws_l[32][130];
    __shared__ float Am[32][33], at[32][33];
    __shared__ float betas[32];

    const size_t row0 = (size_t)b * LSEQ + (size_t)c * 32;   // global row of chunk
    const size_t base = row0 * DMODEL + (size_t)h * DHEAD;

    // load q,k fp32; v bf16; beta
    for (int idx = tid; idx < 32 * 128; idx += 256) {
        int i = idx >> 7, d = idx & 127;
        size_t g = base + (size_t)i * DMODEL + d;
        qs[i][d] = qconv[g];
        ks[i][d] = kconv[g];
        vs[i][d] = __bfloat162float(vbf[g]);
    }
    if (tid < 32) betas[tid] = beta[(row0 + tid) * NHEAD + h];
    __syncthreads();

    // l2norm rows of q,k (eps 1e-6)
    {
        int row = tid >> 3, ln = tid & 7;
        float sq = 0.f, sk = 0.f;
        for (int d = ln; d < 128; d += 8) {
            float a_ = qs[row][d]; sq += a_ * a_;
            float b_ = ks[row][d]; sk += b_ * b_;
        }
#pragma unroll
        for (int m = 1; m < 8; m <<= 1) { sq += __shfl_xor(sq, m); sk += __shfl_xor(sk, m); }
        float rq = rsqrtf(sq + 1e-6f), rk = rsqrtf(sk + 1e-6f);
        for (int d = ln; d < 128; d += 8) { qs[row][d] *= rq; ks[row][d] *= rk; }
    }
    __syncthreads();

    // Am = tril(beta_i * kn_i . kn_j, -1) ; at = tril(qn_i . kn_j)  (incl diag)
    {
        int i0 = tid >> 5, j = tid & 31;
#pragma unroll
        for (int qd = 0; qd < 4; ++qd) {
            int i = i0 + qd * 8;
            float dk0 = 0.f, dk1 = 0.f, dq0 = 0.f, dq1 = 0.f;
#pragma unroll 8
            for (int d = 0; d < 128; d += 2) {
                float kj0 = ks[j][d], kj1 = ks[j][d + 1];
                dk0 += ks[i][d] * kj0; dk1 += ks[i][d + 1] * kj1;
                dq0 += qs[i][d] * kj0; dq1 += qs[i][d + 1] * kj1;
            }
            Am[i][j] = (i > j)  ? betas[i] * (dk0 + dk1) : 0.f;
            at[i][j] = (i >= j) ? (dq0 + dq1) : 0.f;
        }
    }
    __syncthreads();

    // forward substitution (I+A)x = rhs; thread t owns one column.
    // t<128: rhs = beta_i * v[i][t]  (-> u)   t>=128: rhs = beta_i * kn[i][t-128]  (-> w)
    {
        float x[32];
        int t = tid;
        if (t < 128) {
#pragma unroll
            for (int i = 0; i < 32; ++i) x[i] = betas[i] * vs[i][t];
        } else {
            int d = t - 128;
#pragma unroll
            for (int i = 0; i < 32; ++i) x[i] = betas[i] * ks[i][d];
        }
#pragma unroll
        for (int i = 1; i < 32; ++i) {
            float s = 0.f;
#pragma unroll
            for (int m = 0; m < i; ++m) s = fmaf(Am[i][m], x[m], s);
            x[i] -= s;
        }
        const size_t tb = (size_t)bid * 8192;   // tile base in wu (bf16 elems)
        if (t < 128) {
#pragma unroll
            for (int i = 0; i < 32; ++i) {
                wu[tb + 4096 + i * 128 + t] = __float2bfloat16(x[i]);  // u
                vs[i][t] = x[i];                                        // u into LDS
            }
        } else {
            int d = t - 128;
#pragma unroll
            for (int i = 0; i < 32; ++i) {
                wu[tb + i * 128 + d] = __float2bfloat16(x[i]);          // w
                ws_l[i][d] = x[i];
            }
        }
    }
    __syncthreads();

    // qe = qn - at @ w ; kn write-through ; o_pre = at @ u
    for (int idx = tid; idx < 4096; idx += 256) {
        int i = idx >> 7, d = idx & 127;
        float s = 0.f, s2 = 0.f;
#pragma unroll
        for (int j = 0; j < 32; ++j) {
            float a = at[i][j];
            s  = fmaf(a, ws_l[j][d], s);
            s2 = fmaf(a, vs[j][d], s2);
        }
        size_t g = base + (size_t)i * DMODEL + d;
        qe_out[g] = qs[i][d] - s;
        kn_out[g] = ks[i][d];
        opre[g] = __float2bfloat16(s2);
    }
}

// ---------------------------------------------------------------------------
// Phase 2: sequential state scan.  256 blocks = (b,h, dv-slice of 16) x 256 thr.
// Per chunk: u_adj = u - w@S ; o = qe@S + o_pre (write) ; S = lam*S + kn^T@u_adj
// S kept transposed in LDS: St[t][d].  Register prefetch of next chunk tiles.
// ---------------------------------------------------------------------------
__global__ __launch_bounds__(256)
void delta_scan2(const float* __restrict__ qe, const float* __restrict__ kn,
                 const bf16* __restrict__ wu, bf16* __restrict__ delta,
                 const float* __restrict__ ret)
{
    const int bid = blockIdx.x;           // (b*8+h)*8 + dvs
    const int dvs = bid & 7, bh = bid >> 3;
    const int h = bh & 7, b = bh >> 3;
    const int tid = threadIdx.x;

    __shared__ float qs[32][130], ks[32][130], ws[32][130];
    __shared__ float St[16][132];
    __shared__ float us[32][18], ua[32][18], ops[32][18];

    const float lam = 0.6f + 0.4f * sigmoidf_(ret[h]);

    for (int idx = tid; idx < 16 * 132; idx += 256) ((float*)St)[idx] = 0.f;

    // per-thread load geometry
    const int li = tid >> 3, ld0 = (tid & 7) * 16;   // full 32x128 tiles
    const int iu = tid >> 3, tu = (tid & 7) * 2;     // 32x16 slices
    const size_t headoff = (size_t)h * DHEAD;

    float4 pq[4], pk[4];
    uint4  pw[2];
    unsigned puv, pov;

#define ISSUE(cc)  {                                                                        \
        size_t rb = ((size_t)b * LSEQ + (size_t)(cc) * 32);                                 \
        const float* gq = qe + (rb + li) * DMODEL + headoff + ld0;                          \
        const float* gk = kn + (rb + li) * DMODEL + headoff + ld0;                          \
        pq[0] = ((const float4*)gq)[0]; pq[1] = ((const float4*)gq)[1];                     \
        pq[2] = ((const float4*)gq)[2]; pq[3] = ((const float4*)gq)[3];                     \
        pk[0] = ((const float4*)gk)[0]; pk[1] = ((const float4*)gk)[1];                     \
        pk[2] = ((const float4*)gk)[2]; pk[3] = ((const float4*)gk)[3];                     \
        size_t tb = ((size_t)bh * NCHUNK + (cc)) * 8192;                                    \
        const uint4* gw = (const uint4*)(wu + tb + li * 128 + ld0);                         \
        pw[0] = gw[0]; pw[1] = gw[1];                                                       \
        puv = *(const unsigned*)(wu + tb + 4096 + iu * 128 + dvs * 16 + tu);                \
        pov = *(const unsigned*)(delta + (rb + iu) * DMODEL + headoff + dvs * 16 + tu);     \
    }

    ISSUE(0);

    for (int c = 0; c < NCHUNK; ++c) {
        // unpack prefetched regs -> LDS
#pragma unroll
        for (int v4 = 0; v4 < 4; ++v4) {
            qs[li][ld0 + v4 * 4 + 0] = ((const float*)&pq[v4])[0];
            qs[li][ld0 + v4 * 4 + 1] = ((const float*)&pq[v4])[1];
            qs[li][ld0 + v4 * 4 + 2] = ((const float*)&pq[v4])[2];
            qs[li][ld0 + v4 * 4 + 3] = ((const float*)&pq[v4])[3];
            ks[li][ld0 + v4 * 4 + 0] = ((const float*)&pk[v4])[0];
            ks[li][ld0 + v4 * 4 + 1] = ((const float*)&pk[v4])[1];
            ks[li][ld0 + v4 * 4 + 2] = ((const float*)&pk[v4])[2];
            ks[li][ld0 + v4 * 4 + 3] = ((const float*)&pk[v4])[3];
        }
#pragma unroll
        for (int half = 0; half < 2; ++half) {
            const unsigned* pwu = (const unsigned*)&pw[half];
#pragma unroll
            for (int j = 0; j < 4; ++j) {
                unsigned u32 = pwu[j];
                ws[li][ld0 + half * 8 + j * 2 + 0] = __bfloat162float(*(const bf16*)&u32);
                unsigned hi = u32 >> 16;
                ws[li][ld0 + half * 8 + j * 2 + 1] = __bfloat162float(*(const bf16*)&hi);
            }
        }
        {
            unsigned lo = puv, hi = puv >> 16;
            us[iu][tu]     = __bfloat162float(*(const bf16*)&lo);
            us[iu][tu + 1] = __bfloat162float(*(const bf16*)&hi);
            unsigned lo2 = pov, hi2 = pov >> 16;
            ops[iu][tu]     = __bfloat162float(*(const bf16*)&lo2);
            ops[iu][tu + 1] = __bfloat162float(*(const bf16*)&hi2);
        }
        if (c + 1 < NCHUNK) ISSUE(c + 1);
        __syncthreads();

        // phase A: u_adj and o (both read OLD St)
        {
            const int t = tid & 15, i0 = tid >> 4;   // rows i0, i0+16
            float u0 = 0.f, u1 = 0.f, v0 = 0.f, v1 = 0.f;
            float o0 = 0.f, o1 = 0.f, p0 = 0.f, p1 = 0.f;
#pragma unroll 8
            for (int d = 0; d < 128; d += 2) {
                float s0 = St[t][d], s1 = St[t][d + 1];
                u0 = fmaf(ws[i0][d], s0, u0);      u1 = fmaf(ws[i0][d + 1], s1, u1);
                v0 = fmaf(ws[i0 + 16][d], s0, v0); v1 = fmaf(ws[i0 + 16][d + 1], s1, v1);
                o0 = fmaf(qs[i0][d], s0, o0);      o1 = fmaf(qs[i0][d + 1], s1, o1);
                p0 = fmaf(qs[i0 + 16][d], s0, p0); p1 = fmaf(qs[i0 + 16][d + 1], s1, p1);
            }
            float ua0 = us[i0][t] - (u0 + u1);
            float ua1 = us[i0 + 16][t] - (v0 + v1);
            ua[i0][t] = ua0;
            ua[i0 + 16][t] = ua1;
            size_t rb = ((size_t)b * LSEQ + (size_t)c * 32);
            delta[(rb + i0) * DMODEL + headoff + dvs * 16 + t] =
                __float2bfloat16(o0 + o1 + ops[i0][t]);
            delta[(rb + i0 + 16) * DMODEL + headoff + dvs * 16 + t] =
                __float2bfloat16(p0 + p1 + ops[i0 + 16][t]);
        }
        __syncthreads();

        // phase B: St[t][d] = lam*St[t][d] + sum_i kn[i][d]*ua[i][t]
        {
            const int d = tid & 127, t0 = tid >> 7;   // t = t0*8 + q
            float acc[8];
#pragma unroll
            for (int q = 0; q < 8; ++q) acc[q] = 0.f;
            for (int i = 0; i < 32; ++i) {
                float kd = ks[i][d];
#pragma unroll
                for (int q = 0; q < 8; ++q) acc[q] = fmaf(kd, ua[i][t0 * 8 + q], acc[q]);
            }
#pragma unroll
            for (int q = 0; q < 8; ++q) {
                int t = t0 * 8 + q;
                St[t][d] = lam * St[t][d] + acc[q];
            }
        }
        __syncthreads();
    }
#undef ISSUE
}

// ---------------------------------------------------------------------------
// FIR (recompute, bf16 v) + per-(b,l,h) means -> stats (R,32)
// ---------------------------------------------------------------------------
__global__ __launch_bounds__(128)
void fir_stats(const bf16* __restrict__ v, const bf16* __restrict__ dlt,
               const float* __restrict__ wshort, const float* __restrict__ wlong,
               float* __restrict__ stats)
{
    const int r = blockIdx.x, h = blockIdx.y, d = threadIdx.x;
    const int l = r & (LSEQ - 1);
    const size_t base = (size_t)r * DMODEL + h * DHEAD + d;
    const long rb = (long)(r - l);
    float vd = __bfloat162float(v[base]);
    const float* wsp = wshort + ((size_t)h * DHEAD + d) * 3;
    float fs = 0.f;
#pragma unroll
    for (int j = 0; j < 3; ++j) {
        int xl = l - 2 + j;
        if (xl >= 0) fs += __bfloat162float(v[(rb + xl) * DMODEL + h * DHEAD + d]) * wsp[j];
    }
    const float* wlp = wlong + ((size_t)h * DHEAD + d) * 63;
    float fl = 0.f;
    for (int j = 0; j < 63; ++j) {
        int xl = l - 62 + j;
        if (xl >= 0) fl += __bfloat162float(v[(rb + xl) * DMODEL + h * DHEAD + d]) * wlp[j];
    }
    float dl = __bfloat162float(dlt[base]);
    float v0 = fs, v1 = fl, v2 = dl, v3 = vd;
#pragma unroll
    for (int m = 1; m < 64; m <<= 1) {
        v0 += __shfl_xor(v0, m); v1 += __shfl_xor(v1, m);
        v2 += __shfl_xor(v2, m); v3 += __shfl_xor(v3, m);
    }
    __shared__ float red[2][4];
    int wv = d >> 6;
    if ((d & 63) == 0) { red[wv][0] = v0; red[wv][1] = v1; red[wv][2] = v2; red[wv][3] = v3; }
    __syncthreads();
    if (d == 0) {
        const float inv = 1.f / 128.f;
        stats[(size_t)r * 32 + 0  + h] = (red[0][0] + red[1][0]) * inv;
        stats[(size_t)r * 32 + 8  + h] = (red[0][1] + red[1][1]) * inv;
        stats[(size_t)r * 32 + 16 + h] = (red[0][2] + red[1][2]) * inv;
        stats[(size_t)r * 32 + 24 + h] = (red[0][3] + red[1][3]) * inv;
    }
}

// ---------------------------------------------------------------------------
// Combine + RMS norm (bf16 v/delta inputs), fp32 out
// ---------------------------------------------------------------------------
__global__ __launch_bounds__(128)
void combine(const bf16* __restrict__ v, const bf16* __restrict__ dlt,
             const float* __restrict__ wshort, const float* __restrict__ wlong,
             const float* __restrict__ p, const float* __restrict__ onw,
             float* __restrict__ on)
{
    const int r = blockIdx.x, h = blockIdx.y, d = threadIdx.x;
    const int l = r & (LSEQ - 1);
    const size_t base = (size_t)r * DMODEL + h * DHEAD + d;
    const long rb = (long)(r - l);
    float vd = __bfloat162float(v[base]);
    const float* wsp = wshort + ((size_t)h * DHEAD + d) * 3;
    float fs = 0.f;
#pragma unroll
    for (int j = 0; j < 3; ++j) {
        int xl = l - 2 + j;
        if (xl >= 0) fs += __bfloat162float(v[(rb + xl) * DMODEL + h * DHEAD + d]) * wsp[j];
    }
    const float* wlp = wlong + ((size_t)h * DHEAD + d) * 63;
    float fl = 0.f;
    for (int j = 0; j < 63; ++j) {
        int xl = l - 62 + j;
        if (xl >= 0) fl += __bfloat162float(v[(rb + xl) * DMODEL + h * DHEAD + d]) * wlp[j];
    }
    float dl = __bfloat162float(dlt[base]);
    const float* pp = p + (size_t)r * 32 + h * 4;
    float o = pp[0] * fs + pp[1] * fl + pp[2] * dl + pp[3] * vd;
    float ss = o * o;
#pragma unroll
    for (int m = 1; m < 64; m <<= 1) ss += __shfl_xor(ss, m);
    __shared__ float red[2];
    int wv = d >> 6;
    if ((d & 63) == 0) red[wv] = ss;
    __syncthreads();
    float tot = red[0] + red[1];
    on[base] = o * rsqrtf(tot * (1.f / 128.f) + 1e-5f) * onw[d];
}

// ---------------------------------------------------------------------------
// Buffers (192MB + ~4.5MB, same proven footprint):
//  bufA: k_pre -> kconv -> kn(in-place) -> o_normed
//  bufB: v_pre(k stage) ... lower 32MB v bf16 ; upper 32MB o_pre/delta bf16
//  bufC: v_pre -> w|u bf16 tiles -> hdn chunk (64MB)
//  d_out: q_pre -> qconv -> qe(in-place) -> final out
// ---------------------------------------------------------------------------
extern "C" void kernel_launch(void* const* d_in, const int* in_sizes, int n_in,
                              void* d_out, int out_size, void* d_ws, size_t ws_size,
                              hipStream_t stream)
{
    const float* hs   = (const float*)d_in[0];
    const float* Wq   = (const float*)d_in[1];
    const float* Wk   = (const float*)d_in[2];
    const float* Wv   = (const float*)d_in[3];
    const float* Wb   = (const float*)d_in[4];
    const float* cqw  = (const float*)d_in[5];
    const float* ckw  = (const float*)d_in[6];
    const float* cvw  = (const float*)d_in[7];
    const float* ret  = (const float*)d_in[8];
    const float* fsw  = (const float*)d_in[9];
    const float* flw  = (const float*)d_in[10];
    const float* gw1  = (const float*)d_in[11];
    const float* gb1  = (const float*)d_in[12];
    const float* gw2  = (const float*)d_in[13];
    const float* gb2  = (const float*)d_in[14];
    const float* ltmp = (const float*)d_in[15];
    const float* onw  = (const float*)d_in[16];
    const float* Wo   = (const float*)d_in[17];
    float* out = (float*)d_out;

    char* wsp = (char*)d_ws;
    size_t off = 0;
    auto alloc = [&](size_t nbytes) -> void* {
        void* pt = (void*)(wsp + off);
        off += ((nbytes + 255) / 256) * 256;
        return pt;
    };
    const int R = R_TOT;
    float* bufA  = (float*)alloc((size_t)R * DMODEL * 4);
    float* bufB  = (float*)alloc((size_t)R * DMODEL * 4);
    float* bufC  = (float*)alloc((size_t)R * DMODEL * 4);
    float* beta  = (float*)alloc((size_t)R * NHEAD * 4);
    float* stats = (float*)alloc((size_t)R * 32 * 4);
    float* pbuf  = (float*)alloc((size_t)R * 32 * 4);
    float* bufO  = out;
    bf16* vbf  = (bf16*)bufB;                       // lower 32MB
    bf16* dlt  = (bf16*)bufB + (size_t)R * DMODEL;  // upper 32MB (o_pre then delta)
    bf16* wu   = (bf16*)bufC;
    (void)ws_size; (void)in_sizes; (void)n_in; (void)out_size;

    dim3 blk(256);
    dim3 gQKV(DMODEL / 64, R / 64);
    sgemm<0><<<gQKV, blk, 0, stream>>>(hs, nullptr, DMODEL, DMODEL, 0, Wq, nullptr, nullptr, bufA, R, DMODEL, DMODEL);
    sgemm<0><<<gQKV, blk, 0, stream>>>(hs, nullptr, DMODEL, DMODEL, 0, Wk, nullptr, nullptr, bufB, R, DMODEL, DMODEL);
    sgemm<0><<<gQKV, blk, 0, stream>>>(hs, nullptr, DMODEL, DMODEL, 0, Wv, nullptr, nullptr, bufC, R, DMODEL, DMODEL);
    dim3 gB(1, R / 64);
    sgemm<1><<<gB, blk, 0, stream>>>(hs, nullptr, DMODEL, DMODEL, 0, Wb, nullptr, nullptr, beta, R, NHEAD, DMODEL);

    int convGrid = (int)(((size_t)R * DMODEL + 255) / 256);
    shortconv<0><<<convGrid, blk, 0, stream>>>(bufA, cqw, bufO, nullptr);   // q fp32 -> bufO
    shortconv<0><<<convGrid, blk, 0, stream>>>(bufB, ckw, bufA, nullptr);   // k fp32 -> bufA
    shortconv<1><<<convGrid, blk, 0, stream>>>(bufC, cvw, nullptr, vbf);    // v bf16 -> bufB lower

    // phase 1: parallel chunk prep (4096 blocks)
    chunk_prep<<<4096, blk, 0, stream>>>(bufO, bufA, vbf, beta, bufO, bufA, wu, dlt);
    // phase 2: sequential scan (256 blocks)
    delta_scan2<<<256, blk, 0, stream>>>(bufO, bufA, wu, dlt, ret);

    dim3 gRH(R, NHEAD);
    fir_stats<<<gRH, dim3(128), 0, stream>>>(vbf, dlt, fsw, flw, stats);

    // gate MLP in two row-chunks of 8192; hdn reuses bufC (w/u dead)
    const int RC = 8192;
    float* hdn = bufC;
    for (int r0 = 0; r0 < R; r0 += RC) {
        dim3 gG1(2048 / 64, RC / 64);
        sgemm<2><<<gG1, blk, 0, stream>>>(hs + (size_t)r0 * DMODEL, stats + (size_t)r0 * 32,
                                          DMODEL, DMODEL, 32, gw1, gb1, nullptr,
                                          hdn, RC, 2048, 1056);
        dim3 gG2(1, RC / 64);
        sgemm<3><<<gG2, blk, 0, stream>>>(hdn, nullptr, 2048, 2048, 0, gw2, gb2, ltmp,
                                          pbuf + (size_t)r0 * 32, RC, 32, 2048);
    }
    combine<<<gRH, dim3(128), 0, stream>>>(vbf, dlt, fsw, flw, pbuf, onw, bufA);
    sgemm<0><<<gQKV, blk, 0, stream>>>(bufA, nullptr, DMODEL, DMODEL, 0, Wo, nullptr, nullptr, out, R, DMODEL, DMODEL);
}

// Round 4
// 2615.785 us; speedup vs baseline: 6.7672x; 3.7715x over previous
//
#include <hip/hip_runtime.h>
#include <hip/hip_bf16.h>
#include <math.h>

#define R_TOT 16384      // B*L
#define LSEQ  4096
#define DMODEL 1024
#define NHEAD 8
#define DHEAD 128        // DK = DV
#define NCHUNK 128       // LSEQ/32

typedef __hip_bfloat16 bf16;
typedef short s8v __attribute__((ext_vector_type(8)));
typedef float f4v __attribute__((ext_vector_type(4)));

__device__ __forceinline__ float sigmoidf_(float x) { return 1.f / (1.f + expf(-x)); }
__device__ __forceinline__ unsigned short f2bf(float f) {
    unsigned u = __float_as_uint(f);
    u += 0x7fffu + ((u >> 16) & 1u);
    return (unsigned short)(u >> 16);
}
__device__ __forceinline__ float bf2f(unsigned short s) {
    return __uint_as_float(((unsigned)s) << 16);
}

// ---------------------------------------------------------------------------
// Transpose-cast: W (K x N fp32, row-major) -> Wt (N x K bf16, row-major)
// ---------------------------------------------------------------------------
__global__ __launch_bounds__(256)
void tcast(const float* __restrict__ W, unsigned short* __restrict__ Wt, int K, int N)
{
    __shared__ float t[32][33];
    const int kb = blockIdx.x * 32, nb = blockIdx.y * 32;
    const int tx = threadIdx.x & 31, ty = threadIdx.x >> 5;   // ty 0..7
    for (int i = ty; i < 32; i += 8) {
        int k = kb + i, n = nb + tx;
        t[i][tx] = (k < K && n < N) ? W[(size_t)k * N + n] : 0.f;
    }
    __syncthreads();
    for (int i = ty; i < 32; i += 8) {
        int n = nb + i, k = kb + tx;
        if (n < N && k < K) Wt[(size_t)n * K + k] = f2bf(t[tx][i]);
    }
}

// ---------------------------------------------------------------------------
// MFMA bf16 GEMM: C = epi(A @ Bt^T), A fp32 MxK (split A/A2 at Ksplit,
// tile-aligned), Bt = bf16 N x K row-major (i.e. B pre-transposed).
// Tile 128x128x32, 256 thr = 4 waves (2x2 of 64x64).
// MODE 0: none   2: gelu(x+bias)   4: qkv split (col/1024 -> C0/C1/C2)
// M,N,K must be multiples of 128/128/32.
// ---------------------------------------------------------------------------
template<int MODE>
__global__ __launch_bounds__(256)
void mgemm(const float* __restrict__ A, const float* __restrict__ A2, int Ksplit,
           int lda1, int lda2,
           const unsigned short* __restrict__ Bt,
           const float* __restrict__ bias,
           float* __restrict__ C0, float* __restrict__ C1, float* __restrict__ C2,
           int M, int N, int K)
{
    __shared__ unsigned short As[128 * 40];   // stride 40 (pad) -> 2-way max
    __shared__ unsigned short Bs[128 * 40];
    const int tid = threadIdx.x;
    const int m0 = blockIdx.y * 128, n0 = blockIdx.x * 128;
    const int l = tid & 63;
    const int wr = (tid >> 7) & 1, wc = (tid >> 6) & 1;
    const int sr = tid >> 1, sh = (tid & 1) * 16;

    const f4v zf = {0.f, 0.f, 0.f, 0.f};
    f4v acc[4][4];
#pragma unroll
    for (int i = 0; i < 4; ++i)
#pragma unroll
        for (int j = 0; j < 4; ++j) acc[i][j] = zf;

    const int nkt = K >> 5;
    for (int kt = 0; kt < nkt; ++kt) {
        const int k0 = kt << 5;
        {   // stage A: 16 fp32 -> 16 bf16
            const float* src = (k0 < Ksplit)
                ? A  + (size_t)(m0 + sr) * lda1 + (size_t)(k0 + sh)
                : A2 + (size_t)(m0 + sr) * lda2 + (size_t)(k0 - Ksplit + sh);
            float4 v0 = ((const float4*)src)[0];
            float4 v1 = ((const float4*)src)[1];
            float4 v2 = ((const float4*)src)[2];
            float4 v3 = ((const float4*)src)[3];
            s8v w0, w1;
            w0[0] = (short)f2bf(v0.x); w0[1] = (short)f2bf(v0.y);
            w0[2] = (short)f2bf(v0.z); w0[3] = (short)f2bf(v0.w);
            w0[4] = (short)f2bf(v1.x); w0[5] = (short)f2bf(v1.y);
            w0[6] = (short)f2bf(v1.z); w0[7] = (short)f2bf(v1.w);
            w1[0] = (short)f2bf(v2.x); w1[1] = (short)f2bf(v2.y);
            w1[2] = (short)f2bf(v2.z); w1[3] = (short)f2bf(v2.w);
            w1[4] = (short)f2bf(v3.x); w1[5] = (short)f2bf(v3.y);
            w1[6] = (short)f2bf(v3.z); w1[7] = (short)f2bf(v3.w);
            *(s8v*)&As[sr * 40 + sh]     = w0;
            *(s8v*)&As[sr * 40 + sh + 8] = w1;
        }
        {   // stage B: straight bf16 copy (Bt row = output col, k contiguous)
            const unsigned short* src = Bt + (size_t)(n0 + sr) * K + (size_t)(k0 + sh);
            s8v b0 = ((const s8v*)src)[0];
            s8v b1 = ((const s8v*)src)[1];
            *(s8v*)&Bs[sr * 40 + sh]     = b0;
            *(s8v*)&Bs[sr * 40 + sh + 8] = b1;
        }
        __syncthreads();
        const int fr = l & 15, fq = (l >> 4) * 8;
        s8v af[4], bfr[4];
#pragma unroll
        for (int i = 0; i < 4; ++i) {
            af[i]  = *(const s8v*)&As[(wr * 64 + i * 16 + fr) * 40 + fq];
            bfr[i] = *(const s8v*)&Bs[(wc * 64 + i * 16 + fr) * 40 + fq];
        }
#pragma unroll
        for (int i = 0; i < 4; ++i)
#pragma unroll
            for (int j = 0; j < 4; ++j)
                acc[i][j] = __builtin_amdgcn_mfma_f32_16x16x32_bf16(af[i], bfr[j], acc[i][j], 0, 0, 0);
        __syncthreads();
    }
    // epilogue: D lane map col=l&15, row=(l>>4)*4+q   [m89-verified]
    const int fr = l & 15, fq4 = (l >> 4) * 4;
#pragma unroll
    for (int i = 0; i < 4; ++i) {
#pragma unroll
        for (int j = 0; j < 4; ++j) {
#pragma unroll
            for (int q = 0; q < 4; ++q) {
                int row = m0 + wr * 64 + i * 16 + fq4 + q;
                int col = n0 + wc * 64 + j * 16 + fr;
                float x = acc[i][j][q];
                if (MODE == 2) {
                    x += bias[col];
                    x = 0.5f * x * (1.f + erff(x * 0.70710678118654752f));
                }
                if (MODE == 4) {
                    float* dst = (col < 1024) ? C0 : ((col < 2048) ? C1 : C2);
                    dst[(size_t)row * 1024 + (col & 1023)] = x;
                } else {
                    C0[(size_t)row * N + col] = x;
                }
            }
        }
    }
}

// ---------------------------------------------------------------------------
// fp32 tiled GEMM (kept for small-N: beta N=8, gate2 N=32)
// MODE 1: sigmoid   3: p-gate (bias, /exp(log_temp), eps+sigmoid)
// ---------------------------------------------------------------------------
template<int MODE>
__global__ __launch_bounds__(256)
void sgemm(const float* __restrict__ A, const float* __restrict__ A2,
           int Ksplit, int lda1, int lda2,
           const float* __restrict__ Bm, const float* __restrict__ bias,
           const float* __restrict__ aux, float* __restrict__ C,
           int M, int N, int K)
{
    __shared__ float As[16][65];
    __shared__ float Bs[16][65];
    const int tid = threadIdx.x;
    const int m0 = blockIdx.y * 64, n0 = blockIdx.x * 64;
    const int tx = tid & 15, ty = tid >> 4;
    const int arow = tid >> 2, ak0 = (tid & 3) * 4;
    const int bcol = tid & 63, bk0 = (tid >> 6) * 4;
    float acc[4][4] = {};
    for (int k0 = 0; k0 < K; k0 += 16) {
#pragma unroll
        for (int i = 0; i < 4; ++i) {
            int kg = k0 + ak0 + i;
            int mg = m0 + arow;
            float v = 0.f;
            if (mg < M && kg < K)
                v = (kg < Ksplit) ? A[(size_t)mg * lda1 + kg]
                                  : A2[(size_t)mg * lda2 + (kg - Ksplit)];
            As[ak0 + i][arow] = v;
        }
#pragma unroll
        for (int i = 0; i < 4; ++i) {
            int kg = k0 + bk0 + i;
            int ng = n0 + bcol;
            float v = 0.f;
            if (kg < K && ng < N) v = Bm[(size_t)kg * N + ng];
            Bs[bk0 + i][bcol] = v;
        }
        __syncthreads();
#pragma unroll
        for (int kk = 0; kk < 16; ++kk) {
            float a[4], b[4];
#pragma unroll
            for (int i = 0; i < 4; ++i) a[i] = As[kk][ty * 4 + i];
#pragma unroll
            for (int j = 0; j < 4; ++j) b[j] = Bs[kk][tx * 4 + j];
#pragma unroll
            for (int i = 0; i < 4; ++i)
#pragma unroll
                for (int j = 0; j < 4; ++j) acc[i][j] = fmaf(a[i], b[j], acc[i][j]);
        }
        __syncthreads();
    }
#pragma unroll
    for (int i = 0; i < 4; ++i) {
        int row = m0 + ty * 4 + i;
        if (row >= M) continue;
#pragma unroll
        for (int j = 0; j < 4; ++j) {
            int col = n0 + tx * 4 + j;
            if (col >= N) continue;
            float x = acc[i][j];
            if (MODE == 1) {
                x = sigmoidf_(x);
            } else if (MODE == 3) {
                x += bias[col];
                x *= expf(-aux[col >> 2]);
                x = 0.02f + 0.98f * sigmoidf_(x);
            }
            C[(size_t)row * N + col] = x;
        }
    }
}

// ---------------------------------------------------------------------------
// Short causal conv (K=4) + SiLU.
// ---------------------------------------------------------------------------
template<int OUT_BF16>
__global__ __launch_bounds__(256)
void shortconv(const float* __restrict__ x, const float* __restrict__ w,
               float* __restrict__ yf, bf16* __restrict__ yb)
{
    size_t idx = (size_t)blockIdx.x * 256 + threadIdx.x;
    if (idx >= (size_t)R_TOT * DMODEL) return;
    int c = (int)(idx & (DMODEL - 1));
    long r = (long)(idx >> 10);
    int l = (int)(r & (LSEQ - 1));
    const float* wc = w + c * 4;
    float acc = 0.f;
#pragma unroll
    for (int j = 0; j < 4; ++j) {
        int xl = l - 3 + j;
        if (xl >= 0) acc += x[(r - l + xl) * DMODEL + c] * wc[j];
    }
    float y = acc * sigmoidf_(acc);
    if (OUT_BF16) yb[idx] = __float2bfloat16(y);
    else          yf[idx] = y;
}

// ---------------------------------------------------------------------------
// Phase 1: per-(b,h,chunk) prep (unchanged, round-3 verified)
// ---------------------------------------------------------------------------
__global__ __launch_bounds__(256)
void chunk_prep(const float* __restrict__ qconv, const float* __restrict__ kconv,
                const bf16* __restrict__ vbf, const float* __restrict__ beta,
                float* __restrict__ qe_out, float* __restrict__ kn_out,
                bf16* __restrict__ wu, bf16* __restrict__ opre)
{
    const int bid = blockIdx.x;              // (b*8+h)*128 + c
    const int c = bid & 127, h = (bid >> 7) & 7, b = bid >> 10;
    const int tid = threadIdx.x;

    __shared__ float qs[32][130], ks[32][130], vs[32][130], ws_l[32][130];
    __shared__ float Am[32][33], at[32][33];
    __shared__ float betas[32];

    const size_t row0 = (size_t)b * LSEQ + (size_t)c * 32;
    const size_t base = row0 * DMODEL + (size_t)h * DHEAD;

    for (int idx = tid; idx < 32 * 128; idx += 256) {
        int i = idx >> 7, d = idx & 127;
        size_t g = base + (size_t)i * DMODEL + d;
        qs[i][d] = qconv[g];
        ks[i][d] = kconv[g];
        vs[i][d] = __bfloat162float(vbf[g]);
    }
    if (tid < 32) betas[tid] = beta[(row0 + tid) * NHEAD + h];
    __syncthreads();

    {
        int row = tid >> 3, ln = tid & 7;
        float sq = 0.f, sk = 0.f;
        for (int d = ln; d < 128; d += 8) {
            float a_ = qs[row][d]; sq += a_ * a_;
            float b_ = ks[row][d]; sk += b_ * b_;
        }
#pragma unroll
        for (int m = 1; m < 8; m <<= 1) { sq += __shfl_xor(sq, m); sk += __shfl_xor(sk, m); }
        float rq = rsqrtf(sq + 1e-6f), rk = rsqrtf(sk + 1e-6f);
        for (int d = ln; d < 128; d += 8) { qs[row][d] *= rq; ks[row][d] *= rk; }
    }
    __syncthreads();

    {
        int i0 = tid >> 5, j = tid & 31;
#pragma unroll
        for (int qd = 0; qd < 4; ++qd) {
            int i = i0 + qd * 8;
            float dk0 = 0.f, dk1 = 0.f, dq0 = 0.f, dq1 = 0.f;
#pragma unroll 8
            for (int d = 0; d < 128; d += 2) {
                float kj0 = ks[j][d], kj1 = ks[j][d + 1];
                dk0 += ks[i][d] * kj0; dk1 += ks[i][d + 1] * kj1;
                dq0 += qs[i][d] * kj0; dq1 += qs[i][d + 1] * kj1;
            }
            Am[i][j] = (i > j)  ? betas[i] * (dk0 + dk1) : 0.f;
            at[i][j] = (i >= j) ? (dq0 + dq1) : 0.f;
        }
    }
    __syncthreads();

    {
        float x[32];
        int t = tid;
        if (t < 128) {
#pragma unroll
            for (int i = 0; i < 32; ++i) x[i] = betas[i] * vs[i][t];
        } else {
            int d = t - 128;
#pragma unroll
            for (int i = 0; i < 32; ++i) x[i] = betas[i] * ks[i][d];
        }
#pragma unroll
        for (int i = 1; i < 32; ++i) {
            float s = 0.f;
#pragma unroll
            for (int m = 0; m < i; ++m) s = fmaf(Am[i][m], x[m], s);
            x[i] -= s;
        }
        const size_t tb = (size_t)bid * 8192;
        if (t < 128) {
#pragma unroll
            for (int i = 0; i < 32; ++i) {
                wu[tb + 4096 + i * 128 + t] = __float2bfloat16(x[i]);  // u
                vs[i][t] = x[i];
            }
        } else {
            int d = t - 128;
#pragma unroll
            for (int i = 0; i < 32; ++i) {
                wu[tb + i * 128 + d] = __float2bfloat16(x[i]);          // w
                ws_l[i][d] = x[i];
            }
        }
    }
    __syncthreads();

    for (int idx = tid; idx < 4096; idx += 256) {
        int i = idx >> 7, d = idx & 127;
        float s = 0.f, s2 = 0.f;
#pragma unroll
        for (int j = 0; j < 32; ++j) {
            float a = at[i][j];
            s  = fmaf(a, ws_l[j][d], s);
            s2 = fmaf(a, vs[j][d], s2);
        }
        size_t g = base + (size_t)i * DMODEL + d;
        qe_out[g] = qs[i][d] - s;
        kn_out[g] = ks[i][d];
        opre[g] = __float2bfloat16(s2);
    }
}

// ---------------------------------------------------------------------------
// Phase 2: sequential state scan (unchanged, round-3 verified)
// ---------------------------------------------------------------------------
__global__ __launch_bounds__(256)
void delta_scan2(const float* __restrict__ qe, const float* __restrict__ kn,
                 const bf16* __restrict__ wu, bf16* __restrict__ delta,
                 const float* __restrict__ ret)
{
    const int bid = blockIdx.x;           // (b*8+h)*8 + dvs
    const int dvs = bid & 7, bh = bid >> 3;
    const int h = bh & 7, b = bh >> 3;
    const int tid = threadIdx.x;

    __shared__ float qs[32][130], ks[32][130], ws[32][130];
    __shared__ float St[16][132];
    __shared__ float us[32][18], ua[32][18], ops[32][18];

    const float lam = 0.6f + 0.4f * sigmoidf_(ret[h]);

    for (int idx = tid; idx < 16 * 132; idx += 256) ((float*)St)[idx] = 0.f;

    const int li = tid >> 3, ld0 = (tid & 7) * 16;
    const int iu = tid >> 3, tu = (tid & 7) * 2;
    const size_t headoff = (size_t)h * DHEAD;

    float4 pq[4], pk[4];
    uint4  pw[2];
    unsigned puv, pov;

#define ISSUE(cc)  {                                                                        \
        size_t rb = ((size_t)b * LSEQ + (size_t)(cc) * 32);                                 \
        const float* gq = qe + (rb + li) * DMODEL + headoff + ld0;                          \
        const float* gk = kn + (rb + li) * DMODEL + headoff + ld0;                          \
        pq[0] = ((const float4*)gq)[0]; pq[1] = ((const float4*)gq)[1];                     \
        pq[2] = ((const float4*)gq)[2]; pq[3] = ((const float4*)gq)[3];                     \
        pk[0] = ((const float4*)gk)[0]; pk[1] = ((const float4*)gk)[1];                     \
        pk[2] = ((const float4*)gk)[2]; pk[3] = ((const float4*)gk)[3];                     \
        size_t tb = ((size_t)bh * NCHUNK + (cc)) * 8192;                                    \
        const uint4* gw = (const uint4*)(wu + tb + li * 128 + ld0);                         \
        pw[0] = gw[0]; pw[1] = gw[1];                                                       \
        puv = *(const unsigned*)(wu + tb + 4096 + iu * 128 + dvs * 16 + tu);                \
        pov = *(const unsigned*)(delta + (rb + iu) * DMODEL + headoff + dvs * 16 + tu);     \
    }

    ISSUE(0);

    for (int c = 0; c < NCHUNK; ++c) {
#pragma unroll
        for (int v4 = 0; v4 < 4; ++v4) {
            qs[li][ld0 + v4 * 4 + 0] = ((const float*)&pq[v4])[0];
            qs[li][ld0 + v4 * 4 + 1] = ((const float*)&pq[v4])[1];
            qs[li][ld0 + v4 * 4 + 2] = ((const float*)&pq[v4])[2];
            qs[li][ld0 + v4 * 4 + 3] = ((const float*)&pq[v4])[3];
            ks[li][ld0 + v4 * 4 + 0] = ((const float*)&pk[v4])[0];
            ks[li][ld0 + v4 * 4 + 1] = ((const float*)&pk[v4])[1];
            ks[li][ld0 + v4 * 4 + 2] = ((const float*)&pk[v4])[2];
            ks[li][ld0 + v4 * 4 + 3] = ((const float*)&pk[v4])[3];
        }
#pragma unroll
        for (int half = 0; half < 2; ++half) {
            const unsigned* pwu = (const unsigned*)&pw[half];
#pragma unroll
            for (int j = 0; j < 4; ++j) {
                unsigned u32 = pwu[j];
                ws[li][ld0 + half * 8 + j * 2 + 0] = __bfloat162float(*(const bf16*)&u32);
                unsigned hi = u32 >> 16;
                ws[li][ld0 + half * 8 + j * 2 + 1] = __bfloat162float(*(const bf16*)&hi);
            }
        }
        {
            unsigned lo = puv, hi = puv >> 16;
            us[iu][tu]     = __bfloat162float(*(const bf16*)&lo);
            us[iu][tu + 1] = __bfloat162float(*(const bf16*)&hi);
            unsigned lo2 = pov, hi2 = pov >> 16;
            ops[iu][tu]     = __bfloat162float(*(const bf16*)&lo2);
            ops[iu][tu + 1] = __bfloat162float(*(const bf16*)&hi2);
        }
        if (c + 1 < NCHUNK) ISSUE(c + 1);
        __syncthreads();

        {
            const int t = tid & 15, i0 = tid >> 4;
            float u0 = 0.f, u1 = 0.f, v0 = 0.f, v1 = 0.f;
            float o0 = 0.f, o1 = 0.f, p0 = 0.f, p1 = 0.f;
#pragma unroll 8
            for (int d = 0; d < 128; d += 2) {
                float s0 = St[t][d], s1 = St[t][d + 1];
                u0 = fmaf(ws[i0][d], s0, u0);      u1 = fmaf(ws[i0][d + 1], s1, u1);
                v0 = fmaf(ws[i0 + 16][d], s0, v0); v1 = fmaf(ws[i0 + 16][d + 1], s1, v1);
                o0 = fmaf(qs[i0][d], s0, o0);      o1 = fmaf(qs[i0][d + 1], s1, o1);
                p0 = fmaf(qs[i0 + 16][d], s0, p0); p1 = fmaf(qs[i0 + 16][d + 1], s1, p1);
            }
            float ua0 = us[i0][t] - (u0 + u1);
            float ua1 = us[i0 + 16][t] - (v0 + v1);
            ua[i0][t] = ua0;
            ua[i0 + 16][t] = ua1;
            size_t rb = ((size_t)b * LSEQ + (size_t)c * 32);
            delta[(rb + i0) * DMODEL + headoff + dvs * 16 + t] =
                __float2bfloat16(o0 + o1 + ops[i0][t]);
            delta[(rb + i0 + 16) * DMODEL + headoff + dvs * 16 + t] =
                __float2bfloat16(p0 + p1 + ops[i0 + 16][t]);
        }
        __syncthreads();

        {
            const int d = tid & 127, t0 = tid >> 7;
            float acc[8];
#pragma unroll
            for (int q = 0; q < 8; ++q) acc[q] = 0.f;
            for (int i = 0; i < 32; ++i) {
                float kd = ks[i][d];
#pragma unroll
                for (int q = 0; q < 8; ++q) acc[q] = fmaf(kd, ua[i][t0 * 8 + q], acc[q]);
            }
#pragma unroll
            for (int q = 0; q < 8; ++q) {
                int t = t0 * 8 + q;
                St[t][d] = lam * St[t][d] + acc[q];
            }
        }
        __syncthreads();
    }
#undef ISSUE
}

// ---------------------------------------------------------------------------
// FIR computed ONCE, LDS-tiled. Block = (l-tile 128, h, b); 256 thr.
// v bf16 (R,1024) -> fs, fl bf16 (R,1024).
// ---------------------------------------------------------------------------
__global__ __launch_bounds__(256)
void fir_compute(const unsigned short* __restrict__ v,
                 const float* __restrict__ wshort, const float* __restrict__ wlong,
                 unsigned short* __restrict__ fso, unsigned short* __restrict__ flo)
{
    const int lt = blockIdx.x, h = blockIdx.y, b = blockIdx.z;
    const int tid = threadIdx.x;
    __shared__ unsigned short vt[190 * 128];
    __shared__ float wl[63 * 128];
    __shared__ float w3[3 * 128];

    for (int i = tid; i < 63 * 128; i += 256) {
        int j = i >> 7, d = i & 127;
        wl[i] = wlong[((size_t)h * 128 + d) * 63 + j];
    }
    for (int i = tid; i < 3 * 128; i += 256) {
        int j = i >> 7, d = i & 127;
        w3[i] = wshort[((size_t)h * 128 + d) * 3 + j];
    }
    const size_t vbase = ((size_t)b * LSEQ) * DMODEL + (size_t)h * DHEAD;
    const int l0 = lt * 128;
    const s8v z8 = {0, 0, 0, 0, 0, 0, 0, 0};
    for (int i = tid; i < 190 * 16; i += 256) {
        int row = i >> 4, dblk = (i & 15) * 8;
        int gl = l0 - 62 + row;
        s8v val = z8;
        if (gl >= 0) val = *(const s8v*)&v[vbase + (size_t)gl * DMODEL + dblk];
        *(s8v*)&vt[row * 128 + dblk] = val;
    }
    __syncthreads();

    const int dp = (tid & 63) * 2, lg = tid >> 6;
    for (int lc = 0; lc < 4; ++lc) {
        const int lb = lg * 32 + lc * 8;
        float a0[8], a1[8], s0[8], s1[8];
#pragma unroll
        for (int li = 0; li < 8; ++li) { a0[li] = a1[li] = s0[li] = s1[li] = 0.f; }
        for (int j = 0; j < 63; ++j) {
            float w0 = wl[j * 128 + dp], w1 = wl[j * 128 + dp + 1];
#pragma unroll
            for (int li = 0; li < 8; ++li) {
                unsigned vv = *(const unsigned*)&vt[(lb + li + j) * 128 + dp];
                a0[li] = fmaf(bf2f((unsigned short)vv), w0, a0[li]);
                a1[li] = fmaf(bf2f((unsigned short)(vv >> 16)), w1, a1[li]);
            }
        }
#pragma unroll
        for (int j = 0; j < 3; ++j) {
            float w0 = w3[j * 128 + dp], w1 = w3[j * 128 + dp + 1];
#pragma unroll
            for (int li = 0; li < 8; ++li) {
                unsigned vv = *(const unsigned*)&vt[(lb + li + 60 + j) * 128 + dp];
                s0[li] = fmaf(bf2f((unsigned short)vv), w0, s0[li]);
                s1[li] = fmaf(bf2f((unsigned short)(vv >> 16)), w1, s1[li]);
            }
        }
        const size_t ob = ((size_t)b * LSEQ + l0) * DMODEL + (size_t)h * DHEAD + dp;
#pragma unroll
        for (int li = 0; li < 8; ++li) {
            unsigned pf = (unsigned)f2bf(a0[li]) | ((unsigned)f2bf(a1[li]) << 16);
            unsigned ps = (unsigned)f2bf(s0[li]) | ((unsigned)f2bf(s1[li]) << 16);
            *(unsigned*)&flo[ob + (size_t)(lb + li) * DMODEL] = pf;
            *(unsigned*)&fso[ob + (size_t)(lb + li) * DMODEL] = ps;
        }
    }
}

// ---------------------------------------------------------------------------
// Stats: one wave per (r,h) row; means of fs, fl, delta, v over d=128.
// ---------------------------------------------------------------------------
__global__ __launch_bounds__(256)
void fir_stats2(const unsigned short* __restrict__ fs, const unsigned short* __restrict__ fl,
                const unsigned short* __restrict__ dlt, const unsigned short* __restrict__ v,
                float* __restrict__ stats)
{
    const int rh = blockIdx.x * 4 + (threadIdx.x >> 6);
    const int lane = threadIdx.x & 63;
    const int r = rh >> 3, h = rh & 7;
    const size_t base = (size_t)r * DMODEL + (size_t)h * DHEAD + lane * 2;
    unsigned ua = *(const unsigned*)(fs + base);
    unsigned ub = *(const unsigned*)(fl + base);
    unsigned uc = *(const unsigned*)(dlt + base);
    unsigned ud = *(const unsigned*)(v + base);
    float s0 = bf2f((unsigned short)ua) + bf2f((unsigned short)(ua >> 16));
    float s1 = bf2f((unsigned short)ub) + bf2f((unsigned short)(ub >> 16));
    float s2 = bf2f((unsigned short)uc) + bf2f((unsigned short)(uc >> 16));
    float s3 = bf2f((unsigned short)ud) + bf2f((unsigned short)(ud >> 16));
#pragma unroll
    for (int m = 1; m < 64; m <<= 1) {
        s0 += __shfl_xor(s0, m); s1 += __shfl_xor(s1, m);
        s2 += __shfl_xor(s2, m); s3 += __shfl_xor(s3, m);
    }
    if (lane == 0) {
        const float inv = 1.f / 128.f;
        stats[(size_t)r * 32 + 0  + h] = s0 * inv;
        stats[(size_t)r * 32 + 8  + h] = s1 * inv;
        stats[(size_t)r * 32 + 16 + h] = s2 * inv;
        stats[(size_t)r * 32 + 24 + h] = s3 * inv;
    }
}

// ---------------------------------------------------------------------------
// Combine + RMS norm: one wave per (r,h); fp32 out (feeds final MFMA GEMM).
// ---------------------------------------------------------------------------
__global__ __launch_bounds__(256)
void combine2(const unsigned short* __restrict__ fs, const unsigned short* __restrict__ fl,
              const unsigned short* __restrict__ dlt, const unsigned short* __restrict__ v,
              const float* __restrict__ p, const float* __restrict__ onw,
              float* __restrict__ on)
{
    const int rh = blockIdx.x * 4 + (threadIdx.x >> 6);
    const int lane = threadIdx.x & 63;
    const int r = rh >> 3, h = rh & 7;
    const size_t base = (size_t)r * DMODEL + (size_t)h * DHEAD + lane * 2;
    unsigned ua = *(const unsigned*)(fs + base);
    unsigned ub = *(const unsigned*)(fl + base);
    unsigned uc = *(const unsigned*)(dlt + base);
    unsigned ud = *(const unsigned*)(v + base);
    const float* pp = p + (size_t)r * 32 + h * 4;
    float p0 = pp[0], p1 = pp[1], p2 = pp[2], p3 = pp[3];
    float ox = p0 * bf2f((unsigned short)ua) + p1 * bf2f((unsigned short)ub)
             + p2 * bf2f((unsigned short)uc) + p3 * bf2f((unsigned short)ud);
    float oy = p0 * bf2f((unsigned short)(ua >> 16)) + p1 * bf2f((unsigned short)(ub >> 16))
             + p2 * bf2f((unsigned short)(uc >> 16)) + p3 * bf2f((unsigned short)(ud >> 16));
    float ss = ox * ox + oy * oy;
#pragma unroll
    for (int m = 1; m < 64; m <<= 1) ss += __shfl_xor(ss, m);
    float sc = rsqrtf(ss * (1.f / 128.f) + 1e-5f);
    float2 o2 = make_float2(ox * sc * onw[lane * 2], oy * sc * onw[lane * 2 + 1]);
    *(float2*)(on + base) = o2;
}

// ---------------------------------------------------------------------------
// Workspace (~202.6 MB):
//  bufA: q_pre -> k(conv) -> kn -> o_norm fp32
//  bufB: k_pre -> [lo 32MB: v bf16][hi 32MB: o_pre/delta bf16]
//  bufC: v_pre -> w|u bf16 tiles -> [lo: fs bf16][hi: fl bf16]
//  d_out: Wqkv_t (6MB) -> q(conv) -> qe -> hdn chunk fp32 -> final out
//  + beta, stats, pbuf, gw1_t, Wo_t
// ---------------------------------------------------------------------------
extern "C" void kernel_launch(void* const* d_in, const int* in_sizes, int n_in,
                              void* d_out, int out_size, void* d_ws, size_t ws_size,
                              hipStream_t stream)
{
    const float* hs   = (const float*)d_in[0];
    const float* Wq   = (const float*)d_in[1];
    const float* Wk   = (const float*)d_in[2];
    const float* Wv   = (const float*)d_in[3];
    const float* Wb   = (const float*)d_in[4];
    const float* cqw  = (const float*)d_in[5];
    const float* ckw  = (const float*)d_in[6];
    const float* cvw  = (const float*)d_in[7];
    const float* ret  = (const float*)d_in[8];
    const float* fsw  = (const float*)d_in[9];
    const float* flw  = (const float*)d_in[10];
    const float* gw1  = (const float*)d_in[11];
    const float* gb1  = (const float*)d_in[12];
    const float* gw2  = (const float*)d_in[13];
    const float* gb2  = (const float*)d_in[14];
    const float* ltmp = (const float*)d_in[15];
    const float* onw  = (const float*)d_in[16];
    const float* Wo   = (const float*)d_in[17];
    float* out = (float*)d_out;

    char* wsp = (char*)d_ws;
    size_t off = 0;
    auto alloc = [&](size_t nbytes) -> void* {
        void* pt = (void*)(wsp + off);
        off += ((nbytes + 255) / 256) * 256;
        return pt;
    };
    const int R = R_TOT;
    float* bufA  = (float*)alloc((size_t)R * DMODEL * 4);
    float* bufB  = (float*)alloc((size_t)R * DMODEL * 4);
    float* bufC  = (float*)alloc((size_t)R * DMODEL * 4);
    float* beta  = (float*)alloc((size_t)R * NHEAD * 4);
    float* stats = (float*)alloc((size_t)R * 32 * 4);
    float* pbuf  = (float*)alloc((size_t)R * 32 * 4);
    unsigned short* gw1t = (unsigned short*)alloc((size_t)2048 * 1056 * 2);
    unsigned short* wot  = (unsigned short*)alloc((size_t)1024 * 1024 * 2);
    float* bufO = out;
    bf16* vbf  = (bf16*)bufB;                        // lower 32MB
    bf16* dlt  = (bf16*)bufB + (size_t)R * DMODEL;   // upper 32MB
    bf16* wu   = (bf16*)bufC;
    unsigned short* fsb = (unsigned short*)bufC;                       // fs after scan
    unsigned short* flb = (unsigned short*)bufC + (size_t)R * DMODEL;  // fl
    unsigned short* wqkvt = (unsigned short*)bufO;   // 3072x1024 bf16 = 6MB
    (void)ws_size; (void)in_sizes; (void)n_in; (void)out_size;

    dim3 blk(256);
    // 1. weight transposes (Wq|Wk|Wv concat into d_out scratch; gw1,Wo into ws)
    tcast<<<dim3(32, 32), blk, 0, stream>>>(Wq, wqkvt, 1024, 1024);
    tcast<<<dim3(32, 32), blk, 0, stream>>>(Wk, wqkvt + (size_t)1024 * 1024, 1024, 1024);
    tcast<<<dim3(32, 32), blk, 0, stream>>>(Wv, wqkvt + (size_t)2048 * 1024, 1024, 1024);
    tcast<<<dim3(33, 64), blk, 0, stream>>>(gw1, gw1t, 1056, 2048);
    tcast<<<dim3(32, 32), blk, 0, stream>>>(Wo, wot, 1024, 1024);

    // 2. fused qkv projection (MFMA): q->bufA, k->bufB, v->bufC
    mgemm<4><<<dim3(24, 128), blk, 0, stream>>>(hs, nullptr, 1 << 30, DMODEL, 0,
                                                wqkvt, nullptr, bufA, bufB, bufC,
                                                R, 3072, 1024);
    // 3. beta = sigmoid(hs @ Wb)
    sgemm<1><<<dim3(1, R / 64), blk, 0, stream>>>(hs, nullptr, 1 << 30, DMODEL, 0,
                                                  Wb, nullptr, nullptr, beta, R, NHEAD, DMODEL);
    // 4. short conv + silu: q: A->O fp32, k: B->A fp32, v: C->B.lo bf16
    int convGrid = (int)(((size_t)R * DMODEL + 255) / 256);
    shortconv<0><<<convGrid, blk, 0, stream>>>(bufA, cqw, bufO, nullptr);
    shortconv<0><<<convGrid, blk, 0, stream>>>(bufB, ckw, bufA, nullptr);
    shortconv<1><<<convGrid, blk, 0, stream>>>(bufC, cvw, nullptr, vbf);
    // 5/6. delta rule
    chunk_prep<<<4096, blk, 0, stream>>>(bufO, bufA, vbf, beta, bufO, bufA, wu, dlt);
    delta_scan2<<<256, blk, 0, stream>>>(bufO, bufA, wu, dlt, ret);
    // 7. FIR once (wu dead -> bufC holds fs|fl)
    fir_compute<<<dim3(32, 8, 4), blk, 0, stream>>>((const unsigned short*)vbf, fsw, flw, fsb, flb);
    // 8. stats
    fir_stats2<<<32768, blk, 0, stream>>>(fsb, flb, (const unsigned short*)dlt,
                                          (const unsigned short*)vbf, stats);
    // 9. gate MLP (two row-chunks; hdn fp32 in d_out scratch)
    const int RC = 8192;
    float* hdn = bufO;
    for (int r0 = 0; r0 < R; r0 += RC) {
        mgemm<2><<<dim3(16, RC / 128), blk, 0, stream>>>(hs + (size_t)r0 * DMODEL,
                                                         stats + (size_t)r0 * 32,
                                                         1024, DMODEL, 32, gw1t, gb1,
                                                         hdn, nullptr, nullptr,
                                                         RC, 2048, 1056);
        sgemm<3><<<dim3(1, RC / 64), blk, 0, stream>>>(hdn, nullptr, 1 << 30, 2048, 0,
                                                       gw2, gb2, ltmp,
                                                       pbuf + (size_t)r0 * 32, RC, 32, 2048);
    }
    // 10. combine + RMS norm -> bufA fp32
    combine2<<<32768, blk, 0, stream>>>(fsb, flb, (const unsigned short*)dlt,
                                        (const unsigned short*)vbf, pbuf, onw, bufA);
    // 11. final projection (MFMA) -> d_out
    mgemm<0><<<dim3(8, 128), blk, 0, stream>>>(bufA, nullptr, 1 << 30, DMODEL, 0,
                                               wot, nullptr, out, nullptr, nullptr,
                                               R, 1024, 1024);
}

// Round 5
// 1714.715 us; speedup vs baseline: 10.3233x; 1.5255x over previous
//
#include <hip/hip_runtime.h>
#include <hip/hip_bf16.h>
#include <math.h>

#define R_TOT 16384      // B*L
#define LSEQ  4096
#define DMODEL 1024
#define NHEAD 8
#define DHEAD 128        // DK = DV
#define NCHUNK 128       // LSEQ/32

typedef __hip_bfloat16 bf16;
typedef short s8v __attribute__((ext_vector_type(8)));
typedef float f4v __attribute__((ext_vector_type(4)));

__device__ __forceinline__ float sigmoidf_(float x) { return 1.f / (1.f + expf(-x)); }
__device__ __forceinline__ unsigned short f2bf(float f) {
    unsigned u = __float_as_uint(f);
    u += 0x7fffu + ((u >> 16) & 1u);
    return (unsigned short)(u >> 16);
}
__device__ __forceinline__ float bf2f(unsigned short s) {
    return __uint_as_float(((unsigned)s) << 16);
}

// ---------------------------------------------------------------------------
// Transpose-cast: W (K x N fp32) -> Wt (Npad x K bf16), zero-padded rows N..Npad
// ---------------------------------------------------------------------------
__global__ __launch_bounds__(256)
void tcast(const float* __restrict__ W, unsigned short* __restrict__ Wt,
           int K, int N, int Npad)
{
    __shared__ float t[32][33];
    const int kb = blockIdx.x * 32, nb = blockIdx.y * 32;
    const int tx = threadIdx.x & 31, ty = threadIdx.x >> 5;   // ty 0..7
    for (int i = ty; i < 32; i += 8) {
        int k = kb + i, n = nb + tx;
        t[i][tx] = (k < K && n < N) ? W[(size_t)k * N + n] : 0.f;
    }
    __syncthreads();
    for (int i = ty; i < 32; i += 8) {
        int n = nb + i, k = kb + tx;
        if (n < Npad && k < K) Wt[(size_t)n * K + k] = f2bf(t[tx][i]);
    }
}

// ---------------------------------------------------------------------------
// MFMA bf16 GEMM: C = epi(A @ Bt^T), A fp32 MxK (split A/A2 at Ksplit),
// Bt = bf16 N x K row-major. Tile 128x128x32, 256 thr = 4 waves.
// MODE 0: none  1: sigmoid (store col<Nout, stride Nout)
// MODE 2: gelu(x+bias)  3: p-gate (store col<Nout, stride Nout)
// MODE 4: qkv split (col/1024 -> C0/C1/C2)
// ---------------------------------------------------------------------------
template<int MODE>
__global__ __launch_bounds__(256)
void mgemm(const float* __restrict__ A, const float* __restrict__ A2, int Ksplit,
           int lda1, int lda2,
           const unsigned short* __restrict__ Bt,
           const float* __restrict__ bias, const float* __restrict__ aux,
           float* __restrict__ C0, float* __restrict__ C1, float* __restrict__ C2,
           int M, int N, int K, int Nout)
{
    __shared__ unsigned short As[128 * 40];
    __shared__ unsigned short Bs[128 * 40];
    const int tid = threadIdx.x;
    const int m0 = blockIdx.y * 128, n0 = blockIdx.x * 128;
    const int l = tid & 63;
    const int wr = (tid >> 7) & 1, wc = (tid >> 6) & 1;
    const int sr = tid >> 1, sh = (tid & 1) * 16;

    const f4v zf = {0.f, 0.f, 0.f, 0.f};
    f4v acc[4][4];
#pragma unroll
    for (int i = 0; i < 4; ++i)
#pragma unroll
        for (int j = 0; j < 4; ++j) acc[i][j] = zf;

    const int nkt = K >> 5;
    for (int kt = 0; kt < nkt; ++kt) {
        const int k0 = kt << 5;
        {
            const float* src = (k0 < Ksplit)
                ? A  + (size_t)(m0 + sr) * lda1 + (size_t)(k0 + sh)
                : A2 + (size_t)(m0 + sr) * lda2 + (size_t)(k0 - Ksplit + sh);
            float4 v0 = ((const float4*)src)[0];
            float4 v1 = ((const float4*)src)[1];
            float4 v2 = ((const float4*)src)[2];
            float4 v3 = ((const float4*)src)[3];
            s8v w0, w1;
            w0[0] = (short)f2bf(v0.x); w0[1] = (short)f2bf(v0.y);
            w0[2] = (short)f2bf(v0.z); w0[3] = (short)f2bf(v0.w);
            w0[4] = (short)f2bf(v1.x); w0[5] = (short)f2bf(v1.y);
            w0[6] = (short)f2bf(v1.z); w0[7] = (short)f2bf(v1.w);
            w1[0] = (short)f2bf(v2.x); w1[1] = (short)f2bf(v2.y);
            w1[2] = (short)f2bf(v2.z); w1[3] = (short)f2bf(v2.w);
            w1[4] = (short)f2bf(v3.x); w1[5] = (short)f2bf(v3.y);
            w1[6] = (short)f2bf(v3.z); w1[7] = (short)f2bf(v3.w);
            *(s8v*)&As[sr * 40 + sh]     = w0;
            *(s8v*)&As[sr * 40 + sh + 8] = w1;
        }
        {
            const unsigned short* src = Bt + (size_t)(n0 + sr) * K + (size_t)(k0 + sh);
            s8v b0 = ((const s8v*)src)[0];
            s8v b1 = ((const s8v*)src)[1];
            *(s8v*)&Bs[sr * 40 + sh]     = b0;
            *(s8v*)&Bs[sr * 40 + sh + 8] = b1;
        }
        __syncthreads();
        const int fr = l & 15, fq = (l >> 4) * 8;
        s8v af[4], bfr[4];
#pragma unroll
        for (int i = 0; i < 4; ++i) {
            af[i]  = *(const s8v*)&As[(wr * 64 + i * 16 + fr) * 40 + fq];
            bfr[i] = *(const s8v*)&Bs[(wc * 64 + i * 16 + fr) * 40 + fq];
        }
#pragma unroll
        for (int i = 0; i < 4; ++i)
#pragma unroll
            for (int j = 0; j < 4; ++j)
                acc[i][j] = __builtin_amdgcn_mfma_f32_16x16x32_bf16(af[i], bfr[j], acc[i][j], 0, 0, 0);
        __syncthreads();
    }
    const int fr = l & 15, fq4 = (l >> 4) * 4;
#pragma unroll
    for (int i = 0; i < 4; ++i) {
#pragma unroll
        for (int j = 0; j < 4; ++j) {
            int col = n0 + wc * 64 + j * 16 + fr;
            if ((MODE == 1 || MODE == 3) && col >= Nout) continue;
#pragma unroll
            for (int q = 0; q < 4; ++q) {
                int row = m0 + wr * 64 + i * 16 + fq4 + q;
                float x = acc[i][j][q];
                if (MODE == 1) {
                    x = sigmoidf_(x);
                    C0[(size_t)row * Nout + col] = x;
                } else if (MODE == 2) {
                    x += bias[col];
                    x = 0.5f * x * (1.f + erff(x * 0.70710678118654752f));
                    C0[(size_t)row * N + col] = x;
                } else if (MODE == 3) {
                    x += bias[col];
                    x *= expf(-aux[col >> 2]);
                    x = 0.02f + 0.98f * sigmoidf_(x);
                    C0[(size_t)row * Nout + col] = x;
                } else if (MODE == 4) {
                    float* dst = (col < 1024) ? C0 : ((col < 2048) ? C1 : C2);
                    dst[(size_t)row * 1024 + (col & 1023)] = x;
                } else {
                    C0[(size_t)row * N + col] = x;
                }
            }
        }
    }
}

// ---------------------------------------------------------------------------
// Short causal conv (K=4) + SiLU.
// ---------------------------------------------------------------------------
template<int OUT_BF16>
__global__ __launch_bounds__(256)
void shortconv(const float* __restrict__ x, const float* __restrict__ w,
               float* __restrict__ yf, bf16* __restrict__ yb)
{
    size_t idx = (size_t)blockIdx.x * 256 + threadIdx.x;
    if (idx >= (size_t)R_TOT * DMODEL) return;
    int c = (int)(idx & (DMODEL - 1));
    long r = (long)(idx >> 10);
    int l = (int)(r & (LSEQ - 1));
    const float* wc = w + c * 4;
    float acc = 0.f;
#pragma unroll
    for (int j = 0; j < 4; ++j) {
        int xl = l - 3 + j;
        if (xl >= 0) acc += x[(r - l + xl) * DMODEL + c] * wc[j];
    }
    float y = acc * sigmoidf_(acc);
    if (OUT_BF16) yb[idx] = __float2bfloat16(y);
    else          yf[idx] = y;
}

// ---------------------------------------------------------------------------
// Phase 1: per-(b,h,chunk) prep (unchanged, round-3/4 verified)
// ---------------------------------------------------------------------------
__global__ __launch_bounds__(256)
void chunk_prep(const float* __restrict__ qconv, const float* __restrict__ kconv,
                const bf16* __restrict__ vbf, const float* __restrict__ beta,
                float* __restrict__ qe_out, float* __restrict__ kn_out,
                bf16* __restrict__ wu, bf16* __restrict__ opre)
{
    const int bid = blockIdx.x;              // (b*8+h)*128 + c
    const int c = bid & 127, h = (bid >> 7) & 7, b = bid >> 10;
    const int tid = threadIdx.x;

    __shared__ float qs[32][130], ks[32][130], vs[32][130], ws_l[32][130];
    __shared__ float Am[32][33], at[32][33];
    __shared__ float betas[32];

    const size_t row0 = (size_t)b * LSEQ + (size_t)c * 32;
    const size_t base = row0 * DMODEL + (size_t)h * DHEAD;

    for (int idx = tid; idx < 32 * 128; idx += 256) {
        int i = idx >> 7, d = idx & 127;
        size_t g = base + (size_t)i * DMODEL + d;
        qs[i][d] = qconv[g];
        ks[i][d] = kconv[g];
        vs[i][d] = __bfloat162float(vbf[g]);
    }
    if (tid < 32) betas[tid] = beta[(row0 + tid) * NHEAD + h];
    __syncthreads();

    {
        int row = tid >> 3, ln = tid & 7;
        float sq = 0.f, sk = 0.f;
        for (int d = ln; d < 128; d += 8) {
            float a_ = qs[row][d]; sq += a_ * a_;
            float b_ = ks[row][d]; sk += b_ * b_;
        }
#pragma unroll
        for (int m = 1; m < 8; m <<= 1) { sq += __shfl_xor(sq, m); sk += __shfl_xor(sk, m); }
        float rq = rsqrtf(sq + 1e-6f), rk = rsqrtf(sk + 1e-6f);
        for (int d = ln; d < 128; d += 8) { qs[row][d] *= rq; ks[row][d] *= rk; }
    }
    __syncthreads();

    {
        int i0 = tid >> 5, j = tid & 31;
#pragma unroll
        for (int qd = 0; qd < 4; ++qd) {
            int i = i0 + qd * 8;
            float dk0 = 0.f, dk1 = 0.f, dq0 = 0.f, dq1 = 0.f;
#pragma unroll 8
            for (int d = 0; d < 128; d += 2) {
                float kj0 = ks[j][d], kj1 = ks[j][d + 1];
                dk0 += ks[i][d] * kj0; dk1 += ks[i][d + 1] * kj1;
                dq0 += qs[i][d] * kj0; dq1 += qs[i][d + 1] * kj1;
            }
            Am[i][j] = (i > j)  ? betas[i] * (dk0 + dk1) : 0.f;
            at[i][j] = (i >= j) ? (dq0 + dq1) : 0.f;
        }
    }
    __syncthreads();

    {
        float x[32];
        int t = tid;
        if (t < 128) {
#pragma unroll
            for (int i = 0; i < 32; ++i) x[i] = betas[i] * vs[i][t];
        } else {
            int d = t - 128;
#pragma unroll
            for (int i = 0; i < 32; ++i) x[i] = betas[i] * ks[i][d];
        }
#pragma unroll
        for (int i = 1; i < 32; ++i) {
            float s = 0.f;
#pragma unroll
            for (int m = 0; m < i; ++m) s = fmaf(Am[i][m], x[m], s);
            x[i] -= s;
        }
        const size_t tb = (size_t)bid * 8192;
        if (t < 128) {
#pragma unroll
            for (int i = 0; i < 32; ++i) {
                wu[tb + 4096 + i * 128 + t] = __float2bfloat16(x[i]);  // u
                vs[i][t] = x[i];
            }
        } else {
            int d = t - 128;
#pragma unroll
            for (int i = 0; i < 32; ++i) {
                wu[tb + i * 128 + d] = __float2bfloat16(x[i]);          // w
                ws_l[i][d] = x[i];
            }
        }
    }
    __syncthreads();

    for (int idx = tid; idx < 4096; idx += 256) {
        int i = idx >> 7, d = idx & 127;
        float s = 0.f, s2 = 0.f;
#pragma unroll
        for (int j = 0; j < 32; ++j) {
            float a = at[i][j];
            s  = fmaf(a, ws_l[j][d], s);
            s2 = fmaf(a, vs[j][d], s2);
        }
        size_t g = base + (size_t)i * DMODEL + d;
        qe_out[g] = qs[i][d] - s;
        kn_out[g] = ks[i][d];
        opre[g] = __float2bfloat16(s2);
    }
}

// ---------------------------------------------------------------------------
// Phase 2: MFMA state scan. 256 blocks = (b,h,dv-slice 16) x 256 thr (4 waves).
// S (128x16 slice) lives in fp32 MFMA accumulators (2 d-tiles per wave);
// each chunk exports bf16 St_b[t][d] to LDS for phase A.
// Phase A (MFMA): ua = u - w@S (waves 0,1), o = opre + qe@S (waves 2,3).
// Phase B (MFMA): Sacc = lam*Sacc + uaT @ knT.
// ---------------------------------------------------------------------------
__global__ __launch_bounds__(256)
void delta_scan3(const float* __restrict__ qe, const float* __restrict__ kn,
                 const bf16* __restrict__ wu, bf16* __restrict__ delta,
                 const float* __restrict__ ret)
{
    const int bid = blockIdx.x;           // (b*8+h)*8 + dvs
    const int dvs = bid & 7, bh = bid >> 3;
    const int h = bh & 7, b = bh >> 3;
    const int tid = threadIdx.x;
    const int l = tid & 63, wid = tid >> 6;

    __shared__ __align__(16) unsigned short qe_b[32 * 136];
    __shared__ __align__(16) unsigned short w_b [32 * 136];
    __shared__ __align__(16) unsigned short knT [128 * 40];
    __shared__ __align__(16) unsigned short St_b[16 * 136];
    __shared__ __align__(16) unsigned short uaT [16 * 40];
    __shared__ float us_s[32][18], ops_s[32][18];

    const float lam = 0.6f + 0.4f * sigmoidf_(ret[h]);

    for (int i = tid; i < 16 * 136; i += 256) St_b[i] = 0;

    const int li = tid >> 3, ld0 = (tid & 7) * 16;
    const int iu = tid >> 3, tu = (tid & 7) * 2;
    const size_t headoff = (size_t)h * DHEAD;

    const f4v zf = {0.f, 0.f, 0.f, 0.f};
    f4v Sacc0 = zf, Sacc1 = zf;        // this wave's S d-tiles (d0 = wid*32)

    float4 pq[4], pk[4];
    uint4  pw[2];
    unsigned puv, pov;

#define ISSUE(cc)  {                                                                        \
        size_t rb = ((size_t)b * LSEQ + (size_t)(cc) * 32);                                 \
        const float* gq = qe + (rb + li) * DMODEL + headoff + ld0;                          \
        const float* gk = kn + (rb + li) * DMODEL + headoff + ld0;                          \
        pq[0] = ((const float4*)gq)[0]; pq[1] = ((const float4*)gq)[1];                     \
        pq[2] = ((const float4*)gq)[2]; pq[3] = ((const float4*)gq)[3];                     \
        pk[0] = ((const float4*)gk)[0]; pk[1] = ((const float4*)gk)[1];                     \
        pk[2] = ((const float4*)gk)[2]; pk[3] = ((const float4*)gk)[3];                     \
        size_t tb = ((size_t)bh * NCHUNK + (cc)) * 8192;                                    \
        const uint4* gw = (const uint4*)(wu + tb + li * 128 + ld0);                         \
        pw[0] = gw[0]; pw[1] = gw[1];                                                       \
        puv = *(const unsigned*)(wu + tb + 4096 + iu * 128 + dvs * 16 + tu);                \
        pov = *(const unsigned*)(delta + (rb + iu) * DMODEL + headoff + dvs * 16 + tu);     \
    }

    ISSUE(0);

    for (int c = 0; c < NCHUNK; ++c) {
        // ---- stage-unpack prefetched regs -> LDS (qe->bf16, kn->knT bf16, w, u, opre)
#pragma unroll
        for (int v4 = 0; v4 < 4; ++v4) {
            const float* pf = (const float*)&pq[v4];
            unsigned lo = (unsigned)f2bf(pf[0]) | ((unsigned)f2bf(pf[1]) << 16);
            unsigned hi = (unsigned)f2bf(pf[2]) | ((unsigned)f2bf(pf[3]) << 16);
            *(unsigned*)&qe_b[li * 136 + ld0 + v4 * 4]     = lo;
            *(unsigned*)&qe_b[li * 136 + ld0 + v4 * 4 + 2] = hi;
        }
#pragma unroll
        for (int v4 = 0; v4 < 4; ++v4) {
            const float* pf = (const float*)&pk[v4];
#pragma unroll
            for (int e = 0; e < 4; ++e)
                knT[(ld0 + v4 * 4 + e) * 40 + li] = f2bf(pf[e]);
        }
        *(uint4*)&w_b[li * 136 + ld0]     = pw[0];
        *(uint4*)&w_b[li * 136 + ld0 + 8] = pw[1];
        {
            us_s[iu][tu]      = bf2f((unsigned short)puv);
            us_s[iu][tu + 1]  = bf2f((unsigned short)(puv >> 16));
            ops_s[iu][tu]     = bf2f((unsigned short)pov);
            ops_s[iu][tu + 1] = bf2f((unsigned short)(pov >> 16));
        }
        if (c + 1 < NCHUNK) ISSUE(c + 1);
        __syncthreads();

        // ---- phase A: waves 0,1 -> ua = u - w@S ; waves 2,3 -> o = opre + qe@S
        {
            const int half = wid & 1;
            const int arow = half * 16 + (l & 15);
            const int koff = (l >> 4) * 8;
            const unsigned short* ab = (wid < 2) ? w_b : qe_b;
            f4v a = zf;
#pragma unroll
            for (int kt = 0; kt < 4; ++kt) {
                s8v af  = *(const s8v*)&ab[arow * 136 + kt * 32 + koff];
                s8v bf_ = *(const s8v*)&St_b[(l & 15) * 136 + kt * 32 + koff];
                a = __builtin_amdgcn_mfma_f32_16x16x32_bf16(af, bf_, a, 0, 0, 0);
            }
            const int ib = half * 16 + ((l >> 4) << 2);
            const int t = l & 15;
            if (wid < 2) {
#pragma unroll
                for (int q = 0; q < 4; ++q) {
                    float v = us_s[ib + q][t] - a[q];
                    uaT[t * 40 + ib + q] = f2bf(v);
                }
            } else {
                size_t rb = (size_t)b * LSEQ + (size_t)c * 32;
#pragma unroll
                for (int q = 0; q < 4; ++q) {
                    float v = ops_s[ib + q][t] + a[q];
                    delta[(rb + ib + q) * DMODEL + headoff + dvs * 16 + t] = __float2bfloat16(v);
                }
            }
        }
        __syncthreads();

        // ---- phase B: Sacc = lam*Sacc + uaT @ knT ; export bf16 St_b
        {
#pragma unroll
            for (int q = 0; q < 4; ++q) { Sacc0[q] *= lam; Sacc1[q] *= lam; }
            const int koff = (l >> 4) * 8;
            s8v af = *(const s8v*)&uaT[(l & 15) * 40 + koff];
            const int d0 = wid * 32;
            s8v b0 = *(const s8v*)&knT[(d0 + (l & 15)) * 40 + koff];
            s8v b1 = *(const s8v*)&knT[(d0 + 16 + (l & 15)) * 40 + koff];
            Sacc0 = __builtin_amdgcn_mfma_f32_16x16x32_bf16(af, b0, Sacc0, 0, 0, 0);
            Sacc1 = __builtin_amdgcn_mfma_f32_16x16x32_bf16(af, b1, Sacc1, 0, 0, 0);
            const int tr = (l >> 4) << 2;
#pragma unroll
            for (int q = 0; q < 4; ++q) {
                St_b[(tr + q) * 136 + d0 + (l & 15)]      = f2bf(Sacc0[q]);
                St_b[(tr + q) * 136 + d0 + 16 + (l & 15)] = f2bf(Sacc1[q]);
            }
        }
        __syncthreads();
    }
#undef ISSUE
}

// ---------------------------------------------------------------------------
// FIR computed once, LDS-tiled (unchanged, round-4 verified)
// ---------------------------------------------------------------------------
__global__ __launch_bounds__(256)
void fir_compute(const unsigned short* __restrict__ v,
                 const float* __restrict__ wshort, const float* __restrict__ wlong,
                 unsigned short* __restrict__ fso, unsigned short* __restrict__ flo)
{
    const int lt = blockIdx.x, h = blockIdx.y, b = blockIdx.z;
    const int tid = threadIdx.x;
    __shared__ unsigned short vt[190 * 128];
    __shared__ float wl[63 * 128];
    __shared__ float w3[3 * 128];

    for (int i = tid; i < 63 * 128; i += 256) {
        int j = i >> 7, d = i & 127;
        wl[i] = wlong[((size_t)h * 128 + d) * 63 + j];
    }
    for (int i = tid; i < 3 * 128; i += 256) {
        int j = i >> 7, d = i & 127;
        w3[i] = wshort[((size_t)h * 128 + d) * 3 + j];
    }
    const size_t vbase = ((size_t)b * LSEQ) * DMODEL + (size_t)h * DHEAD;
    const int l0 = lt * 128;
    const s8v z8 = {0, 0, 0, 0, 0, 0, 0, 0};
    for (int i = tid; i < 190 * 16; i += 256) {
        int row = i >> 4, dblk = (i & 15) * 8;
        int gl = l0 - 62 + row;
        s8v val = z8;
        if (gl >= 0) val = *(const s8v*)&v[vbase + (size_t)gl * DMODEL + dblk];
        *(s8v*)&vt[row * 128 + dblk] = val;
    }
    __syncthreads();

    const int dp = (tid & 63) * 2, lg = tid >> 6;
    for (int lc = 0; lc < 4; ++lc) {
        const int lb = lg * 32 + lc * 8;
        float a0[8], a1[8], s0[8], s1[8];
#pragma unroll
        for (int li = 0; li < 8; ++li) { a0[li] = a1[li] = s0[li] = s1[li] = 0.f; }
        for (int j = 0; j < 63; ++j) {
            float w0 = wl[j * 128 + dp], w1 = wl[j * 128 + dp + 1];
#pragma unroll
            for (int li = 0; li < 8; ++li) {
                unsigned vv = *(const unsigned*)&vt[(lb + li + j) * 128 + dp];
                a0[li] = fmaf(bf2f((unsigned short)vv), w0, a0[li]);
                a1[li] = fmaf(bf2f((unsigned short)(vv >> 16)), w1, a1[li]);
            }
        }
#pragma unroll
        for (int j = 0; j < 3; ++j) {
            float w0 = w3[j * 128 + dp], w1 = w3[j * 128 + dp + 1];
#pragma unroll
            for (int li = 0; li < 8; ++li) {
                unsigned vv = *(const unsigned*)&vt[(lb + li + 60 + j) * 128 + dp];
                s0[li] = fmaf(bf2f((unsigned short)vv), w0, s0[li]);
                s1[li] = fmaf(bf2f((unsigned short)(vv >> 16)), w1, s1[li]);
            }
        }
        const size_t ob = ((size_t)b * LSEQ + l0) * DMODEL + (size_t)h * DHEAD + dp;
#pragma unroll
        for (int li = 0; li < 8; ++li) {
            unsigned pf = (unsigned)f2bf(a0[li]) | ((unsigned)f2bf(a1[li]) << 16);
            unsigned ps = (unsigned)f2bf(s0[li]) | ((unsigned)f2bf(s1[li]) << 16);
            *(unsigned*)&flo[ob + (size_t)(lb + li) * DMODEL] = pf;
            *(unsigned*)&fso[ob + (size_t)(lb + li) * DMODEL] = ps;
        }
    }
}

// ---------------------------------------------------------------------------
// Stats: one wave per (r,h) row (unchanged)
// ---------------------------------------------------------------------------
__global__ __launch_bounds__(256)
void fir_stats2(const unsigned short* __restrict__ fs, const unsigned short* __restrict__ fl,
                const unsigned short* __restrict__ dlt, const unsigned short* __restrict__ v,
                float* __restrict__ stats)
{
    const int rh = blockIdx.x * 4 + (threadIdx.x >> 6);
    const int lane = threadIdx.x & 63;
    const int r = rh >> 3, h = rh & 7;
    const size_t base = (size_t)r * DMODEL + (size_t)h * DHEAD + lane * 2;
    unsigned ua = *(const unsigned*)(fs + base);
    unsigned ub = *(const unsigned*)(fl + base);
    unsigned uc = *(const unsigned*)(dlt + base);
    unsigned ud = *(const unsigned*)(v + base);
    float s0 = bf2f((unsigned short)ua) + bf2f((unsigned short)(ua >> 16));
    float s1 = bf2f((unsigned short)ub) + bf2f((unsigned short)(ub >> 16));
    float s2 = bf2f((unsigned short)uc) + bf2f((unsigned short)(uc >> 16));
    float s3 = bf2f((unsigned short)ud) + bf2f((unsigned short)(ud >> 16));
#pragma unroll
    for (int m = 1; m < 64; m <<= 1) {
        s0 += __shfl_xor(s0, m); s1 += __shfl_xor(s1, m);
        s2 += __shfl_xor(s2, m); s3 += __shfl_xor(s3, m);
    }
    if (lane == 0) {
        const float inv = 1.f / 128.f;
        stats[(size_t)r * 32 + 0  + h] = s0 * inv;
        stats[(size_t)r * 32 + 8  + h] = s1 * inv;
        stats[(size_t)r * 32 + 16 + h] = s2 * inv;
        stats[(size_t)r * 32 + 24 + h] = s3 * inv;
    }
}

// ---------------------------------------------------------------------------
// Combine + RMS norm (unchanged)
// ---------------------------------------------------------------------------
__global__ __launch_bounds__(256)
void combine2(const unsigned short* __restrict__ fs, const unsigned short* __restrict__ fl,
              const unsigned short* __restrict__ dlt, const unsigned short* __restrict__ v,
              const float* __restrict__ p, const float* __restrict__ onw,
              float* __restrict__ on)
{
    const int rh = blockIdx.x * 4 + (threadIdx.x >> 6);
    const int lane = threadIdx.x & 63;
    const int r = rh >> 3, h = rh & 7;
    const size_t base = (size_t)r * DMODEL + (size_t)h * DHEAD + lane * 2;
    unsigned ua = *(const unsigned*)(fs + base);
    unsigned ub = *(const unsigned*)(fl + base);
    unsigned uc = *(const unsigned*)(dlt + base);
    unsigned ud = *(const unsigned*)(v + base);
    const float* pp = p + (size_t)r * 32 + h * 4;
    float p0 = pp[0], p1 = pp[1], p2 = pp[2], p3 = pp[3];
    float ox = p0 * bf2f((unsigned short)ua) + p1 * bf2f((unsigned short)ub)
             + p2 * bf2f((unsigned short)uc) + p3 * bf2f((unsigned short)ud);
    float oy = p0 * bf2f((unsigned short)(ua >> 16)) + p1 * bf2f((unsigned short)(ub >> 16))
             + p2 * bf2f((unsigned short)(uc >> 16)) + p3 * bf2f((unsigned short)(ud >> 16));
    float ss = ox * ox + oy * oy;
#pragma unroll
    for (int m = 1; m < 64; m <<= 1) ss += __shfl_xor(ss, m);
    float sc = rsqrtf(ss * (1.f / 128.f) + 1e-5f);
    float2 o2 = make_float2(ox * sc * onw[lane * 2], oy * sc * onw[lane * 2 + 1]);
    *(float2*)(on + base) = o2;
}

// ---------------------------------------------------------------------------
// Workspace (~203.5 MB): bufA/B/C as round 4 + padded bf16 weights
// ---------------------------------------------------------------------------
extern "C" void kernel_launch(void* const* d_in, const int* in_sizes, int n_in,
                              void* d_out, int out_size, void* d_ws, size_t ws_size,
                              hipStream_t stream)
{
    const float* hs   = (const float*)d_in[0];
    const float* Wq   = (const float*)d_in[1];
    const float* Wk   = (const float*)d_in[2];
    const float* Wv   = (const float*)d_in[3];
    const float* Wb   = (const float*)d_in[4];
    const float* cqw  = (const float*)d_in[5];
    const float* ckw  = (const float*)d_in[6];
    const float* cvw  = (const float*)d_in[7];
    const float* ret  = (const float*)d_in[8];
    const float* fsw  = (const float*)d_in[9];
    const float* flw  = (const float*)d_in[10];
    const float* gw1  = (const float*)d_in[11];
    const float* gb1  = (const float*)d_in[12];
    const float* gw2  = (const float*)d_in[13];
    const float* gb2  = (const float*)d_in[14];
    const float* ltmp = (const float*)d_in[15];
    const float* onw  = (const float*)d_in[16];
    const float* Wo   = (const float*)d_in[17];
    float* out = (float*)d_out;

    char* wsp = (char*)d_ws;
    size_t off = 0;
    auto alloc = [&](size_t nbytes) -> void* {
        void* pt = (void*)(wsp + off);
        off += ((nbytes + 255) / 256) * 256;
        return pt;
    };
    const int R = R_TOT;
    float* bufA  = (float*)alloc((size_t)R * DMODEL * 4);
    float* bufB  = (float*)alloc((size_t)R * DMODEL * 4);
    float* bufC  = (float*)alloc((size_t)R * DMODEL * 4);
    float* beta  = (float*)alloc((size_t)R * NHEAD * 4);
    float* stats = (float*)alloc((size_t)R * 32 * 4);
    float* pbuf  = (float*)alloc((size_t)R * 32 * 4);
    unsigned short* gw1t = (unsigned short*)alloc((size_t)2048 * 1056 * 2);
    unsigned short* wot  = (unsigned short*)alloc((size_t)1024 * 1024 * 2);
    unsigned short* wbt  = (unsigned short*)alloc((size_t)128 * 1024 * 2);
    unsigned short* gw2t = (unsigned short*)alloc((size_t)128 * 2048 * 2);
    float* bufO = out;
    bf16* vbf  = (bf16*)bufB;                        // lower 32MB
    bf16* dlt  = (bf16*)bufB + (size_t)R * DMODEL;   // upper 32MB
    bf16* wu   = (bf16*)bufC;
    unsigned short* fsb = (unsigned short*)bufC;
    unsigned short* flb = (unsigned short*)bufC + (size_t)R * DMODEL;
    unsigned short* wqkvt = (unsigned short*)bufO;   // 3072x1024 bf16 = 6MB
    (void)ws_size; (void)in_sizes; (void)n_in; (void)out_size;

    dim3 blk(256);
    // 1. weight transposes / pads
    tcast<<<dim3(32, 32), blk, 0, stream>>>(Wq, wqkvt, 1024, 1024, 1024);
    tcast<<<dim3(32, 32), blk, 0, stream>>>(Wk, wqkvt + (size_t)1024 * 1024, 1024, 1024, 1024);
    tcast<<<dim3(32, 32), blk, 0, stream>>>(Wv, wqkvt + (size_t)2048 * 1024, 1024, 1024, 1024);
    tcast<<<dim3(33, 64), blk, 0, stream>>>(gw1, gw1t, 1056, 2048, 2048);
    tcast<<<dim3(32, 32), blk, 0, stream>>>(Wo, wot, 1024, 1024, 1024);
    tcast<<<dim3(32, 4),  blk, 0, stream>>>(Wb, wbt, 1024, 8, 128);
    tcast<<<dim3(64, 4),  blk, 0, stream>>>(gw2, gw2t, 2048, 32, 128);

    // 2. fused qkv projection (MFMA)
    mgemm<4><<<dim3(24, 128), blk, 0, stream>>>(hs, nullptr, 1 << 30, DMODEL, 0,
                                                wqkvt, nullptr, nullptr,
                                                bufA, bufB, bufC, R, 3072, 1024, 0);
    // 3. beta = sigmoid(hs @ Wb)  (MFMA, padded N)
    mgemm<1><<<dim3(1, 128), blk, 0, stream>>>(hs, nullptr, 1 << 30, DMODEL, 0,
                                               wbt, nullptr, nullptr,
                                               beta, nullptr, nullptr, R, 128, 1024, 8);
    // 4. short conv + silu
    int convGrid = (int)(((size_t)R * DMODEL + 255) / 256);
    shortconv<0><<<convGrid, blk, 0, stream>>>(bufA, cqw, bufO, nullptr);
    shortconv<0><<<convGrid, blk, 0, stream>>>(bufB, ckw, bufA, nullptr);
    shortconv<1><<<convGrid, blk, 0, stream>>>(bufC, cvw, nullptr, vbf);
    // 5/6. delta rule
    chunk_prep<<<4096, blk, 0, stream>>>(bufO, bufA, vbf, beta, bufO, bufA, wu, dlt);
    delta_scan3<<<256, blk, 0, stream>>>(bufO, bufA, wu, dlt, ret);
    // 7. FIR once
    fir_compute<<<dim3(32, 8, 4), blk, 0, stream>>>((const unsigned short*)vbf, fsw, flw, fsb, flb);
    // 8. stats
    fir_stats2<<<32768, blk, 0, stream>>>(fsb, flb, (const unsigned short*)dlt,
                                          (const unsigned short*)vbf, stats);
    // 9. gate MLP (two row-chunks; hdn fp32 in d_out scratch)
    const int RC = 8192;
    float* hdn = bufO;
    for (int r0 = 0; r0 < R; r0 += RC) {
        mgemm<2><<<dim3(16, RC / 128), blk, 0, stream>>>(hs + (size_t)r0 * DMODEL,
                                                         stats + (size_t)r0 * 32,
                                                         1024, DMODEL, 32, gw1t, gb1, nullptr,
                                                         hdn, nullptr, nullptr,
                                                         RC, 2048, 1056, 0);
        mgemm<3><<<dim3(1, RC / 128), blk, 0, stream>>>(hdn, nullptr, 1 << 30, 2048, 0,
                                                        gw2t, gb2, ltmp,
                                                        pbuf + (size_t)r0 * 32, nullptr, nullptr,
                                                        RC, 128, 2048, 32);
    }
    // 10. combine + RMS norm -> bufA fp32
    combine2<<<32768, blk, 0, stream>>>(fsb, flb, (const unsigned short*)dlt,
                                        (const unsigned short*)vbf, pbuf, onw, bufA);
    // 11. final projection (MFMA) -> d_out
    mgemm<0><<<dim3(8, 128), blk, 0, stream>>>(bufA, nullptr, 1 << 30, DMODEL, 0,
                                               wot, nullptr, nullptr,
                                               out, nullptr, nullptr, R, 1024, 1024, 0);
}

// Round 6
// 1619.009 us; speedup vs baseline: 10.9335x; 1.0591x over previous
//
#include <hip/hip_runtime.h>
#include <hip/hip_bf16.h>
#include <math.h>

#define R_TOT 16384      // B*L
#define LSEQ  4096
#define DMODEL 1024
#define NHEAD 8
#define DHEAD 128        // DK = DV
#define NCHUNK 128       // LSEQ/32

typedef __hip_bfloat16 bf16;
typedef short s8v __attribute__((ext_vector_type(8)));
typedef float f4v __attribute__((ext_vector_type(4)));

__device__ __forceinline__ float sigmoidf_(float x) { return 1.f / (1.f + expf(-x)); }
__device__ __forceinline__ unsigned short f2bf(float f) {
    unsigned u = __float_as_uint(f);
    u += 0x7fffu + ((u >> 16) & 1u);
    return (unsigned short)(u >> 16);
}
__device__ __forceinline__ float bf2f(unsigned short s) {
    return __uint_as_float(((unsigned)s) << 16);
}

// ---------------------------------------------------------------------------
// Transpose-cast: W (K x N fp32) -> Wt (Npad x K bf16), zero-padded rows N..Npad
// ---------------------------------------------------------------------------
__global__ __launch_bounds__(256)
void tcast(const float* __restrict__ W, unsigned short* __restrict__ Wt,
           int K, int N, int Npad)
{
    __shared__ float t[32][33];
    const int kb = blockIdx.x * 32, nb = blockIdx.y * 32;
    const int tx = threadIdx.x & 31, ty = threadIdx.x >> 5;   // ty 0..7
    for (int i = ty; i < 32; i += 8) {
        int k = kb + i, n = nb + tx;
        t[i][tx] = (k < K && n < N) ? W[(size_t)k * N + n] : 0.f;
    }
    __syncthreads();
    for (int i = ty; i < 32; i += 8) {
        int n = nb + i, k = kb + tx;
        if (n < Npad && k < K) Wt[(size_t)n * K + k] = f2bf(t[tx][i]);
    }
}

// ---------------------------------------------------------------------------
// MFMA bf16 GEMM: C = epi(A @ Bt^T), A fp32 MxK (split A/A2 at Ksplit),
// Bt = bf16 N x K row-major. Tile 128x128x32, 256 thr = 4 waves.
// MODE 0: none  1: sigmoid (store col<Nout, stride Nout)
// MODE 2: gelu(x+bias)  3: p-gate (store col<Nout, stride Nout)
// MODE 4: qkv split (col/1024 -> C0/C1/C2)
// ---------------------------------------------------------------------------
template<int MODE>
__global__ __launch_bounds__(256)
void mgemm(const float* __restrict__ A, const float* __restrict__ A2, int Ksplit,
           int lda1, int lda2,
           const unsigned short* __restrict__ Bt,
           const float* __restrict__ bias, const float* __restrict__ aux,
           float* __restrict__ C0, float* __restrict__ C1, float* __restrict__ C2,
           int M, int N, int K, int Nout)
{
    __shared__ unsigned short As[128 * 40];
    __shared__ unsigned short Bs[128 * 40];
    const int tid = threadIdx.x;
    const int m0 = blockIdx.y * 128, n0 = blockIdx.x * 128;
    const int l = tid & 63;
    const int wr = (tid >> 7) & 1, wc = (tid >> 6) & 1;
    const int sr = tid >> 1, sh = (tid & 1) * 16;

    const f4v zf = {0.f, 0.f, 0.f, 0.f};
    f4v acc[4][4];
#pragma unroll
    for (int i = 0; i < 4; ++i)
#pragma unroll
        for (int j = 0; j < 4; ++j) acc[i][j] = zf;

    const int nkt = K >> 5;
    for (int kt = 0; kt < nkt; ++kt) {
        const int k0 = kt << 5;
        {
            const float* src = (k0 < Ksplit)
                ? A  + (size_t)(m0 + sr) * lda1 + (size_t)(k0 + sh)
                : A2 + (size_t)(m0 + sr) * lda2 + (size_t)(k0 - Ksplit + sh);
            float4 v0 = ((const float4*)src)[0];
            float4 v1 = ((const float4*)src)[1];
            float4 v2 = ((const float4*)src)[2];
            float4 v3 = ((const float4*)src)[3];
            s8v w0, w1;
            w0[0] = (short)f2bf(v0.x); w0[1] = (short)f2bf(v0.y);
            w0[2] = (short)f2bf(v0.z); w0[3] = (short)f2bf(v0.w);
            w0[4] = (short)f2bf(v1.x); w0[5] = (short)f2bf(v1.y);
            w0[6] = (short)f2bf(v1.z); w0[7] = (short)f2bf(v1.w);
            w1[0] = (short)f2bf(v2.x); w1[1] = (short)f2bf(v2.y);
            w1[2] = (short)f2bf(v2.z); w1[3] = (short)f2bf(v2.w);
            w1[4] = (short)f2bf(v3.x); w1[5] = (short)f2bf(v3.y);
            w1[6] = (short)f2bf(v3.z); w1[7] = (short)f2bf(v3.w);
            *(s8v*)&As[sr * 40 + sh]     = w0;
            *(s8v*)&As[sr * 40 + sh + 8] = w1;
        }
        {
            const unsigned short* src = Bt + (size_t)(n0 + sr) * K + (size_t)(k0 + sh);
            s8v b0 = ((const s8v*)src)[0];
            s8v b1 = ((const s8v*)src)[1];
            *(s8v*)&Bs[sr * 40 + sh]     = b0;
            *(s8v*)&Bs[sr * 40 + sh + 8] = b1;
        }
        __syncthreads();
        const int fr = l & 15, fq = (l >> 4) * 8;
        s8v af[4], bfr[4];
#pragma unroll
        for (int i = 0; i < 4; ++i) {
            af[i]  = *(const s8v*)&As[(wr * 64 + i * 16 + fr) * 40 + fq];
            bfr[i] = *(const s8v*)&Bs[(wc * 64 + i * 16 + fr) * 40 + fq];
        }
#pragma unroll
        for (int i = 0; i < 4; ++i)
#pragma unroll
            for (int j = 0; j < 4; ++j)
                acc[i][j] = __builtin_amdgcn_mfma_f32_16x16x32_bf16(af[i], bfr[j], acc[i][j], 0, 0, 0);
        __syncthreads();
    }
    const int fr = l & 15, fq4 = (l >> 4) * 4;
#pragma unroll
    for (int i = 0; i < 4; ++i) {
#pragma unroll
        for (int j = 0; j < 4; ++j) {
            int col = n0 + wc * 64 + j * 16 + fr;
            if ((MODE == 1 || MODE == 3) && col >= Nout) continue;
#pragma unroll
            for (int q = 0; q < 4; ++q) {
                int row = m0 + wr * 64 + i * 16 + fq4 + q;
                float x = acc[i][j][q];
                if (MODE == 1) {
                    x = sigmoidf_(x);
                    C0[(size_t)row * Nout + col] = x;
                } else if (MODE == 2) {
                    x += bias[col];
                    x = 0.5f * x * (1.f + erff(x * 0.70710678118654752f));
                    C0[(size_t)row * N + col] = x;
                } else if (MODE == 3) {
                    x += bias[col];
                    x *= expf(-aux[col >> 2]);
                    x = 0.02f + 0.98f * sigmoidf_(x);
                    C0[(size_t)row * Nout + col] = x;
                } else if (MODE == 4) {
                    float* dst = (col < 1024) ? C0 : ((col < 2048) ? C1 : C2);
                    dst[(size_t)row * 1024 + (col & 1023)] = x;
                } else {
                    C0[(size_t)row * N + col] = x;
                }
            }
        }
    }
}

// ---------------------------------------------------------------------------
// Short causal conv (K=4) + SiLU.
// ---------------------------------------------------------------------------
template<int OUT_BF16>
__global__ __launch_bounds__(256)
void shortconv(const float* __restrict__ x, const float* __restrict__ w,
               float* __restrict__ yf, bf16* __restrict__ yb)
{
    size_t idx = (size_t)blockIdx.x * 256 + threadIdx.x;
    if (idx >= (size_t)R_TOT * DMODEL) return;
    int c = (int)(idx & (DMODEL - 1));
    long r = (long)(idx >> 10);
    int l = (int)(r & (LSEQ - 1));
    const float* wc = w + c * 4;
    float acc = 0.f;
#pragma unroll
    for (int j = 0; j < 4; ++j) {
        int xl = l - 3 + j;
        if (xl >= 0) acc += x[(r - l + xl) * DMODEL + c] * wc[j];
    }
    float y = acc * sigmoidf_(acc);
    if (OUT_BF16) yb[idx] = __float2bfloat16(y);
    else          yf[idx] = y;
}

// ---------------------------------------------------------------------------
// Phase 1: per-(b,h,chunk) prep.  bf16 in (qconv,kconv,v), bf16 out (qe,kn,wu,opre)
// qe = qn - attn@w ; o_pre = attn@u ; so o = qe@S + o_pre  (exact algebra)
// ---------------------------------------------------------------------------
__global__ __launch_bounds__(256)
void chunk_prep(const unsigned short* __restrict__ qconv, const unsigned short* __restrict__ kconv,
                const unsigned short* __restrict__ vbf, const float* __restrict__ beta,
                unsigned short* __restrict__ qe_out, unsigned short* __restrict__ kn_out,
                bf16* __restrict__ wu, unsigned short* __restrict__ opre)
{
    const int bid = blockIdx.x;              // (b*8+h)*128 + c
    const int c = bid & 127, h = (bid >> 7) & 7, b = bid >> 10;
    const int tid = threadIdx.x;

    __shared__ float qs[32][130], ks[32][130], vs[32][130], ws_l[32][130];
    __shared__ float Am[32][33], at[32][33];
    __shared__ float betas[32];

    const size_t row0 = (size_t)b * LSEQ + (size_t)c * 32;
    const size_t base = row0 * DMODEL + (size_t)h * DHEAD;

    for (int idx = tid; idx < 32 * 64; idx += 256) {
        int i = idx >> 6, d2 = (idx & 63) << 1;
        size_t g = base + (size_t)i * DMODEL + d2;
        unsigned uq = *(const unsigned*)(qconv + g);
        unsigned uk = *(const unsigned*)(kconv + g);
        unsigned uv = *(const unsigned*)(vbf + g);
        qs[i][d2] = bf2f((unsigned short)uq); qs[i][d2 + 1] = bf2f((unsigned short)(uq >> 16));
        ks[i][d2] = bf2f((unsigned short)uk); ks[i][d2 + 1] = bf2f((unsigned short)(uk >> 16));
        vs[i][d2] = bf2f((unsigned short)uv); vs[i][d2 + 1] = bf2f((unsigned short)(uv >> 16));
    }
    if (tid < 32) betas[tid] = beta[(row0 + tid) * NHEAD + h];
    __syncthreads();

    {
        int row = tid >> 3, ln = tid & 7;
        float sq = 0.f, sk = 0.f;
        for (int d = ln; d < 128; d += 8) {
            float a_ = qs[row][d]; sq += a_ * a_;
            float b_ = ks[row][d]; sk += b_ * b_;
        }
#pragma unroll
        for (int m = 1; m < 8; m <<= 1) { sq += __shfl_xor(sq, m); sk += __shfl_xor(sk, m); }
        float rq = rsqrtf(sq + 1e-6f), rk = rsqrtf(sk + 1e-6f);
        for (int d = ln; d < 128; d += 8) { qs[row][d] *= rq; ks[row][d] *= rk; }
    }
    __syncthreads();

    {
        int i0 = tid >> 5, j = tid & 31;
#pragma unroll
        for (int qd = 0; qd < 4; ++qd) {
            int i = i0 + qd * 8;
            float dk0 = 0.f, dk1 = 0.f, dq0 = 0.f, dq1 = 0.f;
#pragma unroll 8
            for (int d = 0; d < 128; d += 2) {
                float kj0 = ks[j][d], kj1 = ks[j][d + 1];
                dk0 += ks[i][d] * kj0; dk1 += ks[i][d + 1] * kj1;
                dq0 += qs[i][d] * kj0; dq1 += qs[i][d + 1] * kj1;
            }
            Am[i][j] = (i > j)  ? betas[i] * (dk0 + dk1) : 0.f;
            at[i][j] = (i >= j) ? (dq0 + dq1) : 0.f;
        }
    }
    __syncthreads();

    {
        float x[32];
        int t = tid;
        if (t < 128) {
#pragma unroll
            for (int i = 0; i < 32; ++i) x[i] = betas[i] * vs[i][t];
        } else {
            int d = t - 128;
#pragma unroll
            for (int i = 0; i < 32; ++i) x[i] = betas[i] * ks[i][d];
        }
#pragma unroll
        for (int i = 1; i < 32; ++i) {
            float s = 0.f;
#pragma unroll
            for (int m = 0; m < i; ++m) s = fmaf(Am[i][m], x[m], s);
            x[i] -= s;
        }
        const size_t tb = (size_t)bid * 8192;
        if (t < 128) {
#pragma unroll
            for (int i = 0; i < 32; ++i) {
                wu[tb + 4096 + i * 128 + t] = __float2bfloat16(x[i]);  // u
                vs[i][t] = x[i];
            }
        } else {
            int d = t - 128;
#pragma unroll
            for (int i = 0; i < 32; ++i) {
                wu[tb + i * 128 + d] = __float2bfloat16(x[i]);          // w
                ws_l[i][d] = x[i];
            }
        }
    }
    __syncthreads();

    for (int idx = tid; idx < 2048; idx += 256) {
        int i = idx >> 6, d2 = (idx & 63) << 1;
        float sa = 0.f, sb = 0.f, s2a = 0.f, s2b = 0.f;
#pragma unroll
        for (int j = 0; j < 32; ++j) {
            float a = at[i][j];
            sa  = fmaf(a, ws_l[j][d2], sa);
            sb  = fmaf(a, ws_l[j][d2 + 1], sb);
            s2a = fmaf(a, vs[j][d2], s2a);
            s2b = fmaf(a, vs[j][d2 + 1], s2b);
        }
        size_t g = base + (size_t)i * DMODEL + d2;
        unsigned uq = (unsigned)f2bf(qs[i][d2] - sa) | ((unsigned)f2bf(qs[i][d2 + 1] - sb) << 16);
        unsigned uk = (unsigned)f2bf(ks[i][d2]) | ((unsigned)f2bf(ks[i][d2 + 1]) << 16);
        unsigned uo = (unsigned)f2bf(s2a) | ((unsigned)f2bf(s2b) << 16);
        *(unsigned*)(qe_out + g) = uq;
        *(unsigned*)(kn_out + g) = uk;
        *(unsigned*)(opre + g) = uo;
    }
}

// ---------------------------------------------------------------------------
// Phase 2: MFMA state scan. 256 blocks = (b,h,dv-slice 16) x 4 waves.
// bid relabeled so the 8 dv-slice siblings of one (b,h) share bid%8 (same XCD
// under round-robin dispatch) -> redundant qe/kn/w reads become L2 hits.
// ---------------------------------------------------------------------------
__global__ __launch_bounds__(256)
void delta_scan3(const unsigned short* __restrict__ qe, const unsigned short* __restrict__ kn,
                 const bf16* __restrict__ wu, bf16* __restrict__ delta,
                 const float* __restrict__ ret)
{
    const int bid0 = blockIdx.x;
    const int dvs = (bid0 >> 3) & 7;                      // dv-slice
    const int bh  = ((bid0 >> 6) << 3) | (bid0 & 7);      // xcd-stable bh
    const int h = bh & 7, b = bh >> 3;
    const int tid = threadIdx.x;
    const int l = tid & 63, wid = tid >> 6;

    __shared__ __align__(16) unsigned short qe_b[32 * 136];
    __shared__ __align__(16) unsigned short w_b [32 * 136];
    __shared__ __align__(16) unsigned short knT [128 * 40];
    __shared__ __align__(16) unsigned short St_b[16 * 136];
    __shared__ __align__(16) unsigned short uaT [16 * 40];
    __shared__ float us_s[32][18], ops_s[32][18];

    const float lam = 0.6f + 0.4f * sigmoidf_(ret[h]);

    for (int i = tid; i < 16 * 136; i += 256) St_b[i] = 0;

    const int li = tid >> 3, ld0 = (tid & 7) * 16;
    const int iu = tid >> 3, tu = (tid & 7) * 2;
    const size_t headoff = (size_t)h * DHEAD;

    const f4v zf = {0.f, 0.f, 0.f, 0.f};
    f4v Sacc0 = zf, Sacc1 = zf;        // this wave's S d-tiles (d0 = wid*32)

    uint4 pq[2], pk[2], pw[2];
    unsigned puv, pov;

#define ISSUE(cc)  {                                                                        \
        size_t rb = ((size_t)b * LSEQ + (size_t)(cc) * 32);                                 \
        const unsigned short* gq = qe + (rb + li) * DMODEL + headoff + ld0;                 \
        const unsigned short* gk = kn + (rb + li) * DMODEL + headoff + ld0;                 \
        pq[0] = ((const uint4*)gq)[0]; pq[1] = ((const uint4*)gq)[1];                       \
        pk[0] = ((const uint4*)gk)[0]; pk[1] = ((const uint4*)gk)[1];                       \
        size_t tb = ((size_t)bh * NCHUNK + (cc)) * 8192;                                    \
        const uint4* gw = (const uint4*)(wu + tb + li * 128 + ld0);                         \
        pw[0] = gw[0]; pw[1] = gw[1];                                                       \
        puv = *(const unsigned*)(wu + tb + 4096 + iu * 128 + dvs * 16 + tu);                \
        pov = *(const unsigned*)(delta + (rb + iu) * DMODEL + headoff + dvs * 16 + tu);     \
    }

    ISSUE(0);

    for (int c = 0; c < NCHUNK; ++c) {
        // ---- unpack prefetched regs -> LDS (qe, w direct; kn -> knT transpose)
        *(uint4*)&qe_b[li * 136 + ld0]     = pq[0];
        *(uint4*)&qe_b[li * 136 + ld0 + 8] = pq[1];
        {
            const unsigned short* pks = (const unsigned short*)&pk[0];
#pragma unroll
            for (int e = 0; e < 16; ++e)
                knT[(ld0 + e) * 40 + li] = pks[e];
        }
        *(uint4*)&w_b[li * 136 + ld0]     = pw[0];
        *(uint4*)&w_b[li * 136 + ld0 + 8] = pw[1];
        {
            us_s[iu][tu]      = bf2f((unsigned short)puv);
            us_s[iu][tu + 1]  = bf2f((unsigned short)(puv >> 16));
            ops_s[iu][tu]     = bf2f((unsigned short)pov);
            ops_s[iu][tu + 1] = bf2f((unsigned short)(pov >> 16));
        }
        if (c + 1 < NCHUNK) ISSUE(c + 1);
        __syncthreads();

        // ---- phase A: waves 0,1 -> ua = u - w@S ; waves 2,3 -> o = opre + qe@S
        {
            const int half = wid & 1;
            const int arow = half * 16 + (l & 15);
            const int koff = (l >> 4) * 8;
            const unsigned short* ab = (wid < 2) ? w_b : qe_b;
            f4v a = zf;
#pragma unroll
            for (int kt = 0; kt < 4; ++kt) {
                s8v af  = *(const s8v*)&ab[arow * 136 + kt * 32 + koff];
                s8v bf_ = *(const s8v*)&St_b[(l & 15) * 136 + kt * 32 + koff];
                a = __builtin_amdgcn_mfma_f32_16x16x32_bf16(af, bf_, a, 0, 0, 0);
            }
            const int ib = half * 16 + ((l >> 4) << 2);
            const int t = l & 15;
            if (wid < 2) {
#pragma unroll
                for (int q = 0; q < 4; ++q) {
                    float v = us_s[ib + q][t] - a[q];
                    uaT[t * 40 + ib + q] = f2bf(v);
                }
            } else {
                size_t rb = (size_t)b * LSEQ + (size_t)c * 32;
#pragma unroll
                for (int q = 0; q < 4; ++q) {
                    float v = ops_s[ib + q][t] + a[q];
                    delta[(rb + ib + q) * DMODEL + headoff + dvs * 16 + t] = __float2bfloat16(v);
                }
            }
        }
        __syncthreads();

        // ---- phase B: Sacc = lam*Sacc + uaT @ knT ; export bf16 St_b
        {
#pragma unroll
            for (int q = 0; q < 4; ++q) { Sacc0[q] *= lam; Sacc1[q] *= lam; }
            const int koff = (l >> 4) * 8;
            s8v af = *(const s8v*)&uaT[(l & 15) * 40 + koff];
            const int d0 = wid * 32;
            s8v b0 = *(const s8v*)&knT[(d0 + (l & 15)) * 40 + koff];
            s8v b1 = *(const s8v*)&knT[(d0 + 16 + (l & 15)) * 40 + koff];
            Sacc0 = __builtin_amdgcn_mfma_f32_16x16x32_bf16(af, b0, Sacc0, 0, 0, 0);
            Sacc1 = __builtin_amdgcn_mfma_f32_16x16x32_bf16(af, b1, Sacc1, 0, 0, 0);
            const int tr = (l >> 4) << 2;
#pragma unroll
            for (int q = 0; q < 4; ++q) {
                St_b[(tr + q) * 136 + d0 + (l & 15)]      = f2bf(Sacc0[q]);
                St_b[(tr + q) * 136 + d0 + 16 + (l & 15)] = f2bf(Sacc1[q]);
            }
        }
        __syncthreads();
    }
#undef ISSUE
}

// ---------------------------------------------------------------------------
// FIR computed once, LDS-tiled (unchanged, round-4/5 verified)
// ---------------------------------------------------------------------------
__global__ __launch_bounds__(256)
void fir_compute(const unsigned short* __restrict__ v,
                 const float* __restrict__ wshort, const float* __restrict__ wlong,
                 unsigned short* __restrict__ fso, unsigned short* __restrict__ flo)
{
    const int lt = blockIdx.x, h = blockIdx.y, b = blockIdx.z;
    const int tid = threadIdx.x;
    __shared__ unsigned short vt[190 * 128];
    __shared__ float wl[63 * 128];
    __shared__ float w3[3 * 128];

    for (int i = tid; i < 63 * 128; i += 256) {
        int j = i >> 7, d = i & 127;
        wl[i] = wlong[((size_t)h * 128 + d) * 63 + j];
    }
    for (int i = tid; i < 3 * 128; i += 256) {
        int j = i >> 7, d = i & 127;
        w3[i] = wshort[((size_t)h * 128 + d) * 3 + j];
    }
    const size_t vbase = ((size_t)b * LSEQ) * DMODEL + (size_t)h * DHEAD;
    const int l0 = lt * 128;
    const s8v z8 = {0, 0, 0, 0, 0, 0, 0, 0};
    for (int i = tid; i < 190 * 16; i += 256) {
        int row = i >> 4, dblk = (i & 15) * 8;
        int gl = l0 - 62 + row;
        s8v val = z8;
        if (gl >= 0) val = *(const s8v*)&v[vbase + (size_t)gl * DMODEL + dblk];
        *(s8v*)&vt[row * 128 + dblk] = val;
    }
    __syncthreads();

    const int dp = (tid & 63) * 2, lg = tid >> 6;
    for (int lc = 0; lc < 4; ++lc) {
        const int lb = lg * 32 + lc * 8;
        float a0[8], a1[8], s0[8], s1[8];
#pragma unroll
        for (int li = 0; li < 8; ++li) { a0[li] = a1[li] = s0[li] = s1[li] = 0.f; }
        for (int j = 0; j < 63; ++j) {
            float w0 = wl[j * 128 + dp], w1 = wl[j * 128 + dp + 1];
#pragma unroll
            for (int li = 0; li < 8; ++li) {
                unsigned vv = *(const unsigned*)&vt[(lb + li + j) * 128 + dp];
                a0[li] = fmaf(bf2f((unsigned short)vv), w0, a0[li]);
                a1[li] = fmaf(bf2f((unsigned short)(vv >> 16)), w1, a1[li]);
            }
        }
#pragma unroll
        for (int j = 0; j < 3; ++j) {
            float w0 = w3[j * 128 + dp], w1 = w3[j * 128 + dp + 1];
#pragma unroll
            for (int li = 0; li < 8; ++li) {
                unsigned vv = *(const unsigned*)&vt[(lb + li + 60 + j) * 128 + dp];
                s0[li] = fmaf(bf2f((unsigned short)vv), w0, s0[li]);
                s1[li] = fmaf(bf2f((unsigned short)(vv >> 16)), w1, s1[li]);
            }
        }
        const size_t ob = ((size_t)b * LSEQ + l0) * DMODEL + (size_t)h * DHEAD + dp;
#pragma unroll
        for (int li = 0; li < 8; ++li) {
            unsigned pf = (unsigned)f2bf(a0[li]) | ((unsigned)f2bf(a1[li]) << 16);
            unsigned ps = (unsigned)f2bf(s0[li]) | ((unsigned)f2bf(s1[li]) << 16);
            *(unsigned*)&flo[ob + (size_t)(lb + li) * DMODEL] = pf;
            *(unsigned*)&fso[ob + (size_t)(lb + li) * DMODEL] = ps;
        }
    }
}

// ---------------------------------------------------------------------------
// Stats: one wave per (r,h) row (unchanged)
// ---------------------------------------------------------------------------
__global__ __launch_bounds__(256)
void fir_stats2(const unsigned short* __restrict__ fs, const unsigned short* __restrict__ fl,
                const unsigned short* __restrict__ dlt, const unsigned short* __restrict__ v,
                float* __restrict__ stats)
{
    const int rh = blockIdx.x * 4 + (threadIdx.x >> 6);
    const int lane = threadIdx.x & 63;
    const int r = rh >> 3, h = rh & 7;
    const size_t base = (size_t)r * DMODEL + (size_t)h * DHEAD + lane * 2;
    unsigned ua = *(const unsigned*)(fs + base);
    unsigned ub = *(const unsigned*)(fl + base);
    unsigned uc = *(const unsigned*)(dlt + base);
    unsigned ud = *(const unsigned*)(v + base);
    float s0 = bf2f((unsigned short)ua) + bf2f((unsigned short)(ua >> 16));
    float s1 = bf2f((unsigned short)ub) + bf2f((unsigned short)(ub >> 16));
    float s2 = bf2f((unsigned short)uc) + bf2f((unsigned short)(uc >> 16));
    float s3 = bf2f((unsigned short)ud) + bf2f((unsigned short)(ud >> 16));
#pragma unroll
    for (int m = 1; m < 64; m <<= 1) {
        s0 += __shfl_xor(s0, m); s1 += __shfl_xor(s1, m);
        s2 += __shfl_xor(s2, m); s3 += __shfl_xor(s3, m);
    }
    if (lane == 0) {
        const float inv = 1.f / 128.f;
        stats[(size_t)r * 32 + 0  + h] = s0 * inv;
        stats[(size_t)r * 32 + 8  + h] = s1 * inv;
        stats[(size_t)r * 32 + 16 + h] = s2 * inv;
        stats[(size_t)r * 32 + 24 + h] = s3 * inv;
    }
}

// ---------------------------------------------------------------------------
// Combine + RMS norm (unchanged)
// ---------------------------------------------------------------------------
__global__ __launch_bounds__(256)
void combine2(const unsigned short* __restrict__ fs, const unsigned short* __restrict__ fl,
              const unsigned short* __restrict__ dlt, const unsigned short* __restrict__ v,
              const float* __restrict__ p, const float* __restrict__ onw,
              float* __restrict__ on)
{
    const int rh = blockIdx.x * 4 + (threadIdx.x >> 6);
    const int lane = threadIdx.x & 63;
    const int r = rh >> 3, h = rh & 7;
    const size_t base = (size_t)r * DMODEL + (size_t)h * DHEAD + lane * 2;
    unsigned ua = *(const unsigned*)(fs + base);
    unsigned ub = *(const unsigned*)(fl + base);
    unsigned uc = *(const unsigned*)(dlt + base);
    unsigned ud = *(const unsigned*)(v + base);
    const float* pp = p + (size_t)r * 32 + h * 4;
    float p0 = pp[0], p1 = pp[1], p2 = pp[2], p3 = pp[3];
    float ox = p0 * bf2f((unsigned short)ua) + p1 * bf2f((unsigned short)ub)
             + p2 * bf2f((unsigned short)uc) + p3 * bf2f((unsigned short)ud);
    float oy = p0 * bf2f((unsigned short)(ua >> 16)) + p1 * bf2f((unsigned short)(ub >> 16))
             + p2 * bf2f((unsigned short)(uc >> 16)) + p3 * bf2f((unsigned short)(ud >> 16));
    float ss = ox * ox + oy * oy;
#pragma unroll
    for (int m = 1; m < 64; m <<= 1) ss += __shfl_xor(ss, m);
    float sc = rsqrtf(ss * (1.f / 128.f) + 1e-5f);
    float2 o2 = make_float2(ox * sc * onw[lane * 2], oy * sc * onw[lane * 2 + 1]);
    *(float2*)(on + base) = o2;
}

// ---------------------------------------------------------------------------
// Workspace (~203.5 MB):
//  bufA: q_pre fp32 -> kconv/kn bf16 (lower 32MB) -> o_norm fp32
//  bufB: k_pre fp32 -> [lo 32MB: v bf16][hi 32MB: o_pre/delta bf16]
//  bufC: v_pre fp32 -> w|u bf16 tiles -> [lo: fs bf16][hi: fl bf16]
//  d_out: Wqkv_t bf16 -> qconv/qe bf16 -> hdn fp32 -> final out
// ---------------------------------------------------------------------------
extern "C" void kernel_launch(void* const* d_in, const int* in_sizes, int n_in,
                              void* d_out, int out_size, void* d_ws, size_t ws_size,
                              hipStream_t stream)
{
    const float* hs   = (const float*)d_in[0];
    const float* Wq   = (const float*)d_in[1];
    const float* Wk   = (const float*)d_in[2];
    const float* Wv   = (const float*)d_in[3];
    const float* Wb   = (const float*)d_in[4];
    const float* cqw  = (const float*)d_in[5];
    const float* ckw  = (const float*)d_in[6];
    const float* cvw  = (const float*)d_in[7];
    const float* ret  = (const float*)d_in[8];
    const float* fsw  = (const float*)d_in[9];
    const float* flw  = (const float*)d_in[10];
    const float* gw1  = (const float*)d_in[11];
    const float* gb1  = (const float*)d_in[12];
    const float* gw2  = (const float*)d_in[13];
    const float* gb2  = (const float*)d_in[14];
    const float* ltmp = (const float*)d_in[15];
    const float* onw  = (const float*)d_in[16];
    const float* Wo   = (const float*)d_in[17];
    float* out = (float*)d_out;

    char* wsp = (char*)d_ws;
    size_t off = 0;
    auto alloc = [&](size_t nbytes) -> void* {
        void* pt = (void*)(wsp + off);
        off += ((nbytes + 255) / 256) * 256;
        return pt;
    };
    const int R = R_TOT;
    float* bufA  = (float*)alloc((size_t)R * DMODEL * 4);
    float* bufB  = (float*)alloc((size_t)R * DMODEL * 4);
    float* bufC  = (float*)alloc((size_t)R * DMODEL * 4);
    float* beta  = (float*)alloc((size_t)R * NHEAD * 4);
    float* stats = (float*)alloc((size_t)R * 32 * 4);
    float* pbuf  = (float*)alloc((size_t)R * 32 * 4);
    unsigned short* gw1t = (unsigned short*)alloc((size_t)2048 * 1056 * 2);
    unsigned short* wot  = (unsigned short*)alloc((size_t)1024 * 1024 * 2);
    unsigned short* wbt  = (unsigned short*)alloc((size_t)128 * 1024 * 2);
    unsigned short* gw2t = (unsigned short*)alloc((size_t)128 * 2048 * 2);
    float* bufO = out;
    unsigned short* qcb = (unsigned short*)bufO;     // qconv/qe bf16 (32MB)
    unsigned short* kcb = (unsigned short*)bufA;     // kconv/kn bf16 (32MB)
    unsigned short* vbf = (unsigned short*)bufB;     // v bf16 (lower 32MB)
    unsigned short* dlt = (unsigned short*)bufB + (size_t)R * DMODEL;  // upper 32MB
    bf16* wu   = (bf16*)bufC;
    unsigned short* fsb = (unsigned short*)bufC;
    unsigned short* flb = (unsigned short*)bufC + (size_t)R * DMODEL;
    unsigned short* wqkvt = (unsigned short*)bufO;   // 3072x1024 bf16 = 6MB
    (void)ws_size; (void)in_sizes; (void)n_in; (void)out_size;

    dim3 blk(256);
    // 1. weight transposes / pads
    tcast<<<dim3(32, 32), blk, 0, stream>>>(Wq, wqkvt, 1024, 1024, 1024);
    tcast<<<dim3(32, 32), blk, 0, stream>>>(Wk, wqkvt + (size_t)1024 * 1024, 1024, 1024, 1024);
    tcast<<<dim3(32, 32), blk, 0, stream>>>(Wv, wqkvt + (size_t)2048 * 1024, 1024, 1024, 1024);
    tcast<<<dim3(33, 64), blk, 0, stream>>>(gw1, gw1t, 1056, 2048, 2048);
    tcast<<<dim3(32, 32), blk, 0, stream>>>(Wo, wot, 1024, 1024, 1024);
    tcast<<<dim3(32, 4),  blk, 0, stream>>>(Wb, wbt, 1024, 8, 128);
    tcast<<<dim3(64, 4),  blk, 0, stream>>>(gw2, gw2t, 2048, 32, 128);

    // 2. fused qkv projection (MFMA)
    mgemm<4><<<dim3(24, 128), blk, 0, stream>>>(hs, nullptr, 1 << 30, DMODEL, 0,
                                                wqkvt, nullptr, nullptr,
                                                bufA, bufB, bufC, R, 3072, 1024, 0);
    // 3. beta = sigmoid(hs @ Wb)  (MFMA, padded N)
    mgemm<1><<<dim3(1, 128), blk, 0, stream>>>(hs, nullptr, 1 << 30, DMODEL, 0,
                                               wbt, nullptr, nullptr,
                                               beta, nullptr, nullptr, R, 128, 1024, 8);
    // 4. short conv + silu (bf16 outputs): q: A->O, k: B->A, v: C->B.lo
    int convGrid = (int)(((size_t)R * DMODEL + 255) / 256);
    shortconv<1><<<convGrid, blk, 0, stream>>>(bufA, cqw, nullptr, (bf16*)qcb);
    shortconv<1><<<convGrid, blk, 0, stream>>>(bufB, ckw, nullptr, (bf16*)kcb);
    shortconv<1><<<convGrid, blk, 0, stream>>>(bufC, cvw, nullptr, (bf16*)vbf);
    // 5/6. delta rule (all-bf16 streams)
    chunk_prep<<<4096, blk, 0, stream>>>(qcb, kcb, vbf, beta, qcb, kcb, wu, dlt);
    delta_scan3<<<256, blk, 0, stream>>>(qcb, kcb, wu, (bf16*)dlt, ret);
    // 7. FIR once (wu dead -> bufC holds fs|fl)
    fir_compute<<<dim3(32, 8, 4), blk, 0, stream>>>(vbf, fsw, flw, fsb, flb);
    // 8. stats
    fir_stats2<<<32768, blk, 0, stream>>>(fsb, flb, dlt, vbf, stats);
    // 9. gate MLP (two row-chunks; hdn fp32 in d_out scratch, qe dead)
    const int RC = 8192;
    float* hdn = bufO;
    for (int r0 = 0; r0 < R; r0 += RC) {
        mgemm<2><<<dim3(16, RC / 128), blk, 0, stream>>>(hs + (size_t)r0 * DMODEL,
                                                         stats + (size_t)r0 * 32,
                                                         1024, DMODEL, 32, gw1t, gb1, nullptr,
                                                         hdn, nullptr, nullptr,
                                                         RC, 2048, 1056, 0);
        mgemm<3><<<dim3(1, RC / 128), blk, 0, stream>>>(hdn, nullptr, 1 << 30, 2048, 0,
                                                        gw2t, gb2, ltmp,
                                                        pbuf + (size_t)r0 * 32, nullptr, nullptr,
                                                        RC, 128, 2048, 32);
    }
    // 10. combine + RMS norm -> bufA fp32 (kn dead)
    combine2<<<32768, blk, 0, stream>>>(fsb, flb, dlt, vbf, pbuf, onw, bufA);
    // 11. final projection (MFMA) -> d_out
    mgemm<0><<<dim3(8, 128), blk, 0, stream>>>(bufA, nullptr, 1 << 30, DMODEL, 0,
                                               wot, nullptr, nullptr,
                                               out, nullptr, nullptr, R, 1024, 1024, 0);
}

// Round 7
// 1537.522 us; speedup vs baseline: 11.5130x; 1.0530x over previous
//
#include <hip/hip_runtime.h>
#include <hip/hip_bf16.h>
#include <math.h>

#define R_TOT 16384      // B*L
#define LSEQ  4096
#define DMODEL 1024
#define NHEAD 8
#define DHEAD 128        // DK = DV
#define NCHUNK 128       // LSEQ/32

typedef __hip_bfloat16 bf16;
typedef short s8v __attribute__((ext_vector_type(8)));
typedef float f4v __attribute__((ext_vector_type(4)));

__device__ __forceinline__ float sigmoidf_(float x) { return 1.f / (1.f + expf(-x)); }
__device__ __forceinline__ unsigned short f2bf(float f) {
    unsigned u = __float_as_uint(f);
    u += 0x7fffu + ((u >> 16) & 1u);
    return (unsigned short)(u >> 16);
}
__device__ __forceinline__ float bf2f(unsigned short s) {
    return __uint_as_float(((unsigned)s) << 16);
}

// ---------------------------------------------------------------------------
// Transpose-cast: W (K x N fp32) -> Wt (Npad x K bf16), zero-padded rows N..Npad
// ---------------------------------------------------------------------------
__global__ __launch_bounds__(256)
void tcast(const float* __restrict__ W, unsigned short* __restrict__ Wt,
           int K, int N, int Npad)
{
    __shared__ float t[32][33];
    const int kb = blockIdx.x * 32, nb = blockIdx.y * 32;
    const int tx = threadIdx.x & 31, ty = threadIdx.x >> 5;   // ty 0..7
    for (int i = ty; i < 32; i += 8) {
        int k = kb + i, n = nb + tx;
        t[i][tx] = (k < K && n < N) ? W[(size_t)k * N + n] : 0.f;
    }
    __syncthreads();
    for (int i = ty; i < 32; i += 8) {
        int n = nb + i, k = kb + tx;
        if (n < Npad && k < K) Wt[(size_t)n * K + k] = f2bf(t[tx][i]);
    }
}

// ---------------------------------------------------------------------------
// MFMA bf16 GEMM: C = epi(A @ Bt^T), A fp32 MxK (split A/A2 at Ksplit),
// Bt = bf16 N x K row-major. Tile 128x128x32, 256 thr = 4 waves.
// MODE 0: none  1: sigmoid (store col<Nout, stride Nout)
// MODE 2: gelu(x+bias)  3: p-gate (store col<Nout, stride Nout)
// MODE 4: qkv split (col/1024 -> C0/C1/C2)
// ---------------------------------------------------------------------------
template<int MODE>
__global__ __launch_bounds__(256)
void mgemm(const float* __restrict__ A, const float* __restrict__ A2, int Ksplit,
           int lda1, int lda2,
           const unsigned short* __restrict__ Bt,
           const float* __restrict__ bias, const float* __restrict__ aux,
           float* __restrict__ C0, float* __restrict__ C1, float* __restrict__ C2,
           int M, int N, int K, int Nout)
{
    __shared__ unsigned short As[128 * 40];
    __shared__ unsigned short Bs[128 * 40];
    const int tid = threadIdx.x;
    const int m0 = blockIdx.y * 128, n0 = blockIdx.x * 128;
    const int l = tid & 63;
    const int wr = (tid >> 7) & 1, wc = (tid >> 6) & 1;
    const int sr = tid >> 1, sh = (tid & 1) * 16;

    const f4v zf = {0.f, 0.f, 0.f, 0.f};
    f4v acc[4][4];
#pragma unroll
    for (int i = 0; i < 4; ++i)
#pragma unroll
        for (int j = 0; j < 4; ++j) acc[i][j] = zf;

    const int nkt = K >> 5;
    for (int kt = 0; kt < nkt; ++kt) {
        const int k0 = kt << 5;
        {
            const float* src = (k0 < Ksplit)
                ? A  + (size_t)(m0 + sr) * lda1 + (size_t)(k0 + sh)
                : A2 + (size_t)(m0 + sr) * lda2 + (size_t)(k0 - Ksplit + sh);
            float4 v0 = ((const float4*)src)[0];
            float4 v1 = ((const float4*)src)[1];
            float4 v2 = ((const float4*)src)[2];
            float4 v3 = ((const float4*)src)[3];
            s8v w0, w1;
            w0[0] = (short)f2bf(v0.x); w0[1] = (short)f2bf(v0.y);
            w0[2] = (short)f2bf(v0.z); w0[3] = (short)f2bf(v0.w);
            w0[4] = (short)f2bf(v1.x); w0[5] = (short)f2bf(v1.y);
            w0[6] = (short)f2bf(v1.z); w0[7] = (short)f2bf(v1.w);
            w1[0] = (short)f2bf(v2.x); w1[1] = (short)f2bf(v2.y);
            w1[2] = (short)f2bf(v2.z); w1[3] = (short)f2bf(v2.w);
            w1[4] = (short)f2bf(v3.x); w1[5] = (short)f2bf(v3.y);
            w1[6] = (short)f2bf(v3.z); w1[7] = (short)f2bf(v3.w);
            *(s8v*)&As[sr * 40 + sh]     = w0;
            *(s8v*)&As[sr * 40 + sh + 8] = w1;
        }
        {
            const unsigned short* src = Bt + (size_t)(n0 + sr) * K + (size_t)(k0 + sh);
            s8v b0 = ((const s8v*)src)[0];
            s8v b1 = ((const s8v*)src)[1];
            *(s8v*)&Bs[sr * 40 + sh]     = b0;
            *(s8v*)&Bs[sr * 40 + sh + 8] = b1;
        }
        __syncthreads();
        const int fr = l & 15, fq = (l >> 4) * 8;
        s8v af[4], bfr[4];
#pragma unroll
        for (int i = 0; i < 4; ++i) {
            af[i]  = *(const s8v*)&As[(wr * 64 + i * 16 + fr) * 40 + fq];
            bfr[i] = *(const s8v*)&Bs[(wc * 64 + i * 16 + fr) * 40 + fq];
        }
#pragma unroll
        for (int i = 0; i < 4; ++i)
#pragma unroll
            for (int j = 0; j < 4; ++j)
                acc[i][j] = __builtin_amdgcn_mfma_f32_16x16x32_bf16(af[i], bfr[j], acc[i][j], 0, 0, 0);
        __syncthreads();
    }
    const int fr = l & 15, fq4 = (l >> 4) * 4;
#pragma unroll
    for (int i = 0; i < 4; ++i) {
#pragma unroll
        for (int j = 0; j < 4; ++j) {
            int col = n0 + wc * 64 + j * 16 + fr;
            if ((MODE == 1 || MODE == 3) && col >= Nout) continue;
#pragma unroll
            for (int q = 0; q < 4; ++q) {
                int row = m0 + wr * 64 + i * 16 + fq4 + q;
                float x = acc[i][j][q];
                if (MODE == 1) {
                    x = sigmoidf_(x);
                    C0[(size_t)row * Nout + col] = x;
                } else if (MODE == 2) {
                    x += bias[col];
                    x = 0.5f * x * (1.f + erff(x * 0.70710678118654752f));
                    C0[(size_t)row * N + col] = x;
                } else if (MODE == 3) {
                    x += bias[col];
                    x *= expf(-aux[col >> 2]);
                    x = 0.02f + 0.98f * sigmoidf_(x);
                    C0[(size_t)row * Nout + col] = x;
                } else if (MODE == 4) {
                    float* dst = (col < 1024) ? C0 : ((col < 2048) ? C1 : C2);
                    dst[(size_t)row * 1024 + (col & 1023)] = x;
                } else {
                    C0[(size_t)row * N + col] = x;
                }
            }
        }
    }
}

// ---------------------------------------------------------------------------
// Short causal conv (K=4) + SiLU.
// ---------------------------------------------------------------------------
template<int OUT_BF16>
__global__ __launch_bounds__(256)
void shortconv(const float* __restrict__ x, const float* __restrict__ w,
               float* __restrict__ yf, bf16* __restrict__ yb)
{
    size_t idx = (size_t)blockIdx.x * 256 + threadIdx.x;
    if (idx >= (size_t)R_TOT * DMODEL) return;
    int c = (int)(idx & (DMODEL - 1));
    long r = (long)(idx >> 10);
    int l = (int)(r & (LSEQ - 1));
    const float* wc = w + c * 4;
    float acc = 0.f;
#pragma unroll
    for (int j = 0; j < 4; ++j) {
        int xl = l - 3 + j;
        if (xl >= 0) acc += x[(r - l + xl) * DMODEL + c] * wc[j];
    }
    float y = acc * sigmoidf_(acc);
    if (OUT_BF16) yb[idx] = __float2bfloat16(y);
    else          yf[idx] = y;
}

// ---------------------------------------------------------------------------
// Phase 1: per-(b,h,chunk) prep, MFMA version.  bf16 in/out.
// Am = tril(beta kn knT, -1) [fp32]; at = tril(qn knT) [bf16];
// forward-sub (I+Am)x = rhs (fp32, per-column regs) -> w,u (bf16, also
// transposed into LDS); qe = qn - at@w, o_pre = at@u via MFMA.
// LDS ~52KB -> 3 blocks/CU.
// ---------------------------------------------------------------------------
__global__ __launch_bounds__(256)
void chunk_prep2(const unsigned short* __restrict__ qconv, const unsigned short* __restrict__ kconv,
                 const unsigned short* __restrict__ vbf, const float* __restrict__ beta,
                 unsigned short* __restrict__ qe_out, unsigned short* __restrict__ kn_out,
                 bf16* __restrict__ wu, unsigned short* __restrict__ opre)
{
    const int bid = blockIdx.x;              // (b*8+h)*128 + c
    const int c = bid & 127, h = (bid >> 7) & 7, b = bid >> 10;
    const int tid = threadIdx.x;
    const int l = tid & 63, wid = tid >> 6;

    __shared__ __align__(16) unsigned short q_b[32 * 136];
    __shared__ __align__(16) unsigned short k_b[32 * 136];
    __shared__ __align__(16) unsigned short v_b[32 * 136];
    __shared__ __align__(16) unsigned short at_b[32 * 40];
    __shared__ __align__(16) unsigned short wT[128 * 40];
    __shared__ __align__(16) unsigned short uT[128 * 40];
    __shared__ float Am[32][33];
    __shared__ float betas_s[32];

    const size_t row0 = (size_t)b * LSEQ + (size_t)c * 32;
    const size_t base = row0 * DMODEL + (size_t)h * DHEAD;
    const f4v zf = {0.f, 0.f, 0.f, 0.f};

    // ---- load q,k,v rows (bf16, vectorized)
    {
        const int li = tid >> 3, ld0 = (tid & 7) * 16;
        const unsigned short* gq = qconv + base + (size_t)li * DMODEL + ld0;
        const unsigned short* gk = kconv + base + (size_t)li * DMODEL + ld0;
        const unsigned short* gv = vbf   + base + (size_t)li * DMODEL + ld0;
        *(uint4*)&q_b[li * 136 + ld0]     = ((const uint4*)gq)[0];
        *(uint4*)&q_b[li * 136 + ld0 + 8] = ((const uint4*)gq)[1];
        *(uint4*)&k_b[li * 136 + ld0]     = ((const uint4*)gk)[0];
        *(uint4*)&k_b[li * 136 + ld0 + 8] = ((const uint4*)gk)[1];
        *(uint4*)&v_b[li * 136 + ld0]     = ((const uint4*)gv)[0];
        *(uint4*)&v_b[li * 136 + ld0 + 8] = ((const uint4*)gv)[1];
    }
    if (tid < 32) betas_s[tid] = beta[(row0 + tid) * NHEAD + h];
    __syncthreads();

    // ---- l2norm rows of q,k (fp32 accum, bf16 write-back)
    {
        const int row = tid >> 3, d0 = (tid & 7) * 16;
        float sq = 0.f, sk = 0.f;
        float qv[16], kv[16];
#pragma unroll
        for (int e = 0; e < 8; ++e) {
            unsigned uq = *(const unsigned*)&q_b[row * 136 + d0 + e * 2];
            unsigned uk = *(const unsigned*)&k_b[row * 136 + d0 + e * 2];
            qv[e * 2] = bf2f((unsigned short)uq); qv[e * 2 + 1] = bf2f((unsigned short)(uq >> 16));
            kv[e * 2] = bf2f((unsigned short)uk); kv[e * 2 + 1] = bf2f((unsigned short)(uk >> 16));
            sq = fmaf(qv[e * 2], qv[e * 2], sq); sq = fmaf(qv[e * 2 + 1], qv[e * 2 + 1], sq);
            sk = fmaf(kv[e * 2], kv[e * 2], sk); sk = fmaf(kv[e * 2 + 1], kv[e * 2 + 1], sk);
        }
#pragma unroll
        for (int m = 1; m < 8; m <<= 1) { sq += __shfl_xor(sq, m); sk += __shfl_xor(sk, m); }
        float rq = rsqrtf(sq + 1e-6f), rk = rsqrtf(sk + 1e-6f);
#pragma unroll
        for (int e = 0; e < 8; ++e) {
            unsigned pq = (unsigned)f2bf(qv[e * 2] * rq) | ((unsigned)f2bf(qv[e * 2 + 1] * rq) << 16);
            unsigned pk = (unsigned)f2bf(kv[e * 2] * rk) | ((unsigned)f2bf(kv[e * 2 + 1] * rk) << 16);
            *(unsigned*)&q_b[row * 136 + d0 + e * 2] = pq;
            *(unsigned*)&k_b[row * 136 + d0 + e * 2] = pk;
        }
    }
    __syncthreads();

    // ---- kn write-through (vectorized)
    {
        const int li = tid >> 3, ld0 = (tid & 7) * 16;
        unsigned short* gk = kn_out + base + (size_t)li * DMODEL + ld0;
        ((uint4*)gk)[0] = *(const uint4*)&k_b[li * 136 + ld0];
        ((uint4*)gk)[1] = *(const uint4*)&k_b[li * 136 + ld0 + 8];
    }

    // ---- Am, at via MFMA: wave wid owns 16x16 tile (tr,tc) of the 32x32 outputs
    {
        const int tr = wid >> 1, tc = wid & 1;
        const int fr = l & 15, ko = (l >> 4) * 8;
        f4v accA = zf, accT = zf;
#pragma unroll
        for (int kt = 0; kt < 4; ++kt) {
            s8v ka  = *(const s8v*)&k_b[(tr * 16 + fr) * 136 + kt * 32 + ko];
            s8v qa  = *(const s8v*)&q_b[(tr * 16 + fr) * 136 + kt * 32 + ko];
            s8v kb2 = *(const s8v*)&k_b[(tc * 16 + fr) * 136 + kt * 32 + ko];
            accA = __builtin_amdgcn_mfma_f32_16x16x32_bf16(ka, kb2, accA, 0, 0, 0);
            accT = __builtin_amdgcn_mfma_f32_16x16x32_bf16(qa, kb2, accT, 0, 0, 0);
        }
        const int jloc = tc * 16 + fr;
#pragma unroll
        for (int q = 0; q < 4; ++q) {
            int iloc = tr * 16 + (l >> 4) * 4 + q;
            Am[iloc][jloc] = (iloc > jloc) ? betas_s[iloc] * accA[q] : 0.f;
            at_b[iloc * 40 + jloc] = f2bf((iloc >= jloc) ? accT[q] : 0.f);
        }
    }
    __syncthreads();

    // ---- forward substitution: (I+Am)x = rhs; thread t owns one column.
    // t<128: rhs = beta_i*v (-> u);  t>=128: rhs = beta_i*kn (-> w)
    {
        float x[32];
        const int t = tid;
        if (t < 128) {
#pragma unroll
            for (int i = 0; i < 32; ++i) x[i] = betas_s[i] * bf2f(v_b[i * 136 + t]);
        } else {
            const int d = t - 128;
#pragma unroll
            for (int i = 0; i < 32; ++i) x[i] = betas_s[i] * bf2f(k_b[i * 136 + d]);
        }
#pragma unroll
        for (int i = 1; i < 32; ++i) {
            float s = 0.f;
#pragma unroll
            for (int m = 0; m < i; ++m) s = fmaf(Am[i][m], x[m], s);
            x[i] -= s;
        }
        const size_t tb = (size_t)bid * 8192;
        if (t < 128) {
#pragma unroll
            for (int i2 = 0; i2 < 16; ++i2) {
                unsigned short b0 = f2bf(x[i2 * 2]), b1 = f2bf(x[i2 * 2 + 1]);
                *(unsigned*)&uT[t * 40 + i2 * 2] = (unsigned)b0 | ((unsigned)b1 << 16);
                wu[tb + 4096 + (i2 * 2) * 128 + t]     = __float2bfloat16(x[i2 * 2]);
                wu[tb + 4096 + (i2 * 2 + 1) * 128 + t] = __float2bfloat16(x[i2 * 2 + 1]);
            }
        } else {
            const int d = t - 128;
#pragma unroll
            for (int i2 = 0; i2 < 16; ++i2) {
                unsigned short b0 = f2bf(x[i2 * 2]), b1 = f2bf(x[i2 * 2 + 1]);
                *(unsigned*)&wT[d * 40 + i2 * 2] = (unsigned)b0 | ((unsigned)b1 << 16);
                wu[tb + (i2 * 2) * 128 + d]     = __float2bfloat16(x[i2 * 2]);
                wu[tb + (i2 * 2 + 1) * 128 + d] = __float2bfloat16(x[i2 * 2 + 1]);
            }
        }
    }
    __syncthreads();

    // ---- qe = qn - at@w ; o_pre = at@u  (MFMA, wave wid owns cols [wid*32, +32))
    {
        const int fr = l & 15, ko = (l >> 4) * 8;
        s8v a0 = *(const s8v*)&at_b[(fr) * 40 + ko];        // rt=0 rows
        s8v a1 = *(const s8v*)&at_b[(16 + fr) * 40 + ko];   // rt=1 rows
        const int ct0 = wid * 2, ct1 = wid * 2 + 1;
        s8v bw0 = *(const s8v*)&wT[(ct0 * 16 + fr) * 40 + ko];
        s8v bw1 = *(const s8v*)&wT[(ct1 * 16 + fr) * 40 + ko];
        s8v bu0 = *(const s8v*)&uT[(ct0 * 16 + fr) * 40 + ko];
        s8v bu1 = *(const s8v*)&uT[(ct1 * 16 + fr) * 40 + ko];
        f4v qw[2][2], ou[2][2];
        qw[0][0] = __builtin_amdgcn_mfma_f32_16x16x32_bf16(a0, bw0, zf, 0, 0, 0);
        qw[0][1] = __builtin_amdgcn_mfma_f32_16x16x32_bf16(a0, bw1, zf, 0, 0, 0);
        qw[1][0] = __builtin_amdgcn_mfma_f32_16x16x32_bf16(a1, bw0, zf, 0, 0, 0);
        qw[1][1] = __builtin_amdgcn_mfma_f32_16x16x32_bf16(a1, bw1, zf, 0, 0, 0);
        ou[0][0] = __builtin_amdgcn_mfma_f32_16x16x32_bf16(a0, bu0, zf, 0, 0, 0);
        ou[0][1] = __builtin_amdgcn_mfma_f32_16x16x32_bf16(a0, bu1, zf, 0, 0, 0);
        ou[1][0] = __builtin_amdgcn_mfma_f32_16x16x32_bf16(a1, bu0, zf, 0, 0, 0);
        ou[1][1] = __builtin_amdgcn_mfma_f32_16x16x32_bf16(a1, bu1, zf, 0, 0, 0);
#pragma unroll
        for (int rt = 0; rt < 2; ++rt) {
#pragma unroll
            for (int ctl = 0; ctl < 2; ++ctl) {
                const int d = (wid * 2 + ctl) * 16 + fr;
#pragma unroll
                for (int q = 0; q < 4; ++q) {
                    const int i = rt * 16 + (l >> 4) * 4 + q;
                    size_t g = base + (size_t)i * DMODEL + d;
                    float qn = bf2f(q_b[i * 136 + d]);
                    qe_out[g] = f2bf(qn - qw[rt][ctl][q]);
                    opre[g]   = f2bf(ou[rt][ctl][q]);
                }
            }
        }
    }
}

// ---------------------------------------------------------------------------
// Phase 2: MFMA state scan (unchanged, round-6 verified)
// ---------------------------------------------------------------------------
__global__ __launch_bounds__(256)
void delta_scan3(const unsigned short* __restrict__ qe, const unsigned short* __restrict__ kn,
                 const bf16* __restrict__ wu, bf16* __restrict__ delta,
                 const float* __restrict__ ret)
{
    const int bid0 = blockIdx.x;
    const int dvs = (bid0 >> 3) & 7;                      // dv-slice
    const int bh  = ((bid0 >> 6) << 3) | (bid0 & 7);      // xcd-stable bh
    const int h = bh & 7, b = bh >> 3;
    const int tid = threadIdx.x;
    const int l = tid & 63, wid = tid >> 6;

    __shared__ __align__(16) unsigned short qe_b[32 * 136];
    __shared__ __align__(16) unsigned short w_b [32 * 136];
    __shared__ __align__(16) unsigned short knT [128 * 40];
    __shared__ __align__(16) unsigned short St_b[16 * 136];
    __shared__ __align__(16) unsigned short uaT [16 * 40];
    __shared__ float us_s[32][18], ops_s[32][18];

    const float lam = 0.6f + 0.4f * sigmoidf_(ret[h]);

    for (int i = tid; i < 16 * 136; i += 256) St_b[i] = 0;

    const int li = tid >> 3, ld0 = (tid & 7) * 16;
    const int iu = tid >> 3, tu = (tid & 7) * 2;
    const size_t headoff = (size_t)h * DHEAD;

    const f4v zf = {0.f, 0.f, 0.f, 0.f};
    f4v Sacc0 = zf, Sacc1 = zf;        // this wave's S d-tiles (d0 = wid*32)

    uint4 pq[2], pk[2], pw[2];
    unsigned puv, pov;

#define ISSUE(cc)  {                                                                        \
        size_t rb = ((size_t)b * LSEQ + (size_t)(cc) * 32);                                 \
        const unsigned short* gq = qe + (rb + li) * DMODEL + headoff + ld0;                 \
        const unsigned short* gk = kn + (rb + li) * DMODEL + headoff + ld0;                 \
        pq[0] = ((const uint4*)gq)[0]; pq[1] = ((const uint4*)gq)[1];                       \
        pk[0] = ((const uint4*)gk)[0]; pk[1] = ((const uint4*)gk)[1];                       \
        size_t tb = ((size_t)bh * NCHUNK + (cc)) * 8192;                                    \
        const uint4* gw = (const uint4*)(wu + tb + li * 128 + ld0);                         \
        pw[0] = gw[0]; pw[1] = gw[1];                                                       \
        puv = *(const unsigned*)(wu + tb + 4096 + iu * 128 + dvs * 16 + tu);                \
        pov = *(const unsigned*)(delta + (rb + iu) * DMODEL + headoff + dvs * 16 + tu);     \
    }

    ISSUE(0);

    for (int c = 0; c < NCHUNK; ++c) {
        // ---- unpack prefetched regs -> LDS (qe, w direct; kn -> knT transpose)
        *(uint4*)&qe_b[li * 136 + ld0]     = pq[0];
        *(uint4*)&qe_b[li * 136 + ld0 + 8] = pq[1];
        {
            const unsigned short* pks = (const unsigned short*)&pk[0];
#pragma unroll
            for (int e = 0; e < 16; ++e)
                knT[(ld0 + e) * 40 + li] = pks[e];
        }
        *(uint4*)&w_b[li * 136 + ld0]     = pw[0];
        *(uint4*)&w_b[li * 136 + ld0 + 8] = pw[1];
        {
            us_s[iu][tu]      = bf2f((unsigned short)puv);
            us_s[iu][tu + 1]  = bf2f((unsigned short)(puv >> 16));
            ops_s[iu][tu]     = bf2f((unsigned short)pov);
            ops_s[iu][tu + 1] = bf2f((unsigned short)(pov >> 16));
        }
        if (c + 1 < NCHUNK) ISSUE(c + 1);
        __syncthreads();

        // ---- phase A: waves 0,1 -> ua = u - w@S ; waves 2,3 -> o = opre + qe@S
        {
            const int half = wid & 1;
            const int arow = half * 16 + (l & 15);
            const int koff = (l >> 4) * 8;
            const unsigned short* ab = (wid < 2) ? w_b : qe_b;
            f4v a = zf;
#pragma unroll
            for (int kt = 0; kt < 4; ++kt) {
                s8v af  = *(const s8v*)&ab[arow * 136 + kt * 32 + koff];
                s8v bf_ = *(const s8v*)&St_b[(l & 15) * 136 + kt * 32 + koff];
                a = __builtin_amdgcn_mfma_f32_16x16x32_bf16(af, bf_, a, 0, 0, 0);
            }
            const int ib = half * 16 + ((l >> 4) << 2);
            const int t = l & 15;
            if (wid < 2) {
#pragma unroll
                for (int q = 0; q < 4; ++q) {
                    float v = us_s[ib + q][t] - a[q];
                    uaT[t * 40 + ib + q] = f2bf(v);
                }
            } else {
                size_t rb = (size_t)b * LSEQ + (size_t)c * 32;
#pragma unroll
                for (int q = 0; q < 4; ++q) {
                    float v = ops_s[ib + q][t] + a[q];
                    delta[(rb + ib + q) * DMODEL + headoff + dvs * 16 + t] = __float2bfloat16(v);
                }
            }
        }
        __syncthreads();

        // ---- phase B: Sacc = lam*Sacc + uaT @ knT ; export bf16 St_b
        {
#pragma unroll
            for (int q = 0; q < 4; ++q) { Sacc0[q] *= lam; Sacc1[q] *= lam; }
            const int koff = (l >> 4) * 8;
            s8v af = *(const s8v*)&uaT[(l & 15) * 40 + koff];
            const int d0 = wid * 32;
            s8v b0 = *(const s8v*)&knT[(d0 + (l & 15)) * 40 + koff];
            s8v b1 = *(const s8v*)&knT[(d0 + 16 + (l & 15)) * 40 + koff];
            Sacc0 = __builtin_amdgcn_mfma_f32_16x16x32_bf16(af, b0, Sacc0, 0, 0, 0);
            Sacc1 = __builtin_amdgcn_mfma_f32_16x16x32_bf16(af, b1, Sacc1, 0, 0, 0);
            const int tr = (l >> 4) << 2;
#pragma unroll
            for (int q = 0; q < 4; ++q) {
                St_b[(tr + q) * 136 + d0 + (l & 15)]      = f2bf(Sacc0[q]);
                St_b[(tr + q) * 136 + d0 + 16 + (l & 15)] = f2bf(Sacc1[q]);
            }
        }
        __syncthreads();
    }
#undef ISSUE
}

// ---------------------------------------------------------------------------
// FIR computed once, LDS-tiled (unchanged)
// ---------------------------------------------------------------------------
__global__ __launch_bounds__(256)
void fir_compute(const unsigned short* __restrict__ v,
                 const float* __restrict__ wshort, const float* __restrict__ wlong,
                 unsigned short* __restrict__ fso, unsigned short* __restrict__ flo)
{
    const int lt = blockIdx.x, h = blockIdx.y, b = blockIdx.z;
    const int tid = threadIdx.x;
    __shared__ unsigned short vt[190 * 128];
    __shared__ float wl[63 * 128];
    __shared__ float w3[3 * 128];

    for (int i = tid; i < 63 * 128; i += 256) {
        int j = i >> 7, d = i & 127;
        wl[i] = wlong[((size_t)h * 128 + d) * 63 + j];
    }
    for (int i = tid; i < 3 * 128; i += 256) {
        int j = i >> 7, d = i & 127;
        w3[i] = wshort[((size_t)h * 128 + d) * 3 + j];
    }
    const size_t vbase = ((size_t)b * LSEQ) * DMODEL + (size_t)h * DHEAD;
    const int l0 = lt * 128;
    const s8v z8 = {0, 0, 0, 0, 0, 0, 0, 0};
    for (int i = tid; i < 190 * 16; i += 256) {
        int row = i >> 4, dblk = (i & 15) * 8;
        int gl = l0 - 62 + row;
        s8v val = z8;
        if (gl >= 0) val = *(const s8v*)&v[vbase + (size_t)gl * DMODEL + dblk];
        *(s8v*)&vt[row * 128 + dblk] = val;
    }
    __syncthreads();

    const int dp = (tid & 63) * 2, lg = tid >> 6;
    for (int lc = 0; lc < 4; ++lc) {
        const int lb = lg * 32 + lc * 8;
        float a0[8], a1[8], s0[8], s1[8];
#pragma unroll
        for (int li = 0; li < 8; ++li) { a0[li] = a1[li] = s0[li] = s1[li] = 0.f; }
        for (int j = 0; j < 63; ++j) {
            float w0 = wl[j * 128 + dp], w1 = wl[j * 128 + dp + 1];
#pragma unroll
            for (int li = 0; li < 8; ++li) {
                unsigned vv = *(const unsigned*)&vt[(lb + li + j) * 128 + dp];
                a0[li] = fmaf(bf2f((unsigned short)vv), w0, a0[li]);
                a1[li] = fmaf(bf2f((unsigned short)(vv >> 16)), w1, a1[li]);
            }
        }
#pragma unroll
        for (int j = 0; j < 3; ++j) {
            float w0 = w3[j * 128 + dp], w1 = w3[j * 128 + dp + 1];
#pragma unroll
            for (int li = 0; li < 8; ++li) {
                unsigned vv = *(const unsigned*)&vt[(lb + li + 60 + j) * 128 + dp];
                s0[li] = fmaf(bf2f((unsigned short)vv), w0, s0[li]);
                s1[li] = fmaf(bf2f((unsigned short)(vv >> 16)), w1, s1[li]);
            }
        }
        const size_t ob = ((size_t)b * LSEQ + l0) * DMODEL + (size_t)h * DHEAD + dp;
#pragma unroll
        for (int li = 0; li < 8; ++li) {
            unsigned pf = (unsigned)f2bf(a0[li]) | ((unsigned)f2bf(a1[li]) << 16);
            unsigned ps = (unsigned)f2bf(s0[li]) | ((unsigned)f2bf(s1[li]) << 16);
            *(unsigned*)&flo[ob + (size_t)(lb + li) * DMODEL] = pf;
            *(unsigned*)&fso[ob + (size_t)(lb + li) * DMODEL] = ps;
        }
    }
}

// ---------------------------------------------------------------------------
// Stats: one wave per (r,h) row (unchanged)
// ---------------------------------------------------------------------------
__global__ __launch_bounds__(256)
void fir_stats2(const unsigned short* __restrict__ fs, const unsigned short* __restrict__ fl,
                const unsigned short* __restrict__ dlt, const unsigned short* __restrict__ v,
                float* __restrict__ stats)
{
    const int rh = blockIdx.x * 4 + (threadIdx.x >> 6);
    const int lane = threadIdx.x & 63;
    const int r = rh >> 3, h = rh & 7;
    const size_t base = (size_t)r * DMODEL + (size_t)h * DHEAD + lane * 2;
    unsigned ua = *(const unsigned*)(fs + base);
    unsigned ub = *(const unsigned*)(fl + base);
    unsigned uc = *(const unsigned*)(dlt + base);
    unsigned ud = *(const unsigned*)(v + base);
    float s0 = bf2f((unsigned short)ua) + bf2f((unsigned short)(ua >> 16));
    float s1 = bf2f((unsigned short)ub) + bf2f((unsigned short)(ub >> 16));
    float s2 = bf2f((unsigned short)uc) + bf2f((unsigned short)(uc >> 16));
    float s3 = bf2f((unsigned short)ud) + bf2f((unsigned short)(ud >> 16));
#pragma unroll
    for (int m = 1; m < 64; m <<= 1) {
        s0 += __shfl_xor(s0, m); s1 += __shfl_xor(s1, m);
        s2 += __shfl_xor(s2, m); s3 += __shfl_xor(s3, m);
    }
    if (lane == 0) {
        const float inv = 1.f / 128.f;
        stats[(size_t)r * 32 + 0  + h] = s0 * inv;
        stats[(size_t)r * 32 + 8  + h] = s1 * inv;
        stats[(size_t)r * 32 + 16 + h] = s2 * inv;
        stats[(size_t)r * 32 + 24 + h] = s3 * inv;
    }
}

// ---------------------------------------------------------------------------
// Combine + RMS norm (unchanged)
// ---------------------------------------------------------------------------
__global__ __launch_bounds__(256)
void combine2(const unsigned short* __restrict__ fs, const unsigned short* __restrict__ fl,
              const unsigned short* __restrict__ dlt, const unsigned short* __restrict__ v,
              const float* __restrict__ p, const float* __restrict__ onw,
              float* __restrict__ on)
{
    const int rh = blockIdx.x * 4 + (threadIdx.x >> 6);
    const int lane = threadIdx.x & 63;
    const int r = rh >> 3, h = rh & 7;
    const size_t base = (size_t)r * DMODEL + (size_t)h * DHEAD + lane * 2;
    unsigned ua = *(const unsigned*)(fs + base);
    unsigned ub = *(const unsigned*)(fl + base);
    unsigned uc = *(const unsigned*)(dlt + base);
    unsigned ud = *(const unsigned*)(v + base);
    const float* pp = p + (size_t)r * 32 + h * 4;
    float p0 = pp[0], p1 = pp[1], p2 = pp[2], p3 = pp[3];
    float ox = p0 * bf2f((unsigned short)ua) + p1 * bf2f((unsigned short)ub)
             + p2 * bf2f((unsigned short)uc) + p3 * bf2f((unsigned short)ud);
    float oy = p0 * bf2f((unsigned short)(ua >> 16)) + p1 * bf2f((unsigned short)(ub >> 16))
             + p2 * bf2f((unsigned short)(uc >> 16)) + p3 * bf2f((unsigned short)(ud >> 16));
    float ss = ox * ox + oy * oy;
#pragma unroll
    for (int m = 1; m < 64; m <<= 1) ss += __shfl_xor(ss, m);
    float sc = rsqrtf(ss * (1.f / 128.f) + 1e-5f);
    float2 o2 = make_float2(ox * sc * onw[lane * 2], oy * sc * onw[lane * 2 + 1]);
    *(float2*)(on + base) = o2;
}

// ---------------------------------------------------------------------------
// Workspace (~203.5 MB):
//  bufA: q_pre fp32 -> kconv/kn bf16 (lower 32MB) -> o_norm fp32
//  bufB: k_pre fp32 -> [lo 32MB: v bf16][hi 32MB: o_pre/delta bf16]
//  bufC: v_pre fp32 -> w|u bf16 tiles -> [lo: fs bf16][hi: fl bf16]
//  d_out: Wqkv_t bf16 -> qconv/qe bf16 -> hdn fp32 -> final out
// ---------------------------------------------------------------------------
extern "C" void kernel_launch(void* const* d_in, const int* in_sizes, int n_in,
                              void* d_out, int out_size, void* d_ws, size_t ws_size,
                              hipStream_t stream)
{
    const float* hs   = (const float*)d_in[0];
    const float* Wq   = (const float*)d_in[1];
    const float* Wk   = (const float*)d_in[2];
    const float* Wv   = (const float*)d_in[3];
    const float* Wb   = (const float*)d_in[4];
    const float* cqw  = (const float*)d_in[5];
    const float* ckw  = (const float*)d_in[6];
    const float* cvw  = (const float*)d_in[7];
    const float* ret  = (const float*)d_in[8];
    const float* fsw  = (const float*)d_in[9];
    const float* flw  = (const float*)d_in[10];
    const float* gw1  = (const float*)d_in[11];
    const float* gb1  = (const float*)d_in[12];
    const float* gw2  = (const float*)d_in[13];
    const float* gb2  = (const float*)d_in[14];
    const float* ltmp = (const float*)d_in[15];
    const float* onw  = (const float*)d_in[16];
    const float* Wo   = (const float*)d_in[17];
    float* out = (float*)d_out;

    char* wsp = (char*)d_ws;
    size_t off = 0;
    auto alloc = [&](size_t nbytes) -> void* {
        void* pt = (void*)(wsp + off);
        off += ((nbytes + 255) / 256) * 256;
        return pt;
    };
    const int R = R_TOT;
    float* bufA  = (float*)alloc((size_t)R * DMODEL * 4);
    float* bufB  = (float*)alloc((size_t)R * DMODEL * 4);
    float* bufC  = (float*)alloc((size_t)R * DMODEL * 4);
    float* beta  = (float*)alloc((size_t)R * NHEAD * 4);
    float* stats = (float*)alloc((size_t)R * 32 * 4);
    float* pbuf  = (float*)alloc((size_t)R * 32 * 4);
    unsigned short* gw1t = (unsigned short*)alloc((size_t)2048 * 1056 * 2);
    unsigned short* wot  = (unsigned short*)alloc((size_t)1024 * 1024 * 2);
    unsigned short* wbt  = (unsigned short*)alloc((size_t)128 * 1024 * 2);
    unsigned short* gw2t = (unsigned short*)alloc((size_t)128 * 2048 * 2);
    float* bufO = out;
    unsigned short* qcb = (unsigned short*)bufO;     // qconv/qe bf16 (32MB)
    unsigned short* kcb = (unsigned short*)bufA;     // kconv/kn bf16 (32MB)
    unsigned short* vbf = (unsigned short*)bufB;     // v bf16 (lower 32MB)
    unsigned short* dlt = (unsigned short*)bufB + (size_t)R * DMODEL;  // upper 32MB
    bf16* wu   = (bf16*)bufC;
    unsigned short* fsb = (unsigned short*)bufC;
    unsigned short* flb = (unsigned short*)bufC + (size_t)R * DMODEL;
    unsigned short* wqkvt = (unsigned short*)bufO;   // 3072x1024 bf16 = 6MB
    (void)ws_size; (void)in_sizes; (void)n_in; (void)out_size;

    dim3 blk(256);
    // 1. weight transposes / pads
    tcast<<<dim3(32, 32), blk, 0, stream>>>(Wq, wqkvt, 1024, 1024, 1024);
    tcast<<<dim3(32, 32), blk, 0, stream>>>(Wk, wqkvt + (size_t)1024 * 1024, 1024, 1024, 1024);
    tcast<<<dim3(32, 32), blk, 0, stream>>>(Wv, wqkvt + (size_t)2048 * 1024, 1024, 1024, 1024);
    tcast<<<dim3(33, 64), blk, 0, stream>>>(gw1, gw1t, 1056, 2048, 2048);
    tcast<<<dim3(32, 32), blk, 0, stream>>>(Wo, wot, 1024, 1024, 1024);
    tcast<<<dim3(32, 4),  blk, 0, stream>>>(Wb, wbt, 1024, 8, 128);
    tcast<<<dim3(64, 4),  blk, 0, stream>>>(gw2, gw2t, 2048, 32, 128);

    // 2. fused qkv projection (MFMA)
    mgemm<4><<<dim3(24, 128), blk, 0, stream>>>(hs, nullptr, 1 << 30, DMODEL, 0,
                                                wqkvt, nullptr, nullptr,
                                                bufA, bufB, bufC, R, 3072, 1024, 0);
    // 3. beta = sigmoid(hs @ Wb)  (MFMA, padded N)
    mgemm<1><<<dim3(1, 128), blk, 0, stream>>>(hs, nullptr, 1 << 30, DMODEL, 0,
                                               wbt, nullptr, nullptr,
                                               beta, nullptr, nullptr, R, 128, 1024, 8);
    // 4. short conv + silu (bf16 outputs): q: A->O, k: B->A, v: C->B.lo
    int convGrid = (int)(((size_t)R * DMODEL + 255) / 256);
    shortconv<1><<<convGrid, blk, 0, stream>>>(bufA, cqw, nullptr, (bf16*)qcb);
    shortconv<1><<<convGrid, blk, 0, stream>>>(bufB, ckw, nullptr, (bf16*)kcb);
    shortconv<1><<<convGrid, blk, 0, stream>>>(bufC, cvw, nullptr, (bf16*)vbf);
    // 5/6. delta rule (all-bf16 streams)
    chunk_prep2<<<4096, blk, 0, stream>>>(qcb, kcb, vbf, beta, qcb, kcb, wu, dlt);
    delta_scan3<<<256, blk, 0, stream>>>(qcb, kcb, wu, (bf16*)dlt, ret);
    // 7. FIR once (wu dead -> bufC holds fs|fl)
    fir_compute<<<dim3(32, 8, 4), blk, 0, stream>>>(vbf, fsw, flw, fsb, flb);
    // 8. stats
    fir_stats2<<<32768, blk, 0, stream>>>(fsb, flb, dlt, vbf, stats);
    // 9. gate MLP (two row-chunks; hdn fp32 in d_out scratch, qe dead)
    const int RC = 8192;
    float* hdn = bufO;
    for (int r0 = 0; r0 < R; r0 += RC) {
        mgemm<2><<<dim3(16, RC / 128), blk, 0, stream>>>(hs + (size_t)r0 * DMODEL,
                                                         stats + (size_t)r0 * 32,
                                                         1024, DMODEL, 32, gw1t, gb1, nullptr,
                                                         hdn, nullptr, nullptr,
                                                         RC, 2048, 1056, 0);
        mgemm<3><<<dim3(1, RC / 128), blk, 0, stream>>>(hdn, nullptr, 1 << 30, 2048, 0,
                                                        gw2t, gb2, ltmp,
                                                        pbuf + (size_t)r0 * 32, nullptr, nullptr,
                                                        RC, 128, 2048, 32);
    }
    // 10. combine + RMS norm -> bufA fp32 (kn dead)
    combine2<<<32768, blk, 0, stream>>>(fsb, flb, dlt, vbf, pbuf, onw, bufA);
    // 11. final projection (MFMA) -> d_out
    mgemm<0><<<dim3(8, 128), blk, 0, stream>>>(bufA, nullptr, 1 << 30, DMODEL, 0,
                                               wot, nullptr, nullptr,
                                               out, nullptr, nullptr, R, 1024, 1024, 0);
}

// Round 8
// 1526.393 us; speedup vs baseline: 11.5969x; 1.0073x over previous
//
#include <hip/hip_runtime.h>
#include <hip/hip_bf16.h>
#include <math.h>

#define R_TOT 16384      // B*L
#define LSEQ  4096
#define DMODEL 1024
#define NHEAD 8
#define DHEAD 128        // DK = DV
#define NCHUNK 128       // LSEQ/32

typedef __hip_bfloat16 bf16;
typedef short s8v __attribute__((ext_vector_type(8)));
typedef float f4v __attribute__((ext_vector_type(4)));

__device__ __forceinline__ float sigmoidf_(float x) { return 1.f / (1.f + expf(-x)); }
__device__ __forceinline__ unsigned short f2bf(float f) {
    unsigned u = __float_as_uint(f);
    u += 0x7fffu + ((u >> 16) & 1u);
    return (unsigned short)(u >> 16);
}
__device__ __forceinline__ float bf2f(unsigned short s) {
    return __uint_as_float(((unsigned)s) << 16);
}

// ---------------------------------------------------------------------------
// Transpose-cast: W (K x N fp32) -> Wt (Npad x K bf16), zero-padded rows N..Npad
// ---------------------------------------------------------------------------
__global__ __launch_bounds__(256)
void tcast(const float* __restrict__ W, unsigned short* __restrict__ Wt,
           int K, int N, int Npad)
{
    __shared__ float t[32][33];
    const int kb = blockIdx.x * 32, nb = blockIdx.y * 32;
    const int tx = threadIdx.x & 31, ty = threadIdx.x >> 5;   // ty 0..7
    for (int i = ty; i < 32; i += 8) {
        int k = kb + i, n = nb + tx;
        t[i][tx] = (k < K && n < N) ? W[(size_t)k * N + n] : 0.f;
    }
    __syncthreads();
    for (int i = ty; i < 32; i += 8) {
        int n = nb + i, k = kb + tx;
        if (n < Npad && k < K) Wt[(size_t)n * K + k] = f2bf(t[tx][i]);
    }
}

// ---------------------------------------------------------------------------
// MFMA bf16 GEMM: C = epi(A @ Bt^T), A fp32 MxK (split A/A2 at Ksplit),
// Bt = bf16 N x K row-major. Tile 128x128x32, 256 thr = 4 waves.
// MODE 0: none  1: sigmoid (store col<Nout, stride Nout)
// MODE 2: gelu(x+bias)  3: p-gate (store col<Nout, stride Nout)
// MODE 5: qkv split, bf16 outputs (col/1024 -> C0/C1/C2 as ushort*)
// ---------------------------------------------------------------------------
template<int MODE>
__global__ __launch_bounds__(256)
void mgemm(const float* __restrict__ A, const float* __restrict__ A2, int Ksplit,
           int lda1, int lda2,
           const unsigned short* __restrict__ Bt,
           const float* __restrict__ bias, const float* __restrict__ aux,
           float* __restrict__ C0, float* __restrict__ C1, float* __restrict__ C2,
           int M, int N, int K, int Nout)
{
    __shared__ unsigned short As[128 * 40];
    __shared__ unsigned short Bs[128 * 40];
    const int tid = threadIdx.x;
    const int m0 = blockIdx.y * 128, n0 = blockIdx.x * 128;
    const int l = tid & 63;
    const int wr = (tid >> 7) & 1, wc = (tid >> 6) & 1;
    const int sr = tid >> 1, sh = (tid & 1) * 16;

    const f4v zf = {0.f, 0.f, 0.f, 0.f};
    f4v acc[4][4];
#pragma unroll
    for (int i = 0; i < 4; ++i)
#pragma unroll
        for (int j = 0; j < 4; ++j) acc[i][j] = zf;

    const int nkt = K >> 5;
    for (int kt = 0; kt < nkt; ++kt) {
        const int k0 = kt << 5;
        {
            const float* src = (k0 < Ksplit)
                ? A  + (size_t)(m0 + sr) * lda1 + (size_t)(k0 + sh)
                : A2 + (size_t)(m0 + sr) * lda2 + (size_t)(k0 - Ksplit + sh);
            float4 v0 = ((const float4*)src)[0];
            float4 v1 = ((const float4*)src)[1];
            float4 v2 = ((const float4*)src)[2];
            float4 v3 = ((const float4*)src)[3];
            s8v w0, w1;
            w0[0] = (short)f2bf(v0.x); w0[1] = (short)f2bf(v0.y);
            w0[2] = (short)f2bf(v0.z); w0[3] = (short)f2bf(v0.w);
            w0[4] = (short)f2bf(v1.x); w0[5] = (short)f2bf(v1.y);
            w0[6] = (short)f2bf(v1.z); w0[7] = (short)f2bf(v1.w);
            w1[0] = (short)f2bf(v2.x); w1[1] = (short)f2bf(v2.y);
            w1[2] = (short)f2bf(v2.z); w1[3] = (short)f2bf(v2.w);
            w1[4] = (short)f2bf(v3.x); w1[5] = (short)f2bf(v3.y);
            w1[6] = (short)f2bf(v3.z); w1[7] = (short)f2bf(v3.w);
            *(s8v*)&As[sr * 40 + sh]     = w0;
            *(s8v*)&As[sr * 40 + sh + 8] = w1;
        }
        {
            const unsigned short* src = Bt + (size_t)(n0 + sr) * K + (size_t)(k0 + sh);
            s8v b0 = ((const s8v*)src)[0];
            s8v b1 = ((const s8v*)src)[1];
            *(s8v*)&Bs[sr * 40 + sh]     = b0;
            *(s8v*)&Bs[sr * 40 + sh + 8] = b1;
        }
        __syncthreads();
        const int fr = l & 15, fq = (l >> 4) * 8;
        s8v af[4], bfr[4];
#pragma unroll
        for (int i = 0; i < 4; ++i) {
            af[i]  = *(const s8v*)&As[(wr * 64 + i * 16 + fr) * 40 + fq];
            bfr[i] = *(const s8v*)&Bs[(wc * 64 + i * 16 + fr) * 40 + fq];
        }
#pragma unroll
        for (int i = 0; i < 4; ++i)
#pragma unroll
            for (int j = 0; j < 4; ++j)
                acc[i][j] = __builtin_amdgcn_mfma_f32_16x16x32_bf16(af[i], bfr[j], acc[i][j], 0, 0, 0);
        __syncthreads();
    }
    const int fr = l & 15, fq4 = (l >> 4) * 4;
#pragma unroll
    for (int i = 0; i < 4; ++i) {
#pragma unroll
        for (int j = 0; j < 4; ++j) {
            int col = n0 + wc * 64 + j * 16 + fr;
            if ((MODE == 1 || MODE == 3) && col >= Nout) continue;
#pragma unroll
            for (int q = 0; q < 4; ++q) {
                int row = m0 + wr * 64 + i * 16 + fq4 + q;
                float x = acc[i][j][q];
                if (MODE == 1) {
                    x = sigmoidf_(x);
                    C0[(size_t)row * Nout + col] = x;
                } else if (MODE == 2) {
                    x += bias[col];
                    x = 0.5f * x * (1.f + erff(x * 0.70710678118654752f));
                    C0[(size_t)row * N + col] = x;
                } else if (MODE == 3) {
                    x += bias[col];
                    x *= expf(-aux[col >> 2]);
                    x = 0.02f + 0.98f * sigmoidf_(x);
                    C0[(size_t)row * Nout + col] = x;
                } else if (MODE == 5) {
                    unsigned short* dst = (col < 1024) ? (unsigned short*)C0
                                        : ((col < 2048) ? (unsigned short*)C1
                                                        : (unsigned short*)C2);
                    dst[(size_t)row * 1024 + (col & 1023)] = f2bf(x);
                } else {
                    C0[(size_t)row * N + col] = x;
                }
            }
        }
    }
}

// ---------------------------------------------------------------------------
// Short causal conv (K=4) + SiLU, bf16 in -> bf16 out (fp32 accumulation)
// ---------------------------------------------------------------------------
__global__ __launch_bounds__(256)
void shortconv_b(const unsigned short* __restrict__ x, const float* __restrict__ w,
                 unsigned short* __restrict__ y)
{
    size_t idx = (size_t)blockIdx.x * 256 + threadIdx.x;
    if (idx >= (size_t)R_TOT * DMODEL) return;
    int c = (int)(idx & (DMODEL - 1));
    long r = (long)(idx >> 10);
    int l = (int)(r & (LSEQ - 1));
    const float* wc = w + c * 4;
    float acc = 0.f;
#pragma unroll
    for (int j = 0; j < 4; ++j) {
        int xl = l - 3 + j;
        if (xl >= 0) acc += bf2f(x[(r - l + xl) * DMODEL + c]) * wc[j];
    }
    float yv = acc * sigmoidf_(acc);
    y[idx] = f2bf(yv);
}

// ---------------------------------------------------------------------------
// Phase 1: per-(b,h,chunk) prep, MFMA version — register-disciplined.
// Phases fenced with sched_barrier(0) to keep liveness local (round-7's
// version spilled at 256 VGPR / 0.8% occupancy).
// ---------------------------------------------------------------------------
__global__ __launch_bounds__(256)
void chunk_prep2(const unsigned short* __restrict__ qconv, const unsigned short* __restrict__ kconv,
                 const unsigned short* __restrict__ vbf, const float* __restrict__ beta,
                 unsigned short* __restrict__ qe_out, unsigned short* __restrict__ kn_out,
                 bf16* __restrict__ wu, unsigned short* __restrict__ opre)
{
    const int bid = blockIdx.x;              // (b*8+h)*128 + c
    const int c = bid & 127, h = (bid >> 7) & 7, b = bid >> 10;
    const int tid = threadIdx.x;
    const int l = tid & 63, wid = tid >> 6;

    __shared__ __align__(16) unsigned short q_b[32 * 136];
    __shared__ __align__(16) unsigned short k_b[32 * 136];
    __shared__ __align__(16) unsigned short v_b[32 * 136];
    __shared__ __align__(16) unsigned short at_b[32 * 40];
    __shared__ __align__(16) unsigned short wT[128 * 40];
    __shared__ __align__(16) unsigned short uT[128 * 40];
    __shared__ float Am[32][33];
    __shared__ float betas_s[32];

    const size_t row0 = (size_t)b * LSEQ + (size_t)c * 32;
    const size_t base = row0 * DMODEL + (size_t)h * DHEAD;
    const f4v zf = {0.f, 0.f, 0.f, 0.f};
    const int li = tid >> 3, ld0 = (tid & 7) * 16;

    // ---- phase 0: load q,k,v rows (bf16, vectorized)
    {
        const unsigned short* gq = qconv + base + (size_t)li * DMODEL + ld0;
        const unsigned short* gk = kconv + base + (size_t)li * DMODEL + ld0;
        const unsigned short* gv = vbf   + base + (size_t)li * DMODEL + ld0;
        *(uint4*)&q_b[li * 136 + ld0]     = ((const uint4*)gq)[0];
        *(uint4*)&q_b[li * 136 + ld0 + 8] = ((const uint4*)gq)[1];
        *(uint4*)&k_b[li * 136 + ld0]     = ((const uint4*)gk)[0];
        *(uint4*)&k_b[li * 136 + ld0 + 8] = ((const uint4*)gk)[1];
        *(uint4*)&v_b[li * 136 + ld0]     = ((const uint4*)gv)[0];
        *(uint4*)&v_b[li * 136 + ld0 + 8] = ((const uint4*)gv)[1];
    }
    if (tid < 32) betas_s[tid] = beta[(row0 + tid) * NHEAD + h];
    __syncthreads();

    // ---- phase 1: l2norm rows of q,k (re-read LDS, no register caching)
    {
        float sq = 0.f, sk = 0.f;
#pragma unroll
        for (int e = 0; e < 8; ++e) {
            unsigned uq = *(const unsigned*)&q_b[li * 136 + ld0 + e * 2];
            unsigned uk = *(const unsigned*)&k_b[li * 136 + ld0 + e * 2];
            float q0 = bf2f((unsigned short)uq), q1 = bf2f((unsigned short)(uq >> 16));
            float k0 = bf2f((unsigned short)uk), k1 = bf2f((unsigned short)(uk >> 16));
            sq = fmaf(q0, q0, fmaf(q1, q1, sq));
            sk = fmaf(k0, k0, fmaf(k1, k1, sk));
        }
#pragma unroll
        for (int m = 1; m < 8; m <<= 1) { sq += __shfl_xor(sq, m); sk += __shfl_xor(sk, m); }
        float rq = rsqrtf(sq + 1e-6f), rk = rsqrtf(sk + 1e-6f);
#pragma unroll
        for (int e = 0; e < 8; ++e) {
            unsigned uq = *(const unsigned*)&q_b[li * 136 + ld0 + e * 2];
            unsigned uk = *(const unsigned*)&k_b[li * 136 + ld0 + e * 2];
            unsigned pq = (unsigned)f2bf(bf2f((unsigned short)uq) * rq)
                        | ((unsigned)f2bf(bf2f((unsigned short)(uq >> 16)) * rq) << 16);
            unsigned pk = (unsigned)f2bf(bf2f((unsigned short)uk) * rk)
                        | ((unsigned)f2bf(bf2f((unsigned short)(uk >> 16)) * rk) << 16);
            *(unsigned*)&q_b[li * 136 + ld0 + e * 2] = pq;
            *(unsigned*)&k_b[li * 136 + ld0 + e * 2] = pk;
        }
    }
    __syncthreads();
    __builtin_amdgcn_sched_barrier(0);

    // ---- phase 2: kn write-through (vectorized)
    {
        unsigned short* gk = kn_out + base + (size_t)li * DMODEL + ld0;
        ((uint4*)gk)[0] = *(const uint4*)&k_b[li * 136 + ld0];
        ((uint4*)gk)[1] = *(const uint4*)&k_b[li * 136 + ld0 + 8];
    }

    // ---- phase 3: Am, at via MFMA (wave wid -> 16x16 tile (tr,tc))
    {
        const int tr = wid >> 1, tc = wid & 1;
        const int fr = l & 15, ko = (l >> 4) * 8;
        f4v accA = zf, accT = zf;
#pragma unroll
        for (int kt = 0; kt < 4; ++kt) {
            s8v ka  = *(const s8v*)&k_b[(tr * 16 + fr) * 136 + kt * 32 + ko];
            s8v qa  = *(const s8v*)&q_b[(tr * 16 + fr) * 136 + kt * 32 + ko];
            s8v kb2 = *(const s8v*)&k_b[(tc * 16 + fr) * 136 + kt * 32 + ko];
            accA = __builtin_amdgcn_mfma_f32_16x16x32_bf16(ka, kb2, accA, 0, 0, 0);
            accT = __builtin_amdgcn_mfma_f32_16x16x32_bf16(qa, kb2, accT, 0, 0, 0);
        }
        const int jloc = tc * 16 + fr;
#pragma unroll
        for (int q = 0; q < 4; ++q) {
            int iloc = tr * 16 + (l >> 4) * 4 + q;
            Am[iloc][jloc] = (iloc > jloc) ? betas_s[iloc] * accA[q] : 0.f;
            at_b[iloc * 40 + jloc] = f2bf((iloc >= jloc) ? accT[q] : 0.f);
        }
    }
    __syncthreads();
    __builtin_amdgcn_sched_barrier(0);

    // ---- phase 4: forward substitution (I+Am)x = rhs; one column per thread
    {
        float x[32];
        const int t = tid;
        if (t < 128) {
#pragma unroll
            for (int i = 0; i < 32; ++i) x[i] = betas_s[i] * bf2f(v_b[i * 136 + t]);
        } else {
            const int d = t - 128;
#pragma unroll
            for (int i = 0; i < 32; ++i) x[i] = betas_s[i] * bf2f(k_b[i * 136 + d]);
        }
#pragma unroll
        for (int i = 1; i < 32; ++i) {
            float s = 0.f;
#pragma unroll
            for (int m = 0; m < i; ++m) s = fmaf(Am[i][m], x[m], s);
            x[i] -= s;
        }
        const size_t tb = (size_t)bid * 8192;
        if (t < 128) {
#pragma unroll
            for (int i2 = 0; i2 < 16; ++i2) {
                unsigned short b0 = f2bf(x[i2 * 2]), b1 = f2bf(x[i2 * 2 + 1]);
                *(unsigned*)&uT[t * 40 + i2 * 2] = (unsigned)b0 | ((unsigned)b1 << 16);
                wu[tb + 4096 + (i2 * 2) * 128 + t]     = __float2bfloat16(x[i2 * 2]);
                wu[tb + 4096 + (i2 * 2 + 1) * 128 + t] = __float2bfloat16(x[i2 * 2 + 1]);
            }
        } else {
            const int d = t - 128;
#pragma unroll
            for (int i2 = 0; i2 < 16; ++i2) {
                unsigned short b0 = f2bf(x[i2 * 2]), b1 = f2bf(x[i2 * 2 + 1]);
                *(unsigned*)&wT[d * 40 + i2 * 2] = (unsigned)b0 | ((unsigned)b1 << 16);
                wu[tb + (i2 * 2) * 128 + d]     = __float2bfloat16(x[i2 * 2]);
                wu[tb + (i2 * 2 + 1) * 128 + d] = __float2bfloat16(x[i2 * 2 + 1]);
            }
        }
    }
    __syncthreads();
    __builtin_amdgcn_sched_barrier(0);

    // ---- phase 5: qe = qn - at@w ; o_pre = at@u  (split by rt to limit liveness)
    {
        const int fr = l & 15, ko = (l >> 4) * 8;
        const int ct0 = wid * 2, ct1 = wid * 2 + 1;
#pragma unroll
        for (int rt = 0; rt < 2; ++rt) {
            s8v a   = *(const s8v*)&at_b[(rt * 16 + fr) * 40 + ko];
            s8v bw0 = *(const s8v*)&wT[(ct0 * 16 + fr) * 40 + ko];
            s8v bw1 = *(const s8v*)&wT[(ct1 * 16 + fr) * 40 + ko];
            s8v bu0 = *(const s8v*)&uT[(ct0 * 16 + fr) * 40 + ko];
            s8v bu1 = *(const s8v*)&uT[(ct1 * 16 + fr) * 40 + ko];
            f4v qw0 = __builtin_amdgcn_mfma_f32_16x16x32_bf16(a, bw0, zf, 0, 0, 0);
            f4v qw1 = __builtin_amdgcn_mfma_f32_16x16x32_bf16(a, bw1, zf, 0, 0, 0);
            f4v ou0 = __builtin_amdgcn_mfma_f32_16x16x32_bf16(a, bu0, zf, 0, 0, 0);
            f4v ou1 = __builtin_amdgcn_mfma_f32_16x16x32_bf16(a, bu1, zf, 0, 0, 0);
#pragma unroll
            for (int q = 0; q < 4; ++q) {
                const int i = rt * 16 + (l >> 4) * 4 + q;
                {
                    const int d = ct0 * 16 + fr;
                    size_t g = base + (size_t)i * DMODEL + d;
                    qe_out[g] = f2bf(bf2f(q_b[i * 136 + d]) - qw0[q]);
                    opre[g]   = f2bf(ou0[q]);
                }
                {
                    const int d = ct1 * 16 + fr;
                    size_t g = base + (size_t)i * DMODEL + d;
                    qe_out[g] = f2bf(bf2f(q_b[i * 136 + d]) - qw1[q]);
                    opre[g]   = f2bf(ou1[q]);
                }
            }
            __builtin_amdgcn_sched_barrier(0);
        }
    }
}

// ---------------------------------------------------------------------------
// Phase 2: MFMA state scan (unchanged, round-6/7 verified)
// ---------------------------------------------------------------------------
__global__ __launch_bounds__(256)
void delta_scan3(const unsigned short* __restrict__ qe, const unsigned short* __restrict__ kn,
                 const bf16* __restrict__ wu, bf16* __restrict__ delta,
                 const float* __restrict__ ret)
{
    const int bid0 = blockIdx.x;
    const int dvs = (bid0 >> 3) & 7;                      // dv-slice
    const int bh  = ((bid0 >> 6) << 3) | (bid0 & 7);      // xcd-stable bh
    const int h = bh & 7, b = bh >> 3;
    const int tid = threadIdx.x;
    const int l = tid & 63, wid = tid >> 6;

    __shared__ __align__(16) unsigned short qe_b[32 * 136];
    __shared__ __align__(16) unsigned short w_b [32 * 136];
    __shared__ __align__(16) unsigned short knT [128 * 40];
    __shared__ __align__(16) unsigned short St_b[16 * 136];
    __shared__ __align__(16) unsigned short uaT [16 * 40];
    __shared__ float us_s[32][18], ops_s[32][18];

    const float lam = 0.6f + 0.4f * sigmoidf_(ret[h]);

    for (int i = tid; i < 16 * 136; i += 256) St_b[i] = 0;

    const int li = tid >> 3, ld0 = (tid & 7) * 16;
    const int iu = tid >> 3, tu = (tid & 7) * 2;
    const size_t headoff = (size_t)h * DHEAD;

    const f4v zf = {0.f, 0.f, 0.f, 0.f};
    f4v Sacc0 = zf, Sacc1 = zf;        // this wave's S d-tiles (d0 = wid*32)

    uint4 pq[2], pk[2], pw[2];
    unsigned puv, pov;

#define ISSUE(cc)  {                                                                        \
        size_t rb = ((size_t)b * LSEQ + (size_t)(cc) * 32);                                 \
        const unsigned short* gq = qe + (rb + li) * DMODEL + headoff + ld0;                 \
        const unsigned short* gk = kn + (rb + li) * DMODEL + headoff + ld0;                 \
        pq[0] = ((const uint4*)gq)[0]; pq[1] = ((const uint4*)gq)[1];                       \
        pk[0] = ((const uint4*)gk)[0]; pk[1] = ((const uint4*)gk)[1];                       \
        size_t tb = ((size_t)bh * NCHUNK + (cc)) * 8192;                                    \
        const uint4* gw = (const uint4*)(wu + tb + li * 128 + ld0);                         \
        pw[0] = gw[0]; pw[1] = gw[1];                                                       \
        puv = *(const unsigned*)(wu + tb + 4096 + iu * 128 + dvs * 16 + tu);                \
        pov = *(const unsigned*)(delta + (rb + iu) * DMODEL + headoff + dvs * 16 + tu);     \
    }

    ISSUE(0);

    for (int c = 0; c < NCHUNK; ++c) {
        // ---- unpack prefetched regs -> LDS (qe, w direct; kn -> knT transpose)
        *(uint4*)&qe_b[li * 136 + ld0]     = pq[0];
        *(uint4*)&qe_b[li * 136 + ld0 + 8] = pq[1];
        {
            const unsigned short* pks = (const unsigned short*)&pk[0];
#pragma unroll
            for (int e = 0; e < 16; ++e)
                knT[(ld0 + e) * 40 + li] = pks[e];
        }
        *(uint4*)&w_b[li * 136 + ld0]     = pw[0];
        *(uint4*)&w_b[li * 136 + ld0 + 8] = pw[1];
        {
            us_s[iu][tu]      = bf2f((unsigned short)puv);
            us_s[iu][tu + 1]  = bf2f((unsigned short)(puv >> 16));
            ops_s[iu][tu]     = bf2f((unsigned short)pov);
            ops_s[iu][tu + 1] = bf2f((unsigned short)(pov >> 16));
        }
        if (c + 1 < NCHUNK) ISSUE(c + 1);
        __syncthreads();

        // ---- phase A: waves 0,1 -> ua = u - w@S ; waves 2,3 -> o = opre + qe@S
        {
            const int half = wid & 1;
            const int arow = half * 16 + (l & 15);
            const int koff = (l >> 4) * 8;
            const unsigned short* ab = (wid < 2) ? w_b : qe_b;
            f4v a = zf;
#pragma unroll
            for (int kt = 0; kt < 4; ++kt) {
                s8v af  = *(const s8v*)&ab[arow * 136 + kt * 32 + koff];
                s8v bf_ = *(const s8v*)&St_b[(l & 15) * 136 + kt * 32 + koff];
                a = __builtin_amdgcn_mfma_f32_16x16x32_bf16(af, bf_, a, 0, 0, 0);
            }
            const int ib = half * 16 + ((l >> 4) << 2);
            const int t = l & 15;
            if (wid < 2) {
#pragma unroll
                for (int q = 0; q < 4; ++q) {
                    float v = us_s[ib + q][t] - a[q];
                    uaT[t * 40 + ib + q] = f2bf(v);
                }
            } else {
                size_t rb = (size_t)b * LSEQ + (size_t)c * 32;
#pragma unroll
                for (int q = 0; q < 4; ++q) {
                    float v = ops_s[ib + q][t] + a[q];
                    delta[(rb + ib + q) * DMODEL + headoff + dvs * 16 + t] = __float2bfloat16(v);
                }
            }
        }
        __syncthreads();

        // ---- phase B: Sacc = lam*Sacc + uaT @ knT ; export bf16 St_b
        {
#pragma unroll
            for (int q = 0; q < 4; ++q) { Sacc0[q] *= lam; Sacc1[q] *= lam; }
            const int koff = (l >> 4) * 8;
            s8v af = *(const s8v*)&uaT[(l & 15) * 40 + koff];
            const int d0 = wid * 32;
            s8v b0 = *(const s8v*)&knT[(d0 + (l & 15)) * 40 + koff];
            s8v b1 = *(const s8v*)&knT[(d0 + 16 + (l & 15)) * 40 + koff];
            Sacc0 = __builtin_amdgcn_mfma_f32_16x16x32_bf16(af, b0, Sacc0, 0, 0, 0);
            Sacc1 = __builtin_amdgcn_mfma_f32_16x16x32_bf16(af, b1, Sacc1, 0, 0, 0);
            const int tr = (l >> 4) << 2;
#pragma unroll
            for (int q = 0; q < 4; ++q) {
                St_b[(tr + q) * 136 + d0 + (l & 15)]      = f2bf(Sacc0[q]);
                St_b[(tr + q) * 136 + d0 + 16 + (l & 15)] = f2bf(Sacc1[q]);
            }
        }
        __syncthreads();
    }
#undef ISSUE
}

// ---------------------------------------------------------------------------
// FIR computed once, LDS-tiled (unchanged)
// ---------------------------------------------------------------------------
__global__ __launch_bounds__(256)
void fir_compute(const unsigned short* __restrict__ v,
                 const float* __restrict__ wshort, const float* __restrict__ wlong,
                 unsigned short* __restrict__ fso, unsigned short* __restrict__ flo)
{
    const int lt = blockIdx.x, h = blockIdx.y, b = blockIdx.z;
    const int tid = threadIdx.x;
    __shared__ unsigned short vt[190 * 128];
    __shared__ float wl[63 * 128];
    __shared__ float w3[3 * 128];

    for (int i = tid; i < 63 * 128; i += 256) {
        int j = i >> 7, d = i & 127;
        wl[i] = wlong[((size_t)h * 128 + d) * 63 + j];
    }
    for (int i = tid; i < 3 * 128; i += 256) {
        int j = i >> 7, d = i & 127;
        w3[i] = wshort[((size_t)h * 128 + d) * 3 + j];
    }
    const size_t vbase = ((size_t)b * LSEQ) * DMODEL + (size_t)h * DHEAD;
    const int l0 = lt * 128;
    const s8v z8 = {0, 0, 0, 0, 0, 0, 0, 0};
    for (int i = tid; i < 190 * 16; i += 256) {
        int row = i >> 4, dblk = (i & 15) * 8;
        int gl = l0 - 62 + row;
        s8v val = z8;
        if (gl >= 0) val = *(const s8v*)&v[vbase + (size_t)gl * DMODEL + dblk];
        *(s8v*)&vt[row * 128 + dblk] = val;
    }
    __syncthreads();

    const int dp = (tid & 63) * 2, lg = tid >> 6;
    for (int lc = 0; lc < 4; ++lc) {
        const int lb = lg * 32 + lc * 8;
        float a0[8], a1[8], s0[8], s1[8];
#pragma unroll
        for (int li = 0; li < 8; ++li) { a0[li] = a1[li] = s0[li] = s1[li] = 0.f; }
        for (int j = 0; j < 63; ++j) {
            float w0 = wl[j * 128 + dp], w1 = wl[j * 128 + dp + 1];
#pragma unroll
            for (int li = 0; li < 8; ++li) {
                unsigned vv = *(const unsigned*)&vt[(lb + li + j) * 128 + dp];
                a0[li] = fmaf(bf2f((unsigned short)vv), w0, a0[li]);
                a1[li] = fmaf(bf2f((unsigned short)(vv >> 16)), w1, a1[li]);
            }
        }
#pragma unroll
        for (int j = 0; j < 3; ++j) {
            float w0 = w3[j * 128 + dp], w1 = w3[j * 128 + dp + 1];
#pragma unroll
            for (int li = 0; li < 8; ++li) {
                unsigned vv = *(const unsigned*)&vt[(lb + li + 60 + j) * 128 + dp];
                s0[li] = fmaf(bf2f((unsigned short)vv), w0, s0[li]);
                s1[li] = fmaf(bf2f((unsigned short)(vv >> 16)), w1, s1[li]);
            }
        }
        const size_t ob = ((size_t)b * LSEQ + l0) * DMODEL + (size_t)h * DHEAD + dp;
#pragma unroll
        for (int li = 0; li < 8; ++li) {
            unsigned pf = (unsigned)f2bf(a0[li]) | ((unsigned)f2bf(a1[li]) << 16);
            unsigned ps = (unsigned)f2bf(s0[li]) | ((unsigned)f2bf(s1[li]) << 16);
            *(unsigned*)&flo[ob + (size_t)(lb + li) * DMODEL] = pf;
            *(unsigned*)&fso[ob + (size_t)(lb + li) * DMODEL] = ps;
        }
    }
}

// ---------------------------------------------------------------------------
// Stats: one wave per (r,h) row (unchanged)
// ---------------------------------------------------------------------------
__global__ __launch_bounds__(256)
void fir_stats2(const unsigned short* __restrict__ fs, const unsigned short* __restrict__ fl,
                const unsigned short* __restrict__ dlt, const unsigned short* __restrict__ v,
                float* __restrict__ stats)
{
    const int rh = blockIdx.x * 4 + (threadIdx.x >> 6);
    const int lane = threadIdx.x & 63;
    const int r = rh >> 3, h = rh & 7;
    const size_t base = (size_t)r * DMODEL + (size_t)h * DHEAD + lane * 2;
    unsigned ua = *(const unsigned*)(fs + base);
    unsigned ub = *(const unsigned*)(fl + base);
    unsigned uc = *(const unsigned*)(dlt + base);
    unsigned ud = *(const unsigned*)(v + base);
    float s0 = bf2f((unsigned short)ua) + bf2f((unsigned short)(ua >> 16));
    float s1 = bf2f((unsigned short)ub) + bf2f((unsigned short)(ub >> 16));
    float s2 = bf2f((unsigned short)uc) + bf2f((unsigned short)(uc >> 16));
    float s3 = bf2f((unsigned short)ud) + bf2f((unsigned short)(ud >> 16));
#pragma unroll
    for (int m = 1; m < 64; m <<= 1) {
        s0 += __shfl_xor(s0, m); s1 += __shfl_xor(s1, m);
        s2 += __shfl_xor(s2, m); s3 += __shfl_xor(s3, m);
    }
    if (lane == 0) {
        const float inv = 1.f / 128.f;
        stats[(size_t)r * 32 + 0  + h] = s0 * inv;
        stats[(size_t)r * 32 + 8  + h] = s1 * inv;
        stats[(size_t)r * 32 + 16 + h] = s2 * inv;
        stats[(size_t)r * 32 + 24 + h] = s3 * inv;
    }
}

// ---------------------------------------------------------------------------
// Combine + RMS norm (unchanged)
// ---------------------------------------------------------------------------
__global__ __launch_bounds__(256)
void combine2(const unsigned short* __restrict__ fs, const unsigned short* __restrict__ fl,
              const unsigned short* __restrict__ dlt, const unsigned short* __restrict__ v,
              const float* __restrict__ p, const float* __restrict__ onw,
              float* __restrict__ on)
{
    const int rh = blockIdx.x * 4 + (threadIdx.x >> 6);
    const int lane = threadIdx.x & 63;
    const int r = rh >> 3, h = rh & 7;
    const size_t base = (size_t)r * DMODEL + (size_t)h * DHEAD + lane * 2;
    unsigned ua = *(const unsigned*)(fs + base);
    unsigned ub = *(const unsigned*)(fl + base);
    unsigned uc = *(const unsigned*)(dlt + base);
    unsigned ud = *(const unsigned*)(v + base);
    const float* pp = p + (size_t)r * 32 + h * 4;
    float p0 = pp[0], p1 = pp[1], p2 = pp[2], p3 = pp[3];
    float ox = p0 * bf2f((unsigned short)ua) + p1 * bf2f((unsigned short)ub)
             + p2 * bf2f((unsigned short)uc) + p3 * bf2f((unsigned short)ud);
    float oy = p0 * bf2f((unsigned short)(ua >> 16)) + p1 * bf2f((unsigned short)(ub >> 16))
             + p2 * bf2f((unsigned short)(uc >> 16)) + p3 * bf2f((unsigned short)(ud >> 16));
    float ss = ox * ox + oy * oy;
#pragma unroll
    for (int m = 1; m < 64; m <<= 1) ss += __shfl_xor(ss, m);
    float sc = rsqrtf(ss * (1.f / 128.f) + 1e-5f);
    float2 o2 = make_float2(ox * sc * onw[lane * 2], oy * sc * onw[lane * 2 + 1]);
    *(float2*)(on + base) = o2;
}

// ---------------------------------------------------------------------------
// Workspace (~203.5 MB):
//  bufA: q_pre bf16 (lo) -> kconv/kn bf16 (lo) -> o_norm fp32
//  bufB: k_pre bf16 (lo) -> [lo: v bf16][hi: o_pre/delta bf16]
//  bufC: v_pre bf16 (lo) -> w|u bf16 tiles -> [lo: fs bf16][hi: fl bf16]
//  d_out: Wqkv_t bf16 -> qconv/qe bf16 -> hdn fp32 -> final out
// ---------------------------------------------------------------------------
extern "C" void kernel_launch(void* const* d_in, const int* in_sizes, int n_in,
                              void* d_out, int out_size, void* d_ws, size_t ws_size,
                              hipStream_t stream)
{
    const float* hs   = (const float*)d_in[0];
    const float* Wq   = (const float*)d_in[1];
    const float* Wk   = (const float*)d_in[2];
    const float* Wv   = (const float*)d_in[3];
    const float* Wb   = (const float*)d_in[4];
    const float* cqw  = (const float*)d_in[5];
    const float* ckw  = (const float*)d_in[6];
    const float* cvw  = (const float*)d_in[7];
    const float* ret  = (const float*)d_in[8];
    const float* fsw  = (const float*)d_in[9];
    const float* flw  = (const float*)d_in[10];
    const float* gw1  = (const float*)d_in[11];
    const float* gb1  = (const float*)d_in[12];
    const float* gw2  = (const float*)d_in[13];
    const float* gb2  = (const float*)d_in[14];
    const float* ltmp = (const float*)d_in[15];
    const float* onw  = (const float*)d_in[16];
    const float* Wo   = (const float*)d_in[17];
    float* out = (float*)d_out;

    char* wsp = (char*)d_ws;
    size_t off = 0;
    auto alloc = [&](size_t nbytes) -> void* {
        void* pt = (void*)(wsp + off);
        off += ((nbytes + 255) / 256) * 256;
        return pt;
    };
    const int R = R_TOT;
    float* bufA  = (float*)alloc((size_t)R * DMODEL * 4);
    float* bufB  = (float*)alloc((size_t)R * DMODEL * 4);
    float* bufC  = (float*)alloc((size_t)R * DMODEL * 4);
    float* beta  = (float*)alloc((size_t)R * NHEAD * 4);
    float* stats = (float*)alloc((size_t)R * 32 * 4);
    float* pbuf  = (float*)alloc((size_t)R * 32 * 4);
    unsigned short* gw1t = (unsigned short*)alloc((size_t)2048 * 1056 * 2);
    unsigned short* wot  = (unsigned short*)alloc((size_t)1024 * 1024 * 2);
    unsigned short* wbt  = (unsigned short*)alloc((size_t)128 * 1024 * 2);
    unsigned short* gw2t = (unsigned short*)alloc((size_t)128 * 2048 * 2);
    float* bufO = out;
    unsigned short* qpb = (unsigned short*)bufA;     // q_pre bf16 (lo)
    unsigned short* kpb = (unsigned short*)bufB;     // k_pre bf16 (lo)
    unsigned short* vpb = (unsigned short*)bufC;     // v_pre bf16 (lo)
    unsigned short* qcb = (unsigned short*)bufO;     // qconv/qe bf16 (32MB)
    unsigned short* kcb = (unsigned short*)bufA;     // kconv/kn bf16 (lo)
    unsigned short* vbf = (unsigned short*)bufB;     // v bf16 (lo)
    unsigned short* dlt = (unsigned short*)bufB + (size_t)R * DMODEL;  // hi 32MB
    bf16* wu   = (bf16*)bufC;
    unsigned short* fsb = (unsigned short*)bufC;
    unsigned short* flb = (unsigned short*)bufC + (size_t)R * DMODEL;
    unsigned short* wqkvt = (unsigned short*)bufO;   // 3072x1024 bf16 = 6MB
    (void)ws_size; (void)in_sizes; (void)n_in; (void)out_size;

    dim3 blk(256);
    // 1. weight transposes / pads
    tcast<<<dim3(32, 32), blk, 0, stream>>>(Wq, wqkvt, 1024, 1024, 1024);
    tcast<<<dim3(32, 32), blk, 0, stream>>>(Wk, wqkvt + (size_t)1024 * 1024, 1024, 1024, 1024);
    tcast<<<dim3(32, 32), blk, 0, stream>>>(Wv, wqkvt + (size_t)2048 * 1024, 1024, 1024, 1024);
    tcast<<<dim3(33, 64), blk, 0, stream>>>(gw1, gw1t, 1056, 2048, 2048);
    tcast<<<dim3(32, 32), blk, 0, stream>>>(Wo, wot, 1024, 1024, 1024);
    tcast<<<dim3(32, 4),  blk, 0, stream>>>(Wb, wbt, 1024, 8, 128);
    tcast<<<dim3(64, 4),  blk, 0, stream>>>(gw2, gw2t, 2048, 32, 128);

    // 2. fused qkv projection (MFMA, bf16 outputs)
    mgemm<5><<<dim3(24, 128), blk, 0, stream>>>(hs, nullptr, 1 << 30, DMODEL, 0,
                                                wqkvt, nullptr, nullptr,
                                                (float*)qpb, (float*)kpb, (float*)vpb,
                                                R, 3072, 1024, 0);
    // 3. beta = sigmoid(hs @ Wb)  (MFMA, padded N)
    mgemm<1><<<dim3(1, 128), blk, 0, stream>>>(hs, nullptr, 1 << 30, DMODEL, 0,
                                               wbt, nullptr, nullptr,
                                               beta, nullptr, nullptr, R, 128, 1024, 8);
    // 4. short conv + silu (bf16 -> bf16): q: A->O, k: B->A, v: C->B.lo
    int convGrid = (int)(((size_t)R * DMODEL + 255) / 256);
    shortconv_b<<<convGrid, blk, 0, stream>>>(qpb, cqw, qcb);
    shortconv_b<<<convGrid, blk, 0, stream>>>(kpb, ckw, kcb);
    shortconv_b<<<convGrid, blk, 0, stream>>>(vpb, cvw, vbf);
    // 5/6. delta rule (all-bf16 streams)
    chunk_prep2<<<4096, blk, 0, stream>>>(qcb, kcb, vbf, beta, qcb, kcb, wu, dlt);
    delta_scan3<<<256, blk, 0, stream>>>(qcb, kcb, wu, (bf16*)dlt, ret);
    // 7. FIR once (wu dead -> bufC holds fs|fl)
    fir_compute<<<dim3(32, 8, 4), blk, 0, stream>>>(vbf, fsw, flw, fsb, flb);
    // 8. stats
    fir_stats2<<<32768, blk, 0, stream>>>(fsb, flb, dlt, vbf, stats);
    // 9. gate MLP (two row-chunks; hdn fp32 in d_out scratch, qe dead)
    const int RC = 8192;
    float* hdn = bufO;
    for (int r0 = 0; r0 < R; r0 += RC) {
        mgemm<2><<<dim3(16, RC / 128), blk, 0, stream>>>(hs + (size_t)r0 * DMODEL,
                                                         stats + (size_t)r0 * 32,
                                                         1024, DMODEL, 32, gw1t, gb1, nullptr,
                                                         hdn, nullptr, nullptr,
                                                         RC, 2048, 1056, 0);
        mgemm<3><<<dim3(1, RC / 128), blk, 0, stream>>>(hdn, nullptr, 1 << 30, 2048, 0,
                                                        gw2t, gb2, ltmp,
                                                        pbuf + (size_t)r0 * 32, nullptr, nullptr,
                                                        RC, 128, 2048, 32);
    }
    // 10. combine + RMS norm -> bufA fp32 (kn dead)
    combine2<<<32768, blk, 0, stream>>>(fsb, flb, dlt, vbf, pbuf, onw, bufA);
    // 11. final projection (MFMA) -> d_out
    mgemm<0><<<dim3(8, 128), blk, 0, stream>>>(bufA, nullptr, 1 << 30, DMODEL, 0,
                                               wot, nullptr, nullptr,
                                               out, nullptr, nullptr, R, 1024, 1024, 0);
}

// Round 9
// 1272.674 us; speedup vs baseline: 13.9089x; 1.1994x over previous
//
#include <hip/hip_runtime.h>
#include <hip/hip_bf16.h>
#include <math.h>

#define R_TOT 16384      // B*L
#define LSEQ  4096
#define DMODEL 1024
#define NHEAD 8
#define DHEAD 128        // DK = DV
#define NCHUNK 128       // LSEQ/32

typedef __hip_bfloat16 bf16;
typedef short s8v __attribute__((ext_vector_type(8)));
typedef float f4v __attribute__((ext_vector_type(4)));

__device__ __forceinline__ float sigmoidf_(float x) { return 1.f / (1.f + expf(-x)); }
__device__ __forceinline__ unsigned short f2bf(float f) {
    unsigned u = __float_as_uint(f);
    u += 0x7fffu + ((u >> 16) & 1u);
    return (unsigned short)(u >> 16);
}
__device__ __forceinline__ float bf2f(unsigned short s) {
    return __uint_as_float(((unsigned)s) << 16);
}

// ---------------------------------------------------------------------------
// Elementwise fp32 -> bf16 cast (hs), 8 elems/thread
// ---------------------------------------------------------------------------
__global__ __launch_bounds__(256)
void hcast(const float* __restrict__ x, unsigned short* __restrict__ y)
{
    size_t i = ((size_t)blockIdx.x * 256 + threadIdx.x) * 8;
    float4 a = ((const float4*)(x + i))[0];
    float4 b = ((const float4*)(x + i))[1];
    s8v o;
    o[0] = (short)f2bf(a.x); o[1] = (short)f2bf(a.y);
    o[2] = (short)f2bf(a.z); o[3] = (short)f2bf(a.w);
    o[4] = (short)f2bf(b.x); o[5] = (short)f2bf(b.y);
    o[6] = (short)f2bf(b.z); o[7] = (short)f2bf(b.w);
    *(s8v*)(y + i) = o;
}

// ---------------------------------------------------------------------------
// Transpose-cast: W (K x N fp32) -> Wt (Npad x K bf16), zero-padded rows N..Npad
// ---------------------------------------------------------------------------
__global__ __launch_bounds__(256)
void tcast(const float* __restrict__ W, unsigned short* __restrict__ Wt,
           int K, int N, int Npad)
{
    __shared__ float t[32][33];
    const int kb = blockIdx.x * 32, nb = blockIdx.y * 32;
    const int tx = threadIdx.x & 31, ty = threadIdx.x >> 5;   // ty 0..7
    for (int i = ty; i < 32; i += 8) {
        int k = kb + i, n = nb + tx;
        t[i][tx] = (k < K && n < N) ? W[(size_t)k * N + n] : 0.f;
    }
    __syncthreads();
    for (int i = ty; i < 32; i += 8) {
        int n = nb + i, k = kb + tx;
        if (n < Npad && k < K) Wt[(size_t)n * K + k] = f2bf(t[tx][i]);
    }
}

// ---------------------------------------------------------------------------
// MFMA bf16 GEMM: C = epi(A @ Bt^T).  A = bf16 MxK (split A/A2 at Ksplit),
// Bt = bf16 N x K row-major. Tile 128x128x32, 4 waves. XCD-swizzled grid
// (nwg must be divisible by 8 -> bijective relabel, same-row tiles co-XCD).
// MODE 0: fp32 out  1: sigmoid fp32 (col<Nout, stride Nout)
// MODE 2: gelu(x+bias) -> bf16   3: p-gate fp32 (col<Nout, stride Nout)
// MODE 5: qkv split -> bf16 (col/1024 -> C0/C1/C2)
// ---------------------------------------------------------------------------
template<int MODE>
__global__ __launch_bounds__(256)
void mgemm(const unsigned short* __restrict__ A, const unsigned short* __restrict__ A2,
           int Ksplit, int lda1, int lda2,
           const unsigned short* __restrict__ Bt,
           const float* __restrict__ bias, const float* __restrict__ aux,
           void* __restrict__ C0, void* __restrict__ C1, void* __restrict__ C2,
           int M, int N, int K, int Nout)
{
    __shared__ unsigned short As[128 * 40];
    __shared__ unsigned short Bs[128 * 40];
    const int tid = threadIdx.x;
    // XCD-aware bijective relabel (T1): 8 siblings of a row-panel share an XCD
    const int nwg = gridDim.x * gridDim.y;
    const int bidf = blockIdx.y * gridDim.x + blockIdx.x;
    const int nb = (bidf & 7) * (nwg >> 3) + (bidf >> 3);
    const int m0 = (nb / gridDim.x) * 128, n0 = (nb % gridDim.x) * 128;
    const int l = tid & 63;
    const int wr = (tid >> 7) & 1, wc = (tid >> 6) & 1;
    const int sr = tid >> 1, sh = (tid & 1) * 16;

    const f4v zf = {0.f, 0.f, 0.f, 0.f};
    f4v acc[4][4];
#pragma unroll
    for (int i = 0; i < 4; ++i)
#pragma unroll
        for (int j = 0; j < 4; ++j) acc[i][j] = zf;

    const int nkt = K >> 5;
    for (int kt = 0; kt < nkt; ++kt) {
        const int k0 = kt << 5;
        {
            const unsigned short* src = (k0 < Ksplit)
                ? A  + (size_t)(m0 + sr) * lda1 + (size_t)(k0 + sh)
                : A2 + (size_t)(m0 + sr) * lda2 + (size_t)(k0 - Ksplit + sh);
            s8v a0 = ((const s8v*)src)[0];
            s8v a1 = ((const s8v*)src)[1];
            *(s8v*)&As[sr * 40 + sh]     = a0;
            *(s8v*)&As[sr * 40 + sh + 8] = a1;
        }
        {
            const unsigned short* src = Bt + (size_t)(n0 + sr) * K + (size_t)(k0 + sh);
            s8v b0 = ((const s8v*)src)[0];
            s8v b1 = ((const s8v*)src)[1];
            *(s8v*)&Bs[sr * 40 + sh]     = b0;
            *(s8v*)&Bs[sr * 40 + sh + 8] = b1;
        }
        __syncthreads();
        const int fr = l & 15, fq = (l >> 4) * 8;
        s8v af[4], bfr[4];
#pragma unroll
        for (int i = 0; i < 4; ++i) {
            af[i]  = *(const s8v*)&As[(wr * 64 + i * 16 + fr) * 40 + fq];
            bfr[i] = *(const s8v*)&Bs[(wc * 64 + i * 16 + fr) * 40 + fq];
        }
#pragma unroll
        for (int i = 0; i < 4; ++i)
#pragma unroll
            for (int j = 0; j < 4; ++j)
                acc[i][j] = __builtin_amdgcn_mfma_f32_16x16x32_bf16(af[i], bfr[j], acc[i][j], 0, 0, 0);
        __syncthreads();
    }
    const int fr = l & 15, fq4 = (l >> 4) * 4;
#pragma unroll
    for (int i = 0; i < 4; ++i) {
#pragma unroll
        for (int j = 0; j < 4; ++j) {
            int col = n0 + wc * 64 + j * 16 + fr;
            if ((MODE == 1 || MODE == 3) && col >= Nout) continue;
#pragma unroll
            for (int q = 0; q < 4; ++q) {
                int row = m0 + wr * 64 + i * 16 + fq4 + q;
                float x = acc[i][j][q];
                if (MODE == 1) {
                    x = sigmoidf_(x);
                    ((float*)C0)[(size_t)row * Nout + col] = x;
                } else if (MODE == 2) {
                    x += bias[col];
                    x = 0.5f * x * (1.f + erff(x * 0.70710678118654752f));
                    ((unsigned short*)C0)[(size_t)row * N + col] = f2bf(x);
                } else if (MODE == 3) {
                    x += bias[col];
                    x *= expf(-aux[col >> 2]);
                    x = 0.02f + 0.98f * sigmoidf_(x);
                    ((float*)C0)[(size_t)row * Nout + col] = x;
                } else if (MODE == 5) {
                    unsigned short* dst = (col < 1024) ? (unsigned short*)C0
                                        : ((col < 2048) ? (unsigned short*)C1
                                                        : (unsigned short*)C2);
                    dst[(size_t)row * 1024 + (col & 1023)] = f2bf(x);
                } else {
                    ((float*)C0)[(size_t)row * N + col] = x;
                }
            }
        }
    }
}

// ---------------------------------------------------------------------------
// Short causal conv (K=4) + SiLU, bf16 in -> bf16 out (fp32 accumulation)
// ---------------------------------------------------------------------------
__global__ __launch_bounds__(256)
void shortconv_b(const unsigned short* __restrict__ x, const float* __restrict__ w,
                 unsigned short* __restrict__ y)
{
    size_t idx = (size_t)blockIdx.x * 256 + threadIdx.x;
    if (idx >= (size_t)R_TOT * DMODEL) return;
    int c = (int)(idx & (DMODEL - 1));
    long r = (long)(idx >> 10);
    int l = (int)(r & (LSEQ - 1));
    const float* wc = w + c * 4;
    float acc = 0.f;
#pragma unroll
    for (int j = 0; j < 4; ++j) {
        int xl = l - 3 + j;
        if (xl >= 0) acc += bf2f(x[(r - l + xl) * DMODEL + c]) * wc[j];
    }
    float yv = acc * sigmoidf_(acc);
    y[idx] = f2bf(yv);
}

// ---------------------------------------------------------------------------
// Phase 1: per-(b,h,chunk) prep (round-8 verified, register-disciplined)
// ---------------------------------------------------------------------------
__global__ __launch_bounds__(256)
void chunk_prep2(const unsigned short* __restrict__ qconv, const unsigned short* __restrict__ kconv,
                 const unsigned short* __restrict__ vbf, const float* __restrict__ beta,
                 unsigned short* __restrict__ qe_out, unsigned short* __restrict__ kn_out,
                 bf16* __restrict__ wu, unsigned short* __restrict__ opre)
{
    const int bid = blockIdx.x;              // (b*8+h)*128 + c
    const int c = bid & 127, h = (bid >> 7) & 7, b = bid >> 10;
    const int tid = threadIdx.x;
    const int l = tid & 63, wid = tid >> 6;

    __shared__ __align__(16) unsigned short q_b[32 * 136];
    __shared__ __align__(16) unsigned short k_b[32 * 136];
    __shared__ __align__(16) unsigned short v_b[32 * 136];
    __shared__ __align__(16) unsigned short at_b[32 * 40];
    __shared__ __align__(16) unsigned short wT[128 * 40];
    __shared__ __align__(16) unsigned short uT[128 * 40];
    __shared__ float Am[32][33];
    __shared__ float betas_s[32];

    const size_t row0 = (size_t)b * LSEQ + (size_t)c * 32;
    const size_t base = row0 * DMODEL + (size_t)h * DHEAD;
    const f4v zf = {0.f, 0.f, 0.f, 0.f};
    const int li = tid >> 3, ld0 = (tid & 7) * 16;

    // ---- phase 0: load q,k,v rows (bf16, vectorized)
    {
        const unsigned short* gq = qconv + base + (size_t)li * DMODEL + ld0;
        const unsigned short* gk = kconv + base + (size_t)li * DMODEL + ld0;
        const unsigned short* gv = vbf   + base + (size_t)li * DMODEL + ld0;
        *(uint4*)&q_b[li * 136 + ld0]     = ((const uint4*)gq)[0];
        *(uint4*)&q_b[li * 136 + ld0 + 8] = ((const uint4*)gq)[1];
        *(uint4*)&k_b[li * 136 + ld0]     = ((const uint4*)gk)[0];
        *(uint4*)&k_b[li * 136 + ld0 + 8] = ((const uint4*)gk)[1];
        *(uint4*)&v_b[li * 136 + ld0]     = ((const uint4*)gv)[0];
        *(uint4*)&v_b[li * 136 + ld0 + 8] = ((const uint4*)gv)[1];
    }
    if (tid < 32) betas_s[tid] = beta[(row0 + tid) * NHEAD + h];
    __syncthreads();

    // ---- phase 1: l2norm rows of q,k (re-read LDS, no register caching)
    {
        float sq = 0.f, sk = 0.f;
#pragma unroll
        for (int e = 0; e < 8; ++e) {
            unsigned uq = *(const unsigned*)&q_b[li * 136 + ld0 + e * 2];
            unsigned uk = *(const unsigned*)&k_b[li * 136 + ld0 + e * 2];
            float q0 = bf2f((unsigned short)uq), q1 = bf2f((unsigned short)(uq >> 16));
            float k0 = bf2f((unsigned short)uk), k1 = bf2f((unsigned short)(uk >> 16));
            sq = fmaf(q0, q0, fmaf(q1, q1, sq));
            sk = fmaf(k0, k0, fmaf(k1, k1, sk));
        }
#pragma unroll
        for (int m = 1; m < 8; m <<= 1) { sq += __shfl_xor(sq, m); sk += __shfl_xor(sk, m); }
        float rq = rsqrtf(sq + 1e-6f), rk = rsqrtf(sk + 1e-6f);
#pragma unroll
        for (int e = 0; e < 8; ++e) {
            unsigned uq = *(const unsigned*)&q_b[li * 136 + ld0 + e * 2];
            unsigned uk = *(const unsigned*)&k_b[li * 136 + ld0 + e * 2];
            unsigned pq = (unsigned)f2bf(bf2f((unsigned short)uq) * rq)
                        | ((unsigned)f2bf(bf2f((unsigned short)(uq >> 16)) * rq) << 16);
            unsigned pk = (unsigned)f2bf(bf2f((unsigned short)uk) * rk)
                        | ((unsigned)f2bf(bf2f((unsigned short)(uk >> 16)) * rk) << 16);
            *(unsigned*)&q_b[li * 136 + ld0 + e * 2] = pq;
            *(unsigned*)&k_b[li * 136 + ld0 + e * 2] = pk;
        }
    }
    __syncthreads();
    __builtin_amdgcn_sched_barrier(0);

    // ---- phase 2: kn write-through (vectorized)
    {
        unsigned short* gk = kn_out + base + (size_t)li * DMODEL + ld0;
        ((uint4*)gk)[0] = *(const uint4*)&k_b[li * 136 + ld0];
        ((uint4*)gk)[1] = *(const uint4*)&k_b[li * 136 + ld0 + 8];
    }

    // ---- phase 3: Am, at via MFMA (wave wid -> 16x16 tile (tr,tc))
    {
        const int tr = wid >> 1, tc = wid & 1;
        const int fr = l & 15, ko = (l >> 4) * 8;
        f4v accA = zf, accT = zf;
#pragma unroll
        for (int kt = 0; kt < 4; ++kt) {
            s8v ka  = *(const s8v*)&k_b[(tr * 16 + fr) * 136 + kt * 32 + ko];
            s8v qa  = *(const s8v*)&q_b[(tr * 16 + fr) * 136 + kt * 32 + ko];
            s8v kb2 = *(const s8v*)&k_b[(tc * 16 + fr) * 136 + kt * 32 + ko];
            accA = __builtin_amdgcn_mfma_f32_16x16x32_bf16(ka, kb2, accA, 0, 0, 0);
            accT = __builtin_amdgcn_mfma_f32_16x16x32_bf16(qa, kb2, accT, 0, 0, 0);
        }
        const int jloc = tc * 16 + fr;
#pragma unroll
        for (int q = 0; q < 4; ++q) {
            int iloc = tr * 16 + (l >> 4) * 4 + q;
            Am[iloc][jloc] = (iloc > jloc) ? betas_s[iloc] * accA[q] : 0.f;
            at_b[iloc * 40 + jloc] = f2bf((iloc >= jloc) ? accT[q] : 0.f);
        }
    }
    __syncthreads();
    __builtin_amdgcn_sched_barrier(0);

    // ---- phase 4: forward substitution (I+Am)x = rhs; one column per thread
    {
        float x[32];
        const int t = tid;
        if (t < 128) {
#pragma unroll
            for (int i = 0; i < 32; ++i) x[i] = betas_s[i] * bf2f(v_b[i * 136 + t]);
        } else {
            const int d = t - 128;
#pragma unroll
            for (int i = 0; i < 32; ++i) x[i] = betas_s[i] * bf2f(k_b[i * 136 + d]);
        }
#pragma unroll
        for (int i = 1; i < 32; ++i) {
            float s = 0.f;
#pragma unroll
            for (int m = 0; m < i; ++m) s = fmaf(Am[i][m], x[m], s);
            x[i] -= s;
        }
        const size_t tb = (size_t)bid * 8192;
        if (t < 128) {
#pragma unroll
            for (int i2 = 0; i2 < 16; ++i2) {
                unsigned short b0 = f2bf(x[i2 * 2]), b1 = f2bf(x[i2 * 2 + 1]);
                *(unsigned*)&uT[t * 40 + i2 * 2] = (unsigned)b0 | ((unsigned)b1 << 16);
                wu[tb + 4096 + (i2 * 2) * 128 + t]     = __float2bfloat16(x[i2 * 2]);
                wu[tb + 4096 + (i2 * 2 + 1) * 128 + t] = __float2bfloat16(x[i2 * 2 + 1]);
            }
        } else {
            const int d = t - 128;
#pragma unroll
            for (int i2 = 0; i2 < 16; ++i2) {
                unsigned short b0 = f2bf(x[i2 * 2]), b1 = f2bf(x[i2 * 2 + 1]);
                *(unsigned*)&wT[d * 40 + i2 * 2] = (unsigned)b0 | ((unsigned)b1 << 16);
                wu[tb + (i2 * 2) * 128 + d]     = __float2bfloat16(x[i2 * 2]);
                wu[tb + (i2 * 2 + 1) * 128 + d] = __float2bfloat16(x[i2 * 2 + 1]);
            }
        }
    }
    __syncthreads();
    __builtin_amdgcn_sched_barrier(0);

    // ---- phase 5: qe = qn - at@w ; o_pre = at@u  (split by rt to limit liveness)
    {
        const int fr = l & 15, ko = (l >> 4) * 8;
        const int ct0 = wid * 2, ct1 = wid * 2 + 1;
#pragma unroll
        for (int rt = 0; rt < 2; ++rt) {
            s8v a   = *(const s8v*)&at_b[(rt * 16 + fr) * 40 + ko];
            s8v bw0 = *(const s8v*)&wT[(ct0 * 16 + fr) * 40 + ko];
            s8v bw1 = *(const s8v*)&wT[(ct1 * 16 + fr) * 40 + ko];
            s8v bu0 = *(const s8v*)&uT[(ct0 * 16 + fr) * 40 + ko];
            s8v bu1 = *(const s8v*)&uT[(ct1 * 16 + fr) * 40 + ko];
            f4v qw0 = __builtin_amdgcn_mfma_f32_16x16x32_bf16(a, bw0, zf, 0, 0, 0);
            f4v qw1 = __builtin_amdgcn_mfma_f32_16x16x32_bf16(a, bw1, zf, 0, 0, 0);
            f4v ou0 = __builtin_amdgcn_mfma_f32_16x16x32_bf16(a, bu0, zf, 0, 0, 0);
            f4v ou1 = __builtin_amdgcn_mfma_f32_16x16x32_bf16(a, bu1, zf, 0, 0, 0);
#pragma unroll
            for (int q = 0; q < 4; ++q) {
                const int i = rt * 16 + (l >> 4) * 4 + q;
                {
                    const int d = ct0 * 16 + fr;
                    size_t g = base + (size_t)i * DMODEL + d;
                    qe_out[g] = f2bf(bf2f(q_b[i * 136 + d]) - qw0[q]);
                    opre[g]   = f2bf(ou0[q]);
                }
                {
                    const int d = ct1 * 16 + fr;
                    size_t g = base + (size_t)i * DMODEL + d;
                    qe_out[g] = f2bf(bf2f(q_b[i * 136 + d]) - qw1[q]);
                    opre[g]   = f2bf(ou1[q]);
                }
            }
            __builtin_amdgcn_sched_barrier(0);
        }
    }
}

// ---------------------------------------------------------------------------
// Phase 2: MFMA state scan (unchanged, round-6/7/8 verified)
// ---------------------------------------------------------------------------
__global__ __launch_bounds__(256)
void delta_scan3(const unsigned short* __restrict__ qe, const unsigned short* __restrict__ kn,
                 const bf16* __restrict__ wu, bf16* __restrict__ delta,
                 const float* __restrict__ ret)
{
    const int bid0 = blockIdx.x;
    const int dvs = (bid0 >> 3) & 7;                      // dv-slice
    const int bh  = ((bid0 >> 6) << 3) | (bid0 & 7);      // xcd-stable bh
    const int h = bh & 7, b = bh >> 3;
    const int tid = threadIdx.x;
    const int l = tid & 63, wid = tid >> 6;

    __shared__ __align__(16) unsigned short qe_b[32 * 136];
    __shared__ __align__(16) unsigned short w_b [32 * 136];
    __shared__ __align__(16) unsigned short knT [128 * 40];
    __shared__ __align__(16) unsigned short St_b[16 * 136];
    __shared__ __align__(16) unsigned short uaT [16 * 40];
    __shared__ float us_s[32][18], ops_s[32][18];

    const float lam = 0.6f + 0.4f * sigmoidf_(ret[h]);

    for (int i = tid; i < 16 * 136; i += 256) St_b[i] = 0;

    const int li = tid >> 3, ld0 = (tid & 7) * 16;
    const int iu = tid >> 3, tu = (tid & 7) * 2;
    const size_t headoff = (size_t)h * DHEAD;

    const f4v zf = {0.f, 0.f, 0.f, 0.f};
    f4v Sacc0 = zf, Sacc1 = zf;        // this wave's S d-tiles (d0 = wid*32)

    uint4 pq[2], pk[2], pw[2];
    unsigned puv, pov;

#define ISSUE(cc)  {                                                                        \
        size_t rb = ((size_t)b * LSEQ + (size_t)(cc) * 32);                                 \
        const unsigned short* gq = qe + (rb + li) * DMODEL + headoff + ld0;                 \
        const unsigned short* gk = kn + (rb + li) * DMODEL + headoff + ld0;                 \
        pq[0] = ((const uint4*)gq)[0]; pq[1] = ((const uint4*)gq)[1];                       \
        pk[0] = ((const uint4*)gk)[0]; pk[1] = ((const uint4*)gk)[1];                       \
        size_t tb = ((size_t)bh * NCHUNK + (cc)) * 8192;                                    \
        const uint4* gw = (const uint4*)(wu + tb + li * 128 + ld0);                         \
        pw[0] = gw[0]; pw[1] = gw[1];                                                       \
        puv = *(const unsigned*)(wu + tb + 4096 + iu * 128 + dvs * 16 + tu);                \
        pov = *(const unsigned*)(delta + (rb + iu) * DMODEL + headoff + dvs * 16 + tu);     \
    }

    ISSUE(0);

    for (int c = 0; c < NCHUNK; ++c) {
        // ---- unpack prefetched regs -> LDS (qe, w direct; kn -> knT transpose)
        *(uint4*)&qe_b[li * 136 + ld0]     = pq[0];
        *(uint4*)&qe_b[li * 136 + ld0 + 8] = pq[1];
        {
            const unsigned short* pks = (const unsigned short*)&pk[0];
#pragma unroll
            for (int e = 0; e < 16; ++e)
                knT[(ld0 + e) * 40 + li] = pks[e];
        }
        *(uint4*)&w_b[li * 136 + ld0]     = pw[0];
        *(uint4*)&w_b[li * 136 + ld0 + 8] = pw[1];
        {
            us_s[iu][tu]      = bf2f((unsigned short)puv);
            us_s[iu][tu + 1]  = bf2f((unsigned short)(puv >> 16));
            ops_s[iu][tu]     = bf2f((unsigned short)pov);
            ops_s[iu][tu + 1] = bf2f((unsigned short)(pov >> 16));
        }
        if (c + 1 < NCHUNK) ISSUE(c + 1);
        __syncthreads();

        // ---- phase A: waves 0,1 -> ua = u - w@S ; waves 2,3 -> o = opre + qe@S
        {
            const int half = wid & 1;
            const int arow = half * 16 + (l & 15);
            const int koff = (l >> 4) * 8;
            const unsigned short* ab = (wid < 2) ? w_b : qe_b;
            f4v a = zf;
#pragma unroll
            for (int kt = 0; kt < 4; ++kt) {
                s8v af  = *(const s8v*)&ab[arow * 136 + kt * 32 + koff];
                s8v bf_ = *(const s8v*)&St_b[(l & 15) * 136 + kt * 32 + koff];
                a = __builtin_amdgcn_mfma_f32_16x16x32_bf16(af, bf_, a, 0, 0, 0);
            }
            const int ib = half * 16 + ((l >> 4) << 2);
            const int t = l & 15;
            if (wid < 2) {
#pragma unroll
                for (int q = 0; q < 4; ++q) {
                    float v = us_s[ib + q][t] - a[q];
                    uaT[t * 40 + ib + q] = f2bf(v);
                }
            } else {
                size_t rb = (size_t)b * LSEQ + (size_t)c * 32;
#pragma unroll
                for (int q = 0; q < 4; ++q) {
                    float v = ops_s[ib + q][t] + a[q];
                    delta[(rb + ib + q) * DMODEL + headoff + dvs * 16 + t] = __float2bfloat16(v);
                }
            }
        }
        __syncthreads();

        // ---- phase B: Sacc = lam*Sacc + uaT @ knT ; export bf16 St_b
        {
#pragma unroll
            for (int q = 0; q < 4; ++q) { Sacc0[q] *= lam; Sacc1[q] *= lam; }
            const int koff = (l >> 4) * 8;
            s8v af = *(const s8v*)&uaT[(l & 15) * 40 + koff];
            const int d0 = wid * 32;
            s8v b0 = *(const s8v*)&knT[(d0 + (l & 15)) * 40 + koff];
            s8v b1 = *(const s8v*)&knT[(d0 + 16 + (l & 15)) * 40 + koff];
            Sacc0 = __builtin_amdgcn_mfma_f32_16x16x32_bf16(af, b0, Sacc0, 0, 0, 0);
            Sacc1 = __builtin_amdgcn_mfma_f32_16x16x32_bf16(af, b1, Sacc1, 0, 0, 0);
            const int tr = (l >> 4) << 2;
#pragma unroll
            for (int q = 0; q < 4; ++q) {
                St_b[(tr + q) * 136 + d0 + (l & 15)]      = f2bf(Sacc0[q]);
                St_b[(tr + q) * 136 + d0 + 16 + (l & 15)] = f2bf(Sacc1[q]);
            }
        }
        __syncthreads();
    }
#undef ISSUE
}

// ---------------------------------------------------------------------------
// FIR computed once, LDS-tiled (unchanged)
// ---------------------------------------------------------------------------
__global__ __launch_bounds__(256)
void fir_compute(const unsigned short* __restrict__ v,
                 const float* __restrict__ wshort, const float* __restrict__ wlong,
                 unsigned short* __restrict__ fso, unsigned short* __restrict__ flo)
{
    const int lt = blockIdx.x, h = blockIdx.y, b = blockIdx.z;
    const int tid = threadIdx.x;
    __shared__ unsigned short vt[190 * 128];
    __shared__ float wl[63 * 128];
    __shared__ float w3[3 * 128];

    for (int i = tid; i < 63 * 128; i += 256) {
        int j = i >> 7, d = i & 127;
        wl[i] = wlong[((size_t)h * 128 + d) * 63 + j];
    }
    for (int i = tid; i < 3 * 128; i += 256) {
        int j = i >> 7, d = i & 127;
        w3[i] = wshort[((size_t)h * 128 + d) * 3 + j];
    }
    const size_t vbase = ((size_t)b * LSEQ) * DMODEL + (size_t)h * DHEAD;
    const int l0 = lt * 128;
    const s8v z8 = {0, 0, 0, 0, 0, 0, 0, 0};
    for (int i = tid; i < 190 * 16; i += 256) {
        int row = i >> 4, dblk = (i & 15) * 8;
        int gl = l0 - 62 + row;
        s8v val = z8;
        if (gl >= 0) val = *(const s8v*)&v[vbase + (size_t)gl * DMODEL + dblk];
        *(s8v*)&vt[row * 128 + dblk] = val;
    }
    __syncthreads();

    const int dp = (tid & 63) * 2, lg = tid >> 6;
    for (int lc = 0; lc < 4; ++lc) {
        const int lb = lg * 32 + lc * 8;
        float a0[8], a1[8], s0[8], s1[8];
#pragma unroll
        for (int li = 0; li < 8; ++li) { a0[li] = a1[li] = s0[li] = s1[li] = 0.f; }
        for (int j = 0; j < 63; ++j) {
            float w0 = wl[j * 128 + dp], w1 = wl[j * 128 + dp + 1];
#pragma unroll
            for (int li = 0; li < 8; ++li) {
                unsigned vv = *(const unsigned*)&vt[(lb + li + j) * 128 + dp];
                a0[li] = fmaf(bf2f((unsigned short)vv), w0, a0[li]);
                a1[li] = fmaf(bf2f((unsigned short)(vv >> 16)), w1, a1[li]);
            }
        }
#pragma unroll
        for (int j = 0; j < 3; ++j) {
            float w0 = w3[j * 128 + dp], w1 = w3[j * 128 + dp + 1];
#pragma unroll
            for (int li = 0; li < 8; ++li) {
                unsigned vv = *(const unsigned*)&vt[(lb + li + 60 + j) * 128 + dp];
                s0[li] = fmaf(bf2f((unsigned short)vv), w0, s0[li]);
                s1[li] = fmaf(bf2f((unsigned short)(vv >> 16)), w1, s1[li]);
            }
        }
        const size_t ob = ((size_t)b * LSEQ + l0) * DMODEL + (size_t)h * DHEAD + dp;
#pragma unroll
        for (int li = 0; li < 8; ++li) {
            unsigned pf = (unsigned)f2bf(a0[li]) | ((unsigned)f2bf(a1[li]) << 16);
            unsigned ps = (unsigned)f2bf(s0[li]) | ((unsigned)f2bf(s1[li]) << 16);
            *(unsigned*)&flo[ob + (size_t)(lb + li) * DMODEL] = pf;
            *(unsigned*)&fso[ob + (size_t)(lb + li) * DMODEL] = ps;
        }
    }
}

// ---------------------------------------------------------------------------
// Stats: one wave per (r,h) row; bf16 output (feeds gate1 A2)
// ---------------------------------------------------------------------------
__global__ __launch_bounds__(256)
void fir_stats2(const unsigned short* __restrict__ fs, const unsigned short* __restrict__ fl,
                const unsigned short* __restrict__ dlt, const unsigned short* __restrict__ v,
                unsigned short* __restrict__ stats)
{
    const int rh = blockIdx.x * 4 + (threadIdx.x >> 6);
    const int lane = threadIdx.x & 63;
    const int r = rh >> 3, h = rh & 7;
    const size_t base = (size_t)r * DMODEL + (size_t)h * DHEAD + lane * 2;
    unsigned ua = *(const unsigned*)(fs + base);
    unsigned ub = *(const unsigned*)(fl + base);
    unsigned uc = *(const unsigned*)(dlt + base);
    unsigned ud = *(const unsigned*)(v + base);
    float s0 = bf2f((unsigned short)ua) + bf2f((unsigned short)(ua >> 16));
    float s1 = bf2f((unsigned short)ub) + bf2f((unsigned short)(ub >> 16));
    float s2 = bf2f((unsigned short)uc) + bf2f((unsigned short)(uc >> 16));
    float s3 = bf2f((unsigned short)ud) + bf2f((unsigned short)(ud >> 16));
#pragma unroll
    for (int m = 1; m < 64; m <<= 1) {
        s0 += __shfl_xor(s0, m); s1 += __shfl_xor(s1, m);
        s2 += __shfl_xor(s2, m); s3 += __shfl_xor(s3, m);
    }
    if (lane == 0) {
        const float inv = 1.f / 128.f;
        stats[(size_t)r * 32 + 0  + h] = f2bf(s0 * inv);
        stats[(size_t)r * 32 + 8  + h] = f2bf(s1 * inv);
        stats[(size_t)r * 32 + 16 + h] = f2bf(s2 * inv);
        stats[(size_t)r * 32 + 24 + h] = f2bf(s3 * inv);
    }
}

// ---------------------------------------------------------------------------
// Combine + RMS norm; bf16 output (feeds final MFMA GEMM)
// ---------------------------------------------------------------------------
__global__ __launch_bounds__(256)
void combine2(const unsigned short* __restrict__ fs, const unsigned short* __restrict__ fl,
              const unsigned short* __restrict__ dlt, const unsigned short* __restrict__ v,
              const float* __restrict__ p, const float* __restrict__ onw,
              unsigned short* __restrict__ on)
{
    const int rh = blockIdx.x * 4 + (threadIdx.x >> 6);
    const int lane = threadIdx.x & 63;
    const int r = rh >> 3, h = rh & 7;
    const size_t base = (size_t)r * DMODEL + (size_t)h * DHEAD + lane * 2;
    unsigned ua = *(const unsigned*)(fs + base);
    unsigned ub = *(const unsigned*)(fl + base);
    unsigned uc = *(const unsigned*)(dlt + base);
    unsigned ud = *(const unsigned*)(v + base);
    const float* pp = p + (size_t)r * 32 + h * 4;
    float p0 = pp[0], p1 = pp[1], p2 = pp[2], p3 = pp[3];
    float ox = p0 * bf2f((unsigned short)ua) + p1 * bf2f((unsigned short)ub)
             + p2 * bf2f((unsigned short)uc) + p3 * bf2f((unsigned short)ud);
    float oy = p0 * bf2f((unsigned short)(ua >> 16)) + p1 * bf2f((unsigned short)(ub >> 16))
             + p2 * bf2f((unsigned short)(uc >> 16)) + p3 * bf2f((unsigned short)(ud >> 16));
    float ss = ox * ox + oy * oy;
#pragma unroll
    for (int m = 1; m < 64; m <<= 1) ss += __shfl_xor(ss, m);
    float sc = rsqrtf(ss * (1.f / 128.f) + 1e-5f);
    unsigned pw = (unsigned)f2bf(ox * sc * onw[lane * 2])
                | ((unsigned)f2bf(oy * sc * onw[lane * 2 + 1]) << 16);
    *(unsigned*)(on + base) = pw;
}

// ---------------------------------------------------------------------------
// Workspace (~202.5 MB). All activation streams bf16 (32MB halves):
//  A.lo: qpb -> kcb/kn -> o_norm     A.hi: kpb -> vbf
//  B.lo: vpb -> opre/delta           B.hi: qcb/qe -> hdn
//  C   : wu tiles -> [C.lo: fs][C.hi: fl]
//  O.lo(d_out): hsb bf16             O.hi: wqkvt   -> final out fp32 (full)
// ---------------------------------------------------------------------------
extern "C" void kernel_launch(void* const* d_in, const int* in_sizes, int n_in,
                              void* d_out, int out_size, void* d_ws, size_t ws_size,
                              hipStream_t stream)
{
    const float* hs   = (const float*)d_in[0];
    const float* Wq   = (const float*)d_in[1];
    const float* Wk   = (const float*)d_in[2];
    const float* Wv   = (const float*)d_in[3];
    const float* Wb   = (const float*)d_in[4];
    const float* cqw  = (const float*)d_in[5];
    const float* ckw  = (const float*)d_in[6];
    const float* cvw  = (const float*)d_in[7];
    const float* ret  = (const float*)d_in[8];
    const float* fsw  = (const float*)d_in[9];
    const float* flw  = (const float*)d_in[10];
    const float* gw1  = (const float*)d_in[11];
    const float* gb1  = (const float*)d_in[12];
    const float* gw2  = (const float*)d_in[13];
    const float* gb2  = (const float*)d_in[14];
    const float* ltmp = (const float*)d_in[15];
    const float* onw  = (const float*)d_in[16];
    const float* Wo   = (const float*)d_in[17];
    float* out = (float*)d_out;

    char* wsp = (char*)d_ws;
    size_t off = 0;
    auto alloc = [&](size_t nbytes) -> void* {
        void* pt = (void*)(wsp + off);
        off += ((nbytes + 255) / 256) * 256;
        return pt;
    };
    const int R = R_TOT;
    const size_t HALF = (size_t)R * DMODEL;        // elements per 32MB half
    float* bufA  = (float*)alloc(HALF * 4);
    float* bufB  = (float*)alloc(HALF * 4);
    float* bufC  = (float*)alloc(HALF * 4);
    float* beta  = (float*)alloc((size_t)R * NHEAD * 4);
    unsigned short* statsb = (unsigned short*)alloc((size_t)R * 32 * 2);
    float* pbuf  = (float*)alloc((size_t)R * 32 * 4);
    unsigned short* gw1t = (unsigned short*)alloc((size_t)2048 * 1056 * 2);
    unsigned short* wot  = (unsigned short*)alloc((size_t)1024 * 1024 * 2);
    unsigned short* wbt  = (unsigned short*)alloc((size_t)128 * 1024 * 2);
    unsigned short* gw2t = (unsigned short*)alloc((size_t)128 * 2048 * 2);

    unsigned short* Alo = (unsigned short*)bufA;  unsigned short* Ahi = Alo + HALF;
    unsigned short* Blo = (unsigned short*)bufB;  unsigned short* Bhi = Blo + HALF;
    unsigned short* Clo = (unsigned short*)bufC;  unsigned short* Chi = Clo + HALF;
    unsigned short* Olo = (unsigned short*)d_out; unsigned short* Ohi = Olo + HALF;

    unsigned short* hsb   = Olo;                  // hs bf16
    unsigned short* wqkvt = Ohi;                  // 3072x1024 bf16 = 6MB
    unsigned short* qpb = Alo, *kpb = Ahi, *vpb = Blo;
    unsigned short* qcb = Bhi, *kcb = Alo, *vbf = Ahi;
    bf16* wu = (bf16*)bufC;
    unsigned short* dlt = Blo;                    // opre -> delta
    unsigned short* fsb = Clo, *flb = Chi;
    unsigned short* hdnb = Bhi;                   // gate1 out bf16
    unsigned short* onb = Alo;                    // o_norm bf16
    (void)ws_size; (void)in_sizes; (void)n_in; (void)out_size;

    dim3 blk(256);
    // 0. hs -> bf16
    hcast<<<(int)(HALF / (256 * 8)), blk, 0, stream>>>(hs, hsb);
    // 1. weight transposes / pads
    tcast<<<dim3(32, 32), blk, 0, stream>>>(Wq, wqkvt, 1024, 1024, 1024);
    tcast<<<dim3(32, 32), blk, 0, stream>>>(Wk, wqkvt + (size_t)1024 * 1024, 1024, 1024, 1024);
    tcast<<<dim3(32, 32), blk, 0, stream>>>(Wv, wqkvt + (size_t)2048 * 1024, 1024, 1024, 1024);
    tcast<<<dim3(33, 64), blk, 0, stream>>>(gw1, gw1t, 1056, 2048, 2048);
    tcast<<<dim3(32, 32), blk, 0, stream>>>(Wo, wot, 1024, 1024, 1024);
    tcast<<<dim3(32, 4),  blk, 0, stream>>>(Wb, wbt, 1024, 8, 128);
    tcast<<<dim3(64, 4),  blk, 0, stream>>>(gw2, gw2t, 2048, 32, 128);

    // 2. fused qkv projection (bf16 A, bf16 out)
    mgemm<5><<<dim3(24, 128), blk, 0, stream>>>(hsb, nullptr, 1 << 30, DMODEL, 0,
                                                wqkvt, nullptr, nullptr,
                                                qpb, kpb, vpb, R, 3072, 1024, 0);
    // 3. beta = sigmoid(hs @ Wb)
    mgemm<1><<<dim3(1, 128), blk, 0, stream>>>(hsb, nullptr, 1 << 30, DMODEL, 0,
                                               wbt, nullptr, nullptr,
                                               beta, nullptr, nullptr, R, 128, 1024, 8);
    // 4. short conv + silu: q: A.lo->B.hi, k: A.hi->A.lo, v: B.lo->A.hi
    int convGrid = (int)(((size_t)R * DMODEL + 255) / 256);
    shortconv_b<<<convGrid, blk, 0, stream>>>(qpb, cqw, qcb);
    shortconv_b<<<convGrid, blk, 0, stream>>>(kpb, ckw, kcb);
    shortconv_b<<<convGrid, blk, 0, stream>>>(vpb, cvw, vbf);
    // 5/6. delta rule
    chunk_prep2<<<4096, blk, 0, stream>>>(qcb, kcb, vbf, beta, qcb, kcb, wu, dlt);
    delta_scan3<<<256, blk, 0, stream>>>(qcb, kcb, wu, (bf16*)dlt, ret);
    // 7. FIR once (wu dead -> bufC holds fs|fl)
    fir_compute<<<dim3(32, 8, 4), blk, 0, stream>>>(vbf, fsw, flw, fsb, flb);
    // 8. stats (bf16)
    fir_stats2<<<32768, blk, 0, stream>>>(fsb, flb, dlt, vbf, statsb);
    // 9. gate MLP (two row-chunks; hdn bf16 in B.hi — qe dead)
    const int RC = 8192;
    for (int r0 = 0; r0 < R; r0 += RC) {
        mgemm<2><<<dim3(16, RC / 128), blk, 0, stream>>>(hsb + (size_t)r0 * DMODEL,
                                                         statsb + (size_t)r0 * 32,
                                                         1024, DMODEL, 32, gw1t, gb1, nullptr,
                                                         hdnb, nullptr, nullptr,
                                                         RC, 2048, 1056, 0);
        mgemm<3><<<dim3(1, RC / 128), blk, 0, stream>>>(hdnb, nullptr, 1 << 30, 2048, 0,
                                                        gw2t, gb2, ltmp,
                                                        pbuf + (size_t)r0 * 32, nullptr, nullptr,
                                                        RC, 128, 2048, 32);
    }
    // 10. combine + RMS norm -> o_norm bf16 (A.lo, kn dead)
    combine2<<<32768, blk, 0, stream>>>(fsb, flb, dlt, vbf, pbuf, onw, onb);
    // 11. final projection -> d_out fp32 (hsb/wqkvt dead)
    mgemm<0><<<dim3(8, 128), blk, 0, stream>>>(onb, nullptr, 1 << 30, DMODEL, 0,
                                               wot, nullptr, nullptr,
                                               out, nullptr, nullptr, R, 1024, 1024, 0);
}

// Round 10
// 1233.620 us; speedup vs baseline: 14.3492x; 1.0317x over previous
//
#include <hip/hip_runtime.h>
#include <hip/hip_bf16.h>
#include <math.h>

#define R_TOT 16384      // B*L
#define LSEQ  4096
#define DMODEL 1024
#define NHEAD 8
#define DHEAD 128        // DK = DV
#define NCHUNK 128       // LSEQ/32

typedef __hip_bfloat16 bf16;
typedef short s8v __attribute__((ext_vector_type(8)));
typedef float f4v __attribute__((ext_vector_type(4)));

__device__ __forceinline__ float sigmoidf_(float x) { return 1.f / (1.f + expf(-x)); }
__device__ __forceinline__ unsigned short f2bf(float f) {
    unsigned u = __float_as_uint(f);
    u += 0x7fffu + ((u >> 16) & 1u);
    return (unsigned short)(u >> 16);
}
__device__ __forceinline__ float bf2f(unsigned short s) {
    return __uint_as_float(((unsigned)s) << 16);
}

// ---------------------------------------------------------------------------
// Elementwise fp32 -> bf16 cast (hs), 8 elems/thread
// ---------------------------------------------------------------------------
__global__ __launch_bounds__(256)
void hcast(const float* __restrict__ x, unsigned short* __restrict__ y)
{
    size_t i = ((size_t)blockIdx.x * 256 + threadIdx.x) * 8;
    float4 a = ((const float4*)(x + i))[0];
    float4 b = ((const float4*)(x + i))[1];
    s8v o;
    o[0] = (short)f2bf(a.x); o[1] = (short)f2bf(a.y);
    o[2] = (short)f2bf(a.z); o[3] = (short)f2bf(a.w);
    o[4] = (short)f2bf(b.x); o[5] = (short)f2bf(b.y);
    o[6] = (short)f2bf(b.z); o[7] = (short)f2bf(b.w);
    *(s8v*)(y + i) = o;
}

// ---------------------------------------------------------------------------
// Transpose-cast: W (K x N fp32) -> Wt (Npad x K bf16), zero-padded rows N..Npad
// ---------------------------------------------------------------------------
__global__ __launch_bounds__(256)
void tcast(const float* __restrict__ W, unsigned short* __restrict__ Wt,
           int K, int N, int Npad)
{
    __shared__ float t[32][33];
    const int kb = blockIdx.x * 32, nb = blockIdx.y * 32;
    const int tx = threadIdx.x & 31, ty = threadIdx.x >> 5;   // ty 0..7
    for (int i = ty; i < 32; i += 8) {
        int k = kb + i, n = nb + tx;
        t[i][tx] = (k < K && n < N) ? W[(size_t)k * N + n] : 0.f;
    }
    __syncthreads();
    for (int i = ty; i < 32; i += 8) {
        int n = nb + i, k = kb + tx;
        if (n < Npad && k < K) Wt[(size_t)n * K + k] = f2bf(t[tx][i]);
    }
}

// ---------------------------------------------------------------------------
// MFMA bf16 GEMM: C = epi(A @ Bt^T).  A = bf16 MxK (split A/A2 at Ksplit),
// Bt = bf16 N x K row-major. Tile 128x128x32, 4 waves. XCD-swizzled grid.
// MODE 0: fp32 out  1: sigmoid fp32 (col<Nout, stride Nout)
// MODE 2: gelu(x+bias) -> bf16   3: p-gate fp32 (col<Nout, stride Nout)
// MODE 5: qkv split -> bf16 (col/1024 -> C0/C1/C2)
// ---------------------------------------------------------------------------
template<int MODE>
__global__ __launch_bounds__(256)
void mgemm(const unsigned short* __restrict__ A, const unsigned short* __restrict__ A2,
           int Ksplit, int lda1, int lda2,
           const unsigned short* __restrict__ Bt,
           const float* __restrict__ bias, const float* __restrict__ aux,
           void* __restrict__ C0, void* __restrict__ C1, void* __restrict__ C2,
           int M, int N, int K, int Nout)
{
    __shared__ unsigned short As[128 * 40];
    __shared__ unsigned short Bs[128 * 40];
    const int tid = threadIdx.x;
    const int nwg = gridDim.x * gridDim.y;
    const int bidf = blockIdx.y * gridDim.x + blockIdx.x;
    const int nb = (bidf & 7) * (nwg >> 3) + (bidf >> 3);
    const int m0 = (nb / gridDim.x) * 128, n0 = (nb % gridDim.x) * 128;
    const int l = tid & 63;
    const int wr = (tid >> 7) & 1, wc = (tid >> 6) & 1;
    const int sr = tid >> 1, sh = (tid & 1) * 16;

    const f4v zf = {0.f, 0.f, 0.f, 0.f};
    f4v acc[4][4];
#pragma unroll
    for (int i = 0; i < 4; ++i)
#pragma unroll
        for (int j = 0; j < 4; ++j) acc[i][j] = zf;

    const int nkt = K >> 5;
    for (int kt = 0; kt < nkt; ++kt) {
        const int k0 = kt << 5;
        {
            const unsigned short* src = (k0 < Ksplit)
                ? A  + (size_t)(m0 + sr) * lda1 + (size_t)(k0 + sh)
                : A2 + (size_t)(m0 + sr) * lda2 + (size_t)(k0 - Ksplit + sh);
            s8v a0 = ((const s8v*)src)[0];
            s8v a1 = ((const s8v*)src)[1];
            *(s8v*)&As[sr * 40 + sh]     = a0;
            *(s8v*)&As[sr * 40 + sh + 8] = a1;
        }
        {
            const unsigned short* src = Bt + (size_t)(n0 + sr) * K + (size_t)(k0 + sh);
            s8v b0 = ((const s8v*)src)[0];
            s8v b1 = ((const s8v*)src)[1];
            *(s8v*)&Bs[sr * 40 + sh]     = b0;
            *(s8v*)&Bs[sr * 40 + sh + 8] = b1;
        }
        __syncthreads();
        const int fr = l & 15, fq = (l >> 4) * 8;
        s8v af[4], bfr[4];
#pragma unroll
        for (int i = 0; i < 4; ++i) {
            af[i]  = *(const s8v*)&As[(wr * 64 + i * 16 + fr) * 40 + fq];
            bfr[i] = *(const s8v*)&Bs[(wc * 64 + i * 16 + fr) * 40 + fq];
        }
#pragma unroll
        for (int i = 0; i < 4; ++i)
#pragma unroll
            for (int j = 0; j < 4; ++j)
                acc[i][j] = __builtin_amdgcn_mfma_f32_16x16x32_bf16(af[i], bfr[j], acc[i][j], 0, 0, 0);
        __syncthreads();
    }
    const int fr = l & 15, fq4 = (l >> 4) * 4;
#pragma unroll
    for (int i = 0; i < 4; ++i) {
#pragma unroll
        for (int j = 0; j < 4; ++j) {
            int col = n0 + wc * 64 + j * 16 + fr;
            if ((MODE == 1 || MODE == 3) && col >= Nout) continue;
#pragma unroll
            for (int q = 0; q < 4; ++q) {
                int row = m0 + wr * 64 + i * 16 + fq4 + q;
                float x = acc[i][j][q];
                if (MODE == 1) {
                    x = sigmoidf_(x);
                    ((float*)C0)[(size_t)row * Nout + col] = x;
                } else if (MODE == 2) {
                    x += bias[col];
                    x = 0.5f * x * (1.f + erff(x * 0.70710678118654752f));
                    ((unsigned short*)C0)[(size_t)row * N + col] = f2bf(x);
                } else if (MODE == 3) {
                    x += bias[col];
                    x *= expf(-aux[col >> 2]);
                    x = 0.02f + 0.98f * sigmoidf_(x);
                    ((float*)C0)[(size_t)row * Nout + col] = x;
                } else if (MODE == 5) {
                    unsigned short* dst = (col < 1024) ? (unsigned short*)C0
                                        : ((col < 2048) ? (unsigned short*)C1
                                                        : (unsigned short*)C2);
                    dst[(size_t)row * 1024 + (col & 1023)] = f2bf(x);
                } else {
                    ((float*)C0)[(size_t)row * N + col] = x;
                }
            }
        }
    }
}

// ---------------------------------------------------------------------------
// Short causal conv (K=4) + SiLU, bf16 in -> bf16 out (fp32 accumulation)
// ---------------------------------------------------------------------------
__global__ __launch_bounds__(256)
void shortconv_b(const unsigned short* __restrict__ x, const float* __restrict__ w,
                 unsigned short* __restrict__ y)
{
    size_t idx = (size_t)blockIdx.x * 256 + threadIdx.x;
    if (idx >= (size_t)R_TOT * DMODEL) return;
    int c = (int)(idx & (DMODEL - 1));
    long r = (long)(idx >> 10);
    int l = (int)(r & (LSEQ - 1));
    const float* wc = w + c * 4;
    float acc = 0.f;
#pragma unroll
    for (int j = 0; j < 4; ++j) {
        int xl = l - 3 + j;
        if (xl >= 0) acc += bf2f(x[(r - l + xl) * DMODEL + c]) * wc[j];
    }
    float yv = acc * sigmoidf_(acc);
    y[idx] = f2bf(yv);
}

// ---------------------------------------------------------------------------
// Phase 1: per-(b,h,chunk) prep (round-8/9 verified, register-disciplined)
// ---------------------------------------------------------------------------
__global__ __launch_bounds__(256)
void chunk_prep2(const unsigned short* __restrict__ qconv, const unsigned short* __restrict__ kconv,
                 const unsigned short* __restrict__ vbf, const float* __restrict__ beta,
                 unsigned short* __restrict__ qe_out, unsigned short* __restrict__ kn_out,
                 bf16* __restrict__ wu, unsigned short* __restrict__ opre)
{
    const int bid = blockIdx.x;              // (b*8+h)*128 + c
    const int c = bid & 127, h = (bid >> 7) & 7, b = bid >> 10;
    const int tid = threadIdx.x;
    const int l = tid & 63, wid = tid >> 6;

    __shared__ __align__(16) unsigned short q_b[32 * 136];
    __shared__ __align__(16) unsigned short k_b[32 * 136];
    __shared__ __align__(16) unsigned short v_b[32 * 136];
    __shared__ __align__(16) unsigned short at_b[32 * 40];
    __shared__ __align__(16) unsigned short wT[128 * 40];
    __shared__ __align__(16) unsigned short uT[128 * 40];
    __shared__ float Am[32][33];
    __shared__ float betas_s[32];

    const size_t row0 = (size_t)b * LSEQ + (size_t)c * 32;
    const size_t base = row0 * DMODEL + (size_t)h * DHEAD;
    const f4v zf = {0.f, 0.f, 0.f, 0.f};
    const int li = tid >> 3, ld0 = (tid & 7) * 16;

    // ---- phase 0: load q,k,v rows (bf16, vectorized)
    {
        const unsigned short* gq = qconv + base + (size_t)li * DMODEL + ld0;
        const unsigned short* gk = kconv + base + (size_t)li * DMODEL + ld0;
        const unsigned short* gv = vbf   + base + (size_t)li * DMODEL + ld0;
        *(uint4*)&q_b[li * 136 + ld0]     = ((const uint4*)gq)[0];
        *(uint4*)&q_b[li * 136 + ld0 + 8] = ((const uint4*)gq)[1];
        *(uint4*)&k_b[li * 136 + ld0]     = ((const uint4*)gk)[0];
        *(uint4*)&k_b[li * 136 + ld0 + 8] = ((const uint4*)gk)[1];
        *(uint4*)&v_b[li * 136 + ld0]     = ((const uint4*)gv)[0];
        *(uint4*)&v_b[li * 136 + ld0 + 8] = ((const uint4*)gv)[1];
    }
    if (tid < 32) betas_s[tid] = beta[(row0 + tid) * NHEAD + h];
    __syncthreads();

    // ---- phase 1: l2norm rows of q,k (re-read LDS, no register caching)
    {
        float sq = 0.f, sk = 0.f;
#pragma unroll
        for (int e = 0; e < 8; ++e) {
            unsigned uq = *(const unsigned*)&q_b[li * 136 + ld0 + e * 2];
            unsigned uk = *(const unsigned*)&k_b[li * 136 + ld0 + e * 2];
            float q0 = bf2f((unsigned short)uq), q1 = bf2f((unsigned short)(uq >> 16));
            float k0 = bf2f((unsigned short)uk), k1 = bf2f((unsigned short)(uk >> 16));
            sq = fmaf(q0, q0, fmaf(q1, q1, sq));
            sk = fmaf(k0, k0, fmaf(k1, k1, sk));
        }
#pragma unroll
        for (int m = 1; m < 8; m <<= 1) { sq += __shfl_xor(sq, m); sk += __shfl_xor(sk, m); }
        float rq = rsqrtf(sq + 1e-6f), rk = rsqrtf(sk + 1e-6f);
#pragma unroll
        for (int e = 0; e < 8; ++e) {
            unsigned uq = *(const unsigned*)&q_b[li * 136 + ld0 + e * 2];
            unsigned uk = *(const unsigned*)&k_b[li * 136 + ld0 + e * 2];
            unsigned pq = (unsigned)f2bf(bf2f((unsigned short)uq) * rq)
                        | ((unsigned)f2bf(bf2f((unsigned short)(uq >> 16)) * rq) << 16);
            unsigned pk = (unsigned)f2bf(bf2f((unsigned short)uk) * rk)
                        | ((unsigned)f2bf(bf2f((unsigned short)(uk >> 16)) * rk) << 16);
            *(unsigned*)&q_b[li * 136 + ld0 + e * 2] = pq;
            *(unsigned*)&k_b[li * 136 + ld0 + e * 2] = pk;
        }
    }
    __syncthreads();
    __builtin_amdgcn_sched_barrier(0);

    // ---- phase 2: kn write-through (vectorized)
    {
        unsigned short* gk = kn_out + base + (size_t)li * DMODEL + ld0;
        ((uint4*)gk)[0] = *(const uint4*)&k_b[li * 136 + ld0];
        ((uint4*)gk)[1] = *(const uint4*)&k_b[li * 136 + ld0 + 8];
    }

    // ---- phase 3: Am, at via MFMA (wave wid -> 16x16 tile (tr,tc))
    {
        const int tr = wid >> 1, tc = wid & 1;
        const int fr = l & 15, ko = (l >> 4) * 8;
        f4v accA = zf, accT = zf;
#pragma unroll
        for (int kt = 0; kt < 4; ++kt) {
            s8v ka  = *(const s8v*)&k_b[(tr * 16 + fr) * 136 + kt * 32 + ko];
            s8v qa  = *(const s8v*)&q_b[(tr * 16 + fr) * 136 + kt * 32 + ko];
            s8v kb2 = *(const s8v*)&k_b[(tc * 16 + fr) * 136 + kt * 32 + ko];
            accA = __builtin_amdgcn_mfma_f32_16x16x32_bf16(ka, kb2, accA, 0, 0, 0);
            accT = __builtin_amdgcn_mfma_f32_16x16x32_bf16(qa, kb2, accT, 0, 0, 0);
        }
        const int jloc = tc * 16 + fr;
#pragma unroll
        for (int q = 0; q < 4; ++q) {
            int iloc = tr * 16 + (l >> 4) * 4 + q;
            Am[iloc][jloc] = (iloc > jloc) ? betas_s[iloc] * accA[q] : 0.f;
            at_b[iloc * 40 + jloc] = f2bf((iloc >= jloc) ? accT[q] : 0.f);
        }
    }
    __syncthreads();
    __builtin_amdgcn_sched_barrier(0);

    // ---- phase 4: forward substitution (I+Am)x = rhs; one column per thread
    {
        float x[32];
        const int t = tid;
        if (t < 128) {
#pragma unroll
            for (int i = 0; i < 32; ++i) x[i] = betas_s[i] * bf2f(v_b[i * 136 + t]);
        } else {
            const int d = t - 128;
#pragma unroll
            for (int i = 0; i < 32; ++i) x[i] = betas_s[i] * bf2f(k_b[i * 136 + d]);
        }
#pragma unroll
        for (int i = 1; i < 32; ++i) {
            float s = 0.f;
#pragma unroll
            for (int m = 0; m < i; ++m) s = fmaf(Am[i][m], x[m], s);
            x[i] -= s;
        }
        const size_t tb = (size_t)bid * 8192;
        if (t < 128) {
#pragma unroll
            for (int i2 = 0; i2 < 16; ++i2) {
                unsigned short b0 = f2bf(x[i2 * 2]), b1 = f2bf(x[i2 * 2 + 1]);
                *(unsigned*)&uT[t * 40 + i2 * 2] = (unsigned)b0 | ((unsigned)b1 << 16);
                wu[tb + 4096 + (i2 * 2) * 128 + t]     = __float2bfloat16(x[i2 * 2]);
                wu[tb + 4096 + (i2 * 2 + 1) * 128 + t] = __float2bfloat16(x[i2 * 2 + 1]);
            }
        } else {
            const int d = t - 128;
#pragma unroll
            for (int i2 = 0; i2 < 16; ++i2) {
                unsigned short b0 = f2bf(x[i2 * 2]), b1 = f2bf(x[i2 * 2 + 1]);
                *(unsigned*)&wT[d * 40 + i2 * 2] = (unsigned)b0 | ((unsigned)b1 << 16);
                wu[tb + (i2 * 2) * 128 + d]     = __float2bfloat16(x[i2 * 2]);
                wu[tb + (i2 * 2 + 1) * 128 + d] = __float2bfloat16(x[i2 * 2 + 1]);
            }
        }
    }
    __syncthreads();
    __builtin_amdgcn_sched_barrier(0);

    // ---- phase 5: qe = qn - at@w ; o_pre = at@u  (split by rt to limit liveness)
    {
        const int fr = l & 15, ko = (l >> 4) * 8;
        const int ct0 = wid * 2, ct1 = wid * 2 + 1;
#pragma unroll
        for (int rt = 0; rt < 2; ++rt) {
            s8v a   = *(const s8v*)&at_b[(rt * 16 + fr) * 40 + ko];
            s8v bw0 = *(const s8v*)&wT[(ct0 * 16 + fr) * 40 + ko];
            s8v bw1 = *(const s8v*)&wT[(ct1 * 16 + fr) * 40 + ko];
            s8v bu0 = *(const s8v*)&uT[(ct0 * 16 + fr) * 40 + ko];
            s8v bu1 = *(const s8v*)&uT[(ct1 * 16 + fr) * 40 + ko];
            f4v qw0 = __builtin_amdgcn_mfma_f32_16x16x32_bf16(a, bw0, zf, 0, 0, 0);
            f4v qw1 = __builtin_amdgcn_mfma_f32_16x16x32_bf16(a, bw1, zf, 0, 0, 0);
            f4v ou0 = __builtin_amdgcn_mfma_f32_16x16x32_bf16(a, bu0, zf, 0, 0, 0);
            f4v ou1 = __builtin_amdgcn_mfma_f32_16x16x32_bf16(a, bu1, zf, 0, 0, 0);
#pragma unroll
            for (int q = 0; q < 4; ++q) {
                const int i = rt * 16 + (l >> 4) * 4 + q;
                {
                    const int d = ct0 * 16 + fr;
                    size_t g = base + (size_t)i * DMODEL + d;
                    qe_out[g] = f2bf(bf2f(q_b[i * 136 + d]) - qw0[q]);
                    opre[g]   = f2bf(ou0[q]);
                }
                {
                    const int d = ct1 * 16 + fr;
                    size_t g = base + (size_t)i * DMODEL + d;
                    qe_out[g] = f2bf(bf2f(q_b[i * 136 + d]) - qw1[q]);
                    opre[g]   = f2bf(ou1[q]);
                }
            }
            __builtin_amdgcn_sched_barrier(0);
        }
    }
}

// ---------------------------------------------------------------------------
// Phase 2: MFMA state scan, double-buffered, 2 barriers/chunk.
// knT stored with XOR column swizzle (col' = i ^ (((d>>4)&3)<<3)) -> 4-way max.
// Next-chunk LDS unpack overlaps phase B's MFMAs.
// ---------------------------------------------------------------------------
__global__ __launch_bounds__(256)
void delta_scan4(const unsigned short* __restrict__ qe, const unsigned short* __restrict__ kn,
                 const bf16* __restrict__ wu, bf16* __restrict__ delta,
                 const float* __restrict__ ret)
{
    const int bid0 = blockIdx.x;
    const int dvs = (bid0 >> 3) & 7;                      // dv-slice
    const int bh  = ((bid0 >> 6) << 3) | (bid0 & 7);      // xcd-stable bh
    const int h = bh & 7, b = bh >> 3;
    const int tid = threadIdx.x;
    const int l = tid & 63, wid = tid >> 6;

    __shared__ __align__(16) unsigned short qe_b[2][32 * 136];
    __shared__ __align__(16) unsigned short w_b [2][32 * 136];
    __shared__ __align__(16) unsigned short knT [2][128 * 40];
    __shared__ __align__(16) unsigned short St_b[16 * 136];
    __shared__ __align__(16) unsigned short uaT [16 * 40];
    __shared__ float us_s[2][32][18], ops_s[2][32][18];

    const float lam = 0.6f + 0.4f * sigmoidf_(ret[h]);

    for (int i = tid; i < 16 * 136; i += 256) St_b[i] = 0;

    const int li = tid >> 3, ld0 = (tid & 7) * 16;
    const int iu = tid >> 3, tu = (tid & 7) * 2;
    const size_t headoff = (size_t)h * DHEAD;
    const int kswz = ((ld0 >> 4) & 3) << 3;   // knT write swizzle (const/thread)
    const int colp = li ^ kswz;

    const f4v zf = {0.f, 0.f, 0.f, 0.f};
    f4v Sacc0 = zf, Sacc1 = zf;        // this wave's S d-tiles (d0 = wid*32)

    uint4 pq[2], pk[2], pw[2];
    unsigned puv, pov;

#define ISSUE(cc)  {                                                                        \
        size_t rb = ((size_t)b * LSEQ + (size_t)(cc) * 32);                                 \
        const unsigned short* gq = qe + (rb + li) * DMODEL + headoff + ld0;                 \
        const unsigned short* gk = kn + (rb + li) * DMODEL + headoff + ld0;                 \
        pq[0] = ((const uint4*)gq)[0]; pq[1] = ((const uint4*)gq)[1];                       \
        pk[0] = ((const uint4*)gk)[0]; pk[1] = ((const uint4*)gk)[1];                       \
        size_t tb = ((size_t)bh * NCHUNK + (cc)) * 8192;                                    \
        const uint4* gw = (const uint4*)(wu + tb + li * 128 + ld0);                         \
        pw[0] = gw[0]; pw[1] = gw[1];                                                       \
        puv = *(const unsigned*)(wu + tb + 4096 + iu * 128 + dvs * 16 + tu);                \
        pov = *(const unsigned*)(delta + (rb + iu) * DMODEL + headoff + dvs * 16 + tu);     \
    }

#define UNPACK(bf)  {                                                                       \
        *(uint4*)&qe_b[bf][li * 136 + ld0]     = pq[0];                                     \
        *(uint4*)&qe_b[bf][li * 136 + ld0 + 8] = pq[1];                                     \
        const unsigned short* pks = (const unsigned short*)&pk[0];                          \
        _Pragma("unroll")                                                                   \
        for (int e = 0; e < 16; ++e)                                                        \
            knT[bf][(ld0 + e) * 40 + colp] = pks[e];                                        \
        *(uint4*)&w_b[bf][li * 136 + ld0]     = pw[0];                                      \
        *(uint4*)&w_b[bf][li * 136 + ld0 + 8] = pw[1];                                      \
        us_s[bf][iu][tu]      = bf2f((unsigned short)puv);                                  \
        us_s[bf][iu][tu + 1]  = bf2f((unsigned short)(puv >> 16));                          \
        ops_s[bf][iu][tu]     = bf2f((unsigned short)pov);                                  \
        ops_s[bf][iu][tu + 1] = bf2f((unsigned short)(pov >> 16));                          \
    }

    ISSUE(0);
    UNPACK(0);
    ISSUE(1);
    __syncthreads();

    for (int c = 0; c < NCHUNK; ++c) {
        const int cur = c & 1;

        // ---- phase A: waves 0,1 -> ua = u - w@S ; waves 2,3 -> o = opre + qe@S
        {
            const int half = wid & 1;
            const int arow = half * 16 + (l & 15);
            const int koff = (l >> 4) * 8;
            const unsigned short* ab = (wid < 2) ? w_b[cur] : qe_b[cur];
            f4v a = zf;
#pragma unroll
            for (int kt = 0; kt < 4; ++kt) {
                s8v af  = *(const s8v*)&ab[arow * 136 + kt * 32 + koff];
                s8v bf_ = *(const s8v*)&St_b[(l & 15) * 136 + kt * 32 + koff];
                a = __builtin_amdgcn_mfma_f32_16x16x32_bf16(af, bf_, a, 0, 0, 0);
            }
            const int ib = half * 16 + ((l >> 4) << 2);
            const int t = l & 15;
            if (wid < 2) {
#pragma unroll
                for (int q = 0; q < 4; ++q) {
                    float v = us_s[cur][ib + q][t] - a[q];
                    uaT[t * 40 + ib + q] = f2bf(v);
                }
            } else {
                size_t rb = (size_t)b * LSEQ + (size_t)c * 32;
#pragma unroll
                for (int q = 0; q < 4; ++q) {
                    float v = ops_s[cur][ib + q][t] + a[q];
                    delta[(rb + ib + q) * DMODEL + headoff + dvs * 16 + t] = __float2bfloat16(v);
                }
            }
        }
        __syncthreads();

        // ---- phase B: Sacc = lam*Sacc + uaT @ knT ; export bf16 St_b
        //      overlapped with next-chunk unpack + prefetch issue
        {
#pragma unroll
            for (int q = 0; q < 4; ++q) { Sacc0[q] *= lam; Sacc1[q] *= lam; }
            const int koff = (l >> 4) * 8;
            const int sw0 = ((2 * wid) & 3) << 3;
            const int sw1 = ((2 * wid + 1) & 3) << 3;
            s8v af = *(const s8v*)&uaT[(l & 15) * 40 + koff];
            const int d0 = wid * 32;
            s8v b0 = *(const s8v*)&knT[cur][(d0 + (l & 15)) * 40 + (koff ^ sw0)];
            s8v b1 = *(const s8v*)&knT[cur][(d0 + 16 + (l & 15)) * 40 + (koff ^ sw1)];
            Sacc0 = __builtin_amdgcn_mfma_f32_16x16x32_bf16(af, b0, Sacc0, 0, 0, 0);
            Sacc1 = __builtin_amdgcn_mfma_f32_16x16x32_bf16(af, b1, Sacc1, 0, 0, 0);

            if (c + 1 < NCHUNK) UNPACK(cur ^ 1);
            if (c + 2 < NCHUNK) ISSUE(c + 2);

            const int tr = (l >> 4) << 2;
#pragma unroll
            for (int q = 0; q < 4; ++q) {
                St_b[(tr + q) * 136 + d0 + (l & 15)]      = f2bf(Sacc0[q]);
                St_b[(tr + q) * 136 + d0 + 16 + (l & 15)] = f2bf(Sacc1[q]);
            }
        }
        __syncthreads();
    }
#undef ISSUE
#undef UNPACK
}

// ---------------------------------------------------------------------------
// FIR computed once, LDS-tiled (unchanged)
// ---------------------------------------------------------------------------
__global__ __launch_bounds__(256)
void fir_compute(const unsigned short* __restrict__ v,
                 const float* __restrict__ wshort, const float* __restrict__ wlong,
                 unsigned short* __restrict__ fso, unsigned short* __restrict__ flo)
{
    const int lt = blockIdx.x, h = blockIdx.y, b = blockIdx.z;
    const int tid = threadIdx.x;
    __shared__ unsigned short vt[190 * 128];
    __shared__ float wl[63 * 128];
    __shared__ float w3[3 * 128];

    for (int i = tid; i < 63 * 128; i += 256) {
        int j = i >> 7, d = i & 127;
        wl[i] = wlong[((size_t)h * 128 + d) * 63 + j];
    }
    for (int i = tid; i < 3 * 128; i += 256) {
        int j = i >> 7, d = i & 127;
        w3[i] = wshort[((size_t)h * 128 + d) * 3 + j];
    }
    const size_t vbase = ((size_t)b * LSEQ) * DMODEL + (size_t)h * DHEAD;
    const int l0 = lt * 128;
    const s8v z8 = {0, 0, 0, 0, 0, 0, 0, 0};
    for (int i = tid; i < 190 * 16; i += 256) {
        int row = i >> 4, dblk = (i & 15) * 8;
        int gl = l0 - 62 + row;
        s8v val = z8;
        if (gl >= 0) val = *(const s8v*)&v[vbase + (size_t)gl * DMODEL + dblk];
        *(s8v*)&vt[row * 128 + dblk] = val;
    }
    __syncthreads();

    const int dp = (tid & 63) * 2, lg = tid >> 6;
    for (int lc = 0; lc < 4; ++lc) {
        const int lb = lg * 32 + lc * 8;
        float a0[8], a1[8], s0[8], s1[8];
#pragma unroll
        for (int li = 0; li < 8; ++li) { a0[li] = a1[li] = s0[li] = s1[li] = 0.f; }
        for (int j = 0; j < 63; ++j) {
            float w0 = wl[j * 128 + dp], w1 = wl[j * 128 + dp + 1];
#pragma unroll
            for (int li = 0; li < 8; ++li) {
                unsigned vv = *(const unsigned*)&vt[(lb + li + j) * 128 + dp];
                a0[li] = fmaf(bf2f((unsigned short)vv), w0, a0[li]);
                a1[li] = fmaf(bf2f((unsigned short)(vv >> 16)), w1, a1[li]);
            }
        }
#pragma unroll
        for (int j = 0; j < 3; ++j) {
            float w0 = w3[j * 128 + dp], w1 = w3[j * 128 + dp + 1];
#pragma unroll
            for (int li = 0; li < 8; ++li) {
                unsigned vv = *(const unsigned*)&vt[(lb + li + 60 + j) * 128 + dp];
                s0[li] = fmaf(bf2f((unsigned short)vv), w0, s0[li]);
                s1[li] = fmaf(bf2f((unsigned short)(vv >> 16)), w1, s1[li]);
            }
        }
        const size_t ob = ((size_t)b * LSEQ + l0) * DMODEL + (size_t)h * DHEAD + dp;
#pragma unroll
        for (int li = 0; li < 8; ++li) {
            unsigned pf = (unsigned)f2bf(a0[li]) | ((unsigned)f2bf(a1[li]) << 16);
            unsigned ps = (unsigned)f2bf(s0[li]) | ((unsigned)f2bf(s1[li]) << 16);
            *(unsigned*)&flo[ob + (size_t)(lb + li) * DMODEL] = pf;
            *(unsigned*)&fso[ob + (size_t)(lb + li) * DMODEL] = ps;
        }
    }
}

// ---------------------------------------------------------------------------
// Stats: one wave per (r,h) row; bf16 output (feeds gate1 A2)
// ---------------------------------------------------------------------------
__global__ __launch_bounds__(256)
void fir_stats2(const unsigned short* __restrict__ fs, const unsigned short* __restrict__ fl,
                const unsigned short* __restrict__ dlt, const unsigned short* __restrict__ v,
                unsigned short* __restrict__ stats)
{
    const int rh = blockIdx.x * 4 + (threadIdx.x >> 6);
    const int lane = threadIdx.x & 63;
    const int r = rh >> 3, h = rh & 7;
    const size_t base = (size_t)r * DMODEL + (size_t)h * DHEAD + lane * 2;
    unsigned ua = *(const unsigned*)(fs + base);
    unsigned ub = *(const unsigned*)(fl + base);
    unsigned uc = *(const unsigned*)(dlt + base);
    unsigned ud = *(const unsigned*)(v + base);
    float s0 = bf2f((unsigned short)ua) + bf2f((unsigned short)(ua >> 16));
    float s1 = bf2f((unsigned short)ub) + bf2f((unsigned short)(ub >> 16));
    float s2 = bf2f((unsigned short)uc) + bf2f((unsigned short)(uc >> 16));
    float s3 = bf2f((unsigned short)ud) + bf2f((unsigned short)(ud >> 16));
#pragma unroll
    for (int m = 1; m < 64; m <<= 1) {
        s0 += __shfl_xor(s0, m); s1 += __shfl_xor(s1, m);
        s2 += __shfl_xor(s2, m); s3 += __shfl_xor(s3, m);
    }
    if (lane == 0) {
        const float inv = 1.f / 128.f;
        stats[(size_t)r * 32 + 0  + h] = f2bf(s0 * inv);
        stats[(size_t)r * 32 + 8  + h] = f2bf(s1 * inv);
        stats[(size_t)r * 32 + 16 + h] = f2bf(s2 * inv);
        stats[(size_t)r * 32 + 24 + h] = f2bf(s3 * inv);
    }
}

// ---------------------------------------------------------------------------
// Combine + RMS norm; bf16 output (feeds final MFMA GEMM)
// ---------------------------------------------------------------------------
__global__ __launch_bounds__(256)
void combine2(const unsigned short* __restrict__ fs, const unsigned short* __restrict__ fl,
              const unsigned short* __restrict__ dlt, const unsigned short* __restrict__ v,
              const float* __restrict__ p, const float* __restrict__ onw,
              unsigned short* __restrict__ on)
{
    const int rh = blockIdx.x * 4 + (threadIdx.x >> 6);
    const int lane = threadIdx.x & 63;
    const int r = rh >> 3, h = rh & 7;
    const size_t base = (size_t)r * DMODEL + (size_t)h * DHEAD + lane * 2;
    unsigned ua = *(const unsigned*)(fs + base);
    unsigned ub = *(const unsigned*)(fl + base);
    unsigned uc = *(const unsigned*)(dlt + base);
    unsigned ud = *(const unsigned*)(v + base);
    const float* pp = p + (size_t)r * 32 + h * 4;
    float p0 = pp[0], p1 = pp[1], p2 = pp[2], p3 = pp[3];
    float ox = p0 * bf2f((unsigned short)ua) + p1 * bf2f((unsigned short)ub)
             + p2 * bf2f((unsigned short)uc) + p3 * bf2f((unsigned short)ud);
    float oy = p0 * bf2f((unsigned short)(ua >> 16)) + p1 * bf2f((unsigned short)(ub >> 16))
             + p2 * bf2f((unsigned short)(uc >> 16)) + p3 * bf2f((unsigned short)(ud >> 16));
    float ss = ox * ox + oy * oy;
#pragma unroll
    for (int m = 1; m < 64; m <<= 1) ss += __shfl_xor(ss, m);
    float sc = rsqrtf(ss * (1.f / 128.f) + 1e-5f);
    unsigned pw = (unsigned)f2bf(ox * sc * onw[lane * 2])
                | ((unsigned)f2bf(oy * sc * onw[lane * 2 + 1]) << 16);
    *(unsigned*)(on + base) = pw;
}

// ---------------------------------------------------------------------------
// Workspace (~202.5 MB). All activation streams bf16 (32MB halves):
//  A.lo: qpb -> kcb/kn -> o_norm     A.hi: kpb -> vbf
//  B.lo: vpb -> opre/delta           B.hi: qcb/qe -> hdn
//  C   : wu tiles -> [C.lo: fs][C.hi: fl]
//  O.lo(d_out): hsb bf16             O.hi: wqkvt   -> final out fp32 (full)
// ---------------------------------------------------------------------------
extern "C" void kernel_launch(void* const* d_in, const int* in_sizes, int n_in,
                              void* d_out, int out_size, void* d_ws, size_t ws_size,
                              hipStream_t stream)
{
    const float* hs   = (const float*)d_in[0];
    const float* Wq   = (const float*)d_in[1];
    const float* Wk   = (const float*)d_in[2];
    const float* Wv   = (const float*)d_in[3];
    const float* Wb   = (const float*)d_in[4];
    const float* cqw  = (const float*)d_in[5];
    const float* ckw  = (const float*)d_in[6];
    const float* cvw  = (const float*)d_in[7];
    const float* ret  = (const float*)d_in[8];
    const float* fsw  = (const float*)d_in[9];
    const float* flw  = (const float*)d_in[10];
    const float* gw1  = (const float*)d_in[11];
    const float* gb1  = (const float*)d_in[12];
    const float* gw2  = (const float*)d_in[13];
    const float* gb2  = (const float*)d_in[14];
    const float* ltmp = (const float*)d_in[15];
    const float* onw  = (const float*)d_in[16];
    const float* Wo   = (const float*)d_in[17];
    float* out = (float*)d_out;

    char* wsp = (char*)d_ws;
    size_t off = 0;
    auto alloc = [&](size_t nbytes) -> void* {
        void* pt = (void*)(wsp + off);
        off += ((nbytes + 255) / 256) * 256;
        return pt;
    };
    const int R = R_TOT;
    const size_t HALF = (size_t)R * DMODEL;        // elements per 32MB half
    float* bufA  = (float*)alloc(HALF * 4);
    float* bufB  = (float*)alloc(HALF * 4);
    float* bufC  = (float*)alloc(HALF * 4);
    float* beta  = (float*)alloc((size_t)R * NHEAD * 4);
    unsigned short* statsb = (unsigned short*)alloc((size_t)R * 32 * 2);
    float* pbuf  = (float*)alloc((size_t)R * 32 * 4);
    unsigned short* gw1t = (unsigned short*)alloc((size_t)2048 * 1056 * 2);
    unsigned short* wot  = (unsigned short*)alloc((size_t)1024 * 1024 * 2);
    unsigned short* wbt  = (unsigned short*)alloc((size_t)128 * 1024 * 2);
    unsigned short* gw2t = (unsigned short*)alloc((size_t)128 * 2048 * 2);

    unsigned short* Alo = (unsigned short*)bufA;  unsigned short* Ahi = Alo + HALF;
    unsigned short* Blo = (unsigned short*)bufB;  unsigned short* Bhi = Blo + HALF;
    unsigned short* Clo = (unsigned short*)bufC;  unsigned short* Chi = Clo + HALF;
    unsigned short* Olo = (unsigned short*)d_out; unsigned short* Ohi = Olo + HALF;

    unsigned short* hsb   = Olo;                  // hs bf16
    unsigned short* wqkvt = Ohi;                  // 3072x1024 bf16 = 6MB
    unsigned short* qpb = Alo, *kpb = Ahi, *vpb = Blo;
    unsigned short* qcb = Bhi, *kcb = Alo, *vbf = Ahi;
    bf16* wu = (bf16*)bufC;
    unsigned short* dlt = Blo;                    // opre -> delta
    unsigned short* fsb = Clo, *flb = Chi;
    unsigned short* hdnb = Bhi;                   // gate1 out bf16
    unsigned short* onb = Alo;                    // o_norm bf16
    (void)ws_size; (void)in_sizes; (void)n_in; (void)out_size;

    dim3 blk(256);
    // 0. hs -> bf16
    hcast<<<(int)(HALF / (256 * 8)), blk, 0, stream>>>(hs, hsb);
    // 1. weight transposes / pads
    tcast<<<dim3(32, 32), blk, 0, stream>>>(Wq, wqkvt, 1024, 1024, 1024);
    tcast<<<dim3(32, 32), blk, 0, stream>>>(Wk, wqkvt + (size_t)1024 * 1024, 1024, 1024, 1024);
    tcast<<<dim3(32, 32), blk, 0, stream>>>(Wv, wqkvt + (size_t)2048 * 1024, 1024, 1024, 1024);
    tcast<<<dim3(33, 64), blk, 0, stream>>>(gw1, gw1t, 1056, 2048, 2048);
    tcast<<<dim3(32, 32), blk, 0, stream>>>(Wo, wot, 1024, 1024, 1024);
    tcast<<<dim3(32, 4),  blk, 0, stream>>>(Wb, wbt, 1024, 8, 128);
    tcast<<<dim3(64, 4),  blk, 0, stream>>>(gw2, gw2t, 2048, 32, 128);

    // 2. fused qkv projection (bf16 A, bf16 out)
    mgemm<5><<<dim3(24, 128), blk, 0, stream>>>(hsb, nullptr, 1 << 30, DMODEL, 0,
                                                wqkvt, nullptr, nullptr,
                                                qpb, kpb, vpb, R, 3072, 1024, 0);
    // 3. beta = sigmoid(hs @ Wb)
    mgemm<1><<<dim3(1, 128), blk, 0, stream>>>(hsb, nullptr, 1 << 30, DMODEL, 0,
                                               wbt, nullptr, nullptr,
                                               beta, nullptr, nullptr, R, 128, 1024, 8);
    // 4. short conv + silu: q: A.lo->B.hi, k: A.hi->A.lo, v: B.lo->A.hi
    int convGrid = (int)(((size_t)R * DMODEL + 255) / 256);
    shortconv_b<<<convGrid, blk, 0, stream>>>(qpb, cqw, qcb);
    shortconv_b<<<convGrid, blk, 0, stream>>>(kpb, ckw, kcb);
    shortconv_b<<<convGrid, blk, 0, stream>>>(vpb, cvw, vbf);
    // 5/6. delta rule
    chunk_prep2<<<4096, blk, 0, stream>>>(qcb, kcb, vbf, beta, qcb, kcb, wu, dlt);
    delta_scan4<<<256, blk, 0, stream>>>(qcb, kcb, wu, (bf16*)dlt, ret);
    // 7. FIR once (wu dead -> bufC holds fs|fl)
    fir_compute<<<dim3(32, 8, 4), blk, 0, stream>>>(vbf, fsw, flw, fsb, flb);
    // 8. stats (bf16)
    fir_stats2<<<32768, blk, 0, stream>>>(fsb, flb, dlt, vbf, statsb);
    // 9. gate MLP (two row-chunks; hdn bf16 in B.hi — qe dead)
    const int RC = 8192;
    for (int r0 = 0; r0 < R; r0 += RC) {
        mgemm<2><<<dim3(16, RC / 128), blk, 0, stream>>>(hsb + (size_t)r0 * DMODEL,
                                                         statsb + (size_t)r0 * 32,
                                                         1024, DMODEL, 32, gw1t, gb1, nullptr,
                                                         hdnb, nullptr, nullptr,
                                                         RC, 2048, 1056, 0);
        mgemm<3><<<dim3(1, RC / 128), blk, 0, stream>>>(hdnb, nullptr, 1 << 30, 2048, 0,
                                                        gw2t, gb2, ltmp,
                                                        pbuf + (size_t)r0 * 32, nullptr, nullptr,
                                                        RC, 128, 2048, 32);
    }
    // 10. combine + RMS norm -> o_norm bf16 (A.lo, kn dead)
    combine2<<<32768, blk, 0, stream>>>(fsb, flb, dlt, vbf, pbuf, onw, onb);
    // 11. final projection -> d_out fp32 (hsb/wqkvt dead)
    mgemm<0><<<dim3(8, 128), blk, 0, stream>>>(onb, nullptr, 1 << 30, DMODEL, 0,
                                               wot, nullptr, nullptr,
                                               out, nullptr, nullptr, R, 1024, 1024, 0);
}